// Round 3
// baseline (9717.783 us; speedup 1.0000x reference)
//
#include <hip/hip_runtime.h>
#include <hip/hip_bf16.h>

#define Bz 32
#define Tz 64
#define Sz 128
#define Hz 512
#define Vz 32000
#define G4 (4*Hz)
#define NBLK 256

using bf16x8 = __attribute__((ext_vector_type(8))) short;
using f32x4  = __attribute__((ext_vector_type(4))) float;

__device__ __forceinline__ unsigned short f2bf(float f){
  unsigned int u = __float_as_uint(f);
  u += 0x7fffu + ((u >> 16) & 1u);
  return (unsigned short)(u >> 16);
}
__device__ __forceinline__ float sigf(float x){ return 1.f/(1.f + expf(-x)); }

// ---------------- grid barrier (device-scope) ----------------
__device__ __forceinline__ void gbar(int* bar){
  __syncthreads();
  if (threadIdx.x == 0){
    __threadfence();
    int g = __hip_atomic_load(&bar[1], __ATOMIC_RELAXED, __HIP_MEMORY_SCOPE_AGENT);
    if (__hip_atomic_fetch_add(&bar[0], 1, __ATOMIC_ACQ_REL, __HIP_MEMORY_SCOPE_AGENT) == NBLK - 1){
      __hip_atomic_store(&bar[0], 0, __ATOMIC_RELAXED, __HIP_MEMORY_SCOPE_AGENT);
      __hip_atomic_fetch_add(&bar[1], 1, __ATOMIC_RELEASE, __HIP_MEMORY_SCOPE_AGENT);
    } else {
      while (__hip_atomic_load(&bar[1], __ATOMIC_ACQUIRE, __HIP_MEMORY_SCOPE_AGENT) == g)
        __builtin_amdgcn_s_sleep(2);
    }
    __threadfence();
  }
  __syncthreads();
}

// ---------------- init ----------------
__global__ __launch_bounds__(256) void init_state_v2(const float* __restrict__ h0,
    const float* __restrict__ c0, float* __restrict__ h0p, float* __restrict__ h1p,
    float* __restrict__ cbuf, int* __restrict__ bar){
  int i = blockIdx.x*256 + threadIdx.x;   // grid 128 -> 32768
  if (i < 16384) h0p[i] = h0[i];
  else           h1p[i-16384] = h0[i];
  cbuf[i] = c0[i];
  if (i < 2) bar[i] = 0;
}

// ---------------- Wo -> bf16 ----------------
__global__ __launch_bounds__(256) void conv_bf16_kernel(const float* __restrict__ src,
    unsigned short* __restrict__ dst){
  int i = (blockIdx.x*256 + threadIdx.x)*4;
  float4 v = *(const float4*)(src + i);
  ushort4 o;
  o.x = f2bf(v.x); o.y = f2bf(v.y); o.z = f2bf(v.z); o.w = f2bf(v.w);
  *(ushort4*)(dst + i) = o;
}

// ---------------- weight packing: [kb][r] float4, r = u*4+gate ----------------
__global__ __launch_bounds__(256) void pack_l0_kernel(const float* __restrict__ W,
    float* __restrict__ out){
  int idx = blockIdx.x*256 + threadIdx.x;   // 1024 blocks
  int r = idx & 2047, kb = idx >> 11;
  int row = (r & 3)*Hz + (r >> 2);
  *(float4*)(out + (size_t)idx*4) = *(const float4*)(W + (size_t)row*Hz + kb*4);
}
__global__ __launch_bounds__(256) void pack_l1_kernel(const float* __restrict__ Wi,
    const float* __restrict__ Wh, float* __restrict__ out){
  int idx = blockIdx.x*256 + threadIdx.x;   // 2048 blocks
  int r = idx & 2047, kb = idx >> 11;
  int row = (r & 3)*Hz + (r >> 2);
  const float* src = (kb < 128) ? (Wi + (size_t)row*Hz + kb*4)
                                : (Wh + (size_t)row*Hz + (kb-128)*4);
  *(float4*)(out + (size_t)idx*4) = *(const float4*)src;
}
__global__ __launch_bounds__(256) void pack_wc_kernel(const float* __restrict__ Wc,
    float* __restrict__ out){
  int idx = blockIdx.x*256 + threadIdx.x;   // 512 blocks
  int u = idx & 511, kb = idx >> 9;
  *(float4*)(out + (size_t)idx*4) = *(const float4*)(Wc + (size_t)u*(2*Hz) + kb*4);
}

// ---------------- x0g: tiled fp32 GEMM ----------------
__global__ __launch_bounds__(256) void x0g_v2(const int* __restrict__ tgt,
    const float* __restrict__ emb, const float* __restrict__ W,
    const float* __restrict__ bi, const float* __restrict__ bh,
    float* __restrict__ out){
  __shared__ float As[32][68], Bs[32][68];
  __shared__ int tok_s[64];
  int tid = threadIdx.x;
  int m0 = blockIdx.y*64, n0 = blockIdx.x*64;
  if (tid < 64){ int tb = m0 + tid; tok_s[tid] = tgt[(tb & 31)*Tz + (tb >> 5)]; }
  __syncthreads();
  int lm = tid >> 2, lk = (tid & 3)*8;
  int ty = tid >> 4, tx = tid & 15;
  float acc[4][4] = {{0.f}};
  for (int kt = 0; kt < 16; kt++){
    float4 a0 = *(const float4*)(emb + (size_t)tok_s[lm]*Hz + kt*32 + lk);
    float4 a1 = *(const float4*)(emb + (size_t)tok_s[lm]*Hz + kt*32 + lk + 4);
    float4 b0 = *(const float4*)(W   + (size_t)(n0+lm)*Hz + kt*32 + lk);
    float4 b1 = *(const float4*)(W   + (size_t)(n0+lm)*Hz + kt*32 + lk + 4);
    __syncthreads();
    As[lk+0][lm]=a0.x; As[lk+1][lm]=a0.y; As[lk+2][lm]=a0.z; As[lk+3][lm]=a0.w;
    As[lk+4][lm]=a1.x; As[lk+5][lm]=a1.y; As[lk+6][lm]=a1.z; As[lk+7][lm]=a1.w;
    Bs[lk+0][lm]=b0.x; Bs[lk+1][lm]=b0.y; Bs[lk+2][lm]=b0.z; Bs[lk+3][lm]=b0.w;
    Bs[lk+4][lm]=b1.x; Bs[lk+5][lm]=b1.y; Bs[lk+6][lm]=b1.z; Bs[lk+7][lm]=b1.w;
    __syncthreads();
    #pragma unroll
    for (int k = 0; k < 32; k++){
      float4 av = *(const float4*)&As[k][ty*4];
      float4 bv = *(const float4*)&Bs[k][tx*4];
      acc[0][0]+=av.x*bv.x; acc[0][1]+=av.x*bv.y; acc[0][2]+=av.x*bv.z; acc[0][3]+=av.x*bv.w;
      acc[1][0]+=av.y*bv.x; acc[1][1]+=av.y*bv.y; acc[1][2]+=av.y*bv.z; acc[1][3]+=av.y*bv.w;
      acc[2][0]+=av.z*bv.x; acc[2][1]+=av.z*bv.y; acc[2][2]+=av.z*bv.z; acc[2][3]+=av.z*bv.w;
      acc[3][0]+=av.w*bv.x; acc[3][1]+=av.w*bv.y; acc[3][2]+=av.w*bv.z; acc[3][3]+=av.w*bv.w;
    }
  }
  #pragma unroll
  for (int j = 0; j < 4; j++){
    int col = n0 + tx*4 + j;
    float bias = bi[col] + bh[col];
    #pragma unroll
    for (int i = 0; i < 4; i++)
      out[(size_t)(m0 + ty*4 + i)*G4 + col] = acc[i][j] + bias;
  }
}

// ---------------- attn-A: scores + softmax + ctx (one block handles b) ----------------
__device__ __forceinline__ void attn_A(int b, const float* hrow,
    const float* __restrict__ enc, float* ea, float* red, float* ctxb, int tid){
  {
    int s = tid >> 1, half = tid & 1;
    const float4* e4 = (const float4*)(enc + ((size_t)b*Sz + s)*Hz + half*256);
    const float4* h4 = (const float4*)(hrow + half*256);
    float a = 0.f;
    #pragma unroll 8
    for (int k = 0; k < 64; k++){
      float4 e = e4[k], h = h4[k];
      a += e.x*h.x + e.y*h.y + e.z*h.z + e.w*h.w;
    }
    a += __shfl_xor(a, 1);
    if (!half) ea[s] = a;
  }
  __syncthreads();
  if (tid < 64){
    float v = fmaxf(ea[tid], ea[tid+64]);
    #pragma unroll
    for (int off = 32; off; off >>= 1) v = fmaxf(v, __shfl_xor(v, off));
    if (tid == 0) red[0] = v;
  }
  __syncthreads();
  if (tid < 128) ea[tid] = expf(ea[tid] - red[0]);
  __syncthreads();
  if (tid < 64){
    float v = ea[tid] + ea[tid+64];
    #pragma unroll
    for (int off = 32; off; off >>= 1) v += __shfl_xor(v, off);
    if (tid == 0) red[1] = v;
  }
  __syncthreads();
  {
    float inv = 1.f/red[1];
    int k0 = tid*2;
    float c0 = 0.f, c1 = 0.f;
    const float* ep = enc + (size_t)b*Sz*Hz + k0;
    #pragma unroll 4
    for (int s = 0; s < Sz; s++){
      float2 ev = *(const float2*)(ep + (size_t)s*Hz);
      float pr = ea[s];
      c0 += pr*ev.x; c1 += pr*ev.y;
    }
    float2 o; o.x = c0*inv; o.y = c1*inv;
    *(float2*)(ctxb + b*Hz + k0) = o;
  }
}

// ---------------- attn-B helpers ----------------
__device__ __forceinline__ void attnB_gemv(const float* __restrict__ h1buf,
    const float* __restrict__ ctxb, const float* wcs, float* rs,
    int aul, int abb, int akq){
  const float* src = (akq < 2) ? (h1buf + abb*Hz + akq*256)
                               : (ctxb + abb*Hz + (akq-2)*256);
  const float4* w4 = (const float4*)&wcs[aul*1028 + akq*256];
  const float4* s4 = (const float4*)src;
  float a = 0.f;
  #pragma unroll 8
  for (int i = 0; i < 64; i++){
    float4 w = w4[i], v = s4[i];
    a += w.x*v.x + w.y*v.y + w.z*v.z + w.w*v.w;
  }
  rs[(aul*32 + abb)*4 + akq] = a;
}
__device__ __forceinline__ void attnB_fin(const float* rs, float bcv, int tb, int u, int tid,
    unsigned short* __restrict__ oa){
  const int ul = tid >> 5, bb = tid & 31;
  float4 rv = *(const float4*)&rs[(ul*32 + bb)*4];
  oa[((size_t)bb*Tz + tb)*Hz + u] = f2bf(tanhf(rv.x+rv.y+rv.z+rv.w+bcv));
  (void)ul;
}

// ---------------- persistent decoder: all 64 steps ----------------
__global__ __launch_bounds__(256, 1) void decoder_persistent(
    const float* __restrict__ WTp0, const float* __restrict__ WTp1,
    const float* __restrict__ WcTp, const float* __restrict__ x0g,
    const float* __restrict__ bi1, const float* __restrict__ bh1,
    const float* __restrict__ bc, const float* __restrict__ enc,
    float* __restrict__ h0p, float* __restrict__ h1p,
    float* __restrict__ cbuf, float* __restrict__ ctxb,
    unsigned short* __restrict__ oa, int* __restrict__ bar){
  extern __shared__ float sm[];
  float* w0s = sm;             // [8][516]   4128
  float* w1s = sm + 4128;      // [8][1028]  8224
  float* wcs = sm + 12352;     // [2][1028]  2056
  float* hst = sm + 14408;     // [32][516]  16512
  float* gs2 = sm + 30920;     // [32][8]    256
  float* rs  = sm + 31176;     // [2][32][4] 256
  float* ea  = sm + 31432;     // [128]
  float* red = sm + 31560;     // [8]
  const int bid = blockIdx.x, tid = threadIdx.x;

  // ---- load weight slices into LDS ----
  for (int i = tid; i < 8*128; i += 256){
    int rl = i >> 7, kb = i & 127;
    *(float4*)&w0s[rl*516 + kb*4] = *(const float4*)(WTp0 + ((size_t)kb*2048 + bid*8 + rl)*4);
  }
  for (int i = tid; i < 8*256; i += 256){
    int rl = i >> 8, kb = i & 255;
    *(float4*)&w1s[rl*1028 + kb*4] = *(const float4*)(WTp1 + ((size_t)kb*2048 + bid*8 + rl)*4);
  }
  for (int i = tid; i < 2*256; i += 256){
    int ul = i >> 8, kb = i & 255;
    *(float4*)&wcs[ul*1028 + kb*4] = *(const float4*)(WcTp + ((size_t)kb*512 + bid*2 + ul)*4);
  }
  const int b8 = tid >> 3, rl = tid & 7;
  const int aul = tid >> 7, alb = tid & 127, abb = alb >> 2, akq = alb & 3;
  float bs_i=0.f, bs_f=0.f, bs_g=0.f, bs_o=0.f, bcv=0.f;
  if (tid < 64){
    int u = bid*2 + (tid>>5);
    bs_i = bi1[u]        + bh1[u];
    bs_f = bi1[512+u]    + bh1[512+u];
    bs_g = bi1[1024+u]   + bh1[1024+u];
    bs_o = bi1[1536+u]   + bh1[1536+u];
    bcv  = bc[u];
  }
  __syncthreads();

  for (int t = 0; t < Tz; t++){
    const int rp = t & 1, wp = rp ^ 1;
    // ================= PHASE 1: L0(t) + attnB(t-2) =================
    for (int j = tid; j < 4096; j += 256){
      int row = j >> 7, c4 = (j & 127)*4;
      *(float4*)&hst[row*516 + c4] = *(const float4*)(h0p + rp*16384 + row*512 + c4);
    }
    __syncthreads();
    {
      const float4* wr = (const float4*)&w0s[rl*516];
      const float4* hr = (const float4*)&hst[b8*516];
      float acc = 0.f;
      #pragma unroll 8
      for (int kb = 0; kb < 128; kb++){
        float4 w = wr[kb], h = hr[kb];
        acc += w.x*h.x + w.y*h.y + w.z*h.z + w.w*h.w;
      }
      gs2[b8*8 + rl] = acc;
    }
    if (t >= 2) attnB_gemv(h1p + wp*16384, ctxb, wcs, rs, aul, abb, akq);
    __syncthreads();
    if (tid < 64){
      const int ul = tid >> 5, bb = tid & 31, u = bid*2 + ul;
      float4 gv = *(float4*)&gs2[bb*8 + ul*4];
      const float* xg = x0g + ((size_t)t*Bz + bb)*G4;
      float ai = gv.x + xg[u], af = gv.y + xg[512+u];
      float ag = gv.z + xg[1024+u], ao = gv.w + xg[1536+u];
      float* cp = cbuf + bb*512 + u;
      float cn = sigf(af)*cp[0] + sigf(ai)*tanhf(ag);
      cp[0] = cn;
      h0p[wp*16384 + bb*512 + u] = sigf(ao)*tanhf(cn);
      if (t >= 2) attnB_fin(rs, bcv, t-2, u, tid, oa);
    }
    gbar(bar);
    // ================= PHASE 2: L1(t) + attnA(t-1) =================
    for (int j = tid; j < 4096; j += 256){
      int row = j >> 7, c4 = (j & 127)*4;
      *(float4*)&hst[row*516 + c4] = *(const float4*)(h0p + wp*16384 + row*512 + c4);
    }
    __syncthreads();
    float acc1 = 0.f;
    {
      const float4* wr = (const float4*)&w1s[rl*1028];
      const float4* hr = (const float4*)&hst[b8*516];
      #pragma unroll 8
      for (int kb = 0; kb < 128; kb++){
        float4 w = wr[kb], h = hr[kb];
        acc1 += w.x*h.x + w.y*h.y + w.z*h.z + w.w*h.w;
      }
    }
    __syncthreads();          // done reading x-stage
    for (int j = tid; j < 4096; j += 256){
      int row = j >> 7, c4 = (j & 127)*4;
      *(float4*)&hst[row*516 + c4] = *(const float4*)(h1p + rp*16384 + row*512 + c4);
    }
    __syncthreads();
    {
      const float4* wr = (const float4*)&w1s[rl*1028 + 512];
      const float4* hr = (const float4*)&hst[b8*516];
      #pragma unroll 8
      for (int kb = 0; kb < 128; kb++){
        float4 w = wr[kb], h = hr[kb];
        acc1 += w.x*h.x + w.y*h.y + w.z*h.z + w.w*h.w;
      }
      gs2[b8*8 + rl] = acc1;
    }
    __syncthreads();
    if (tid < 64){
      const int ul = tid >> 5, bb = tid & 31, u = bid*2 + ul;
      float4 gv = *(float4*)&gs2[bb*8 + ul*4];
      float ai = gv.x + bs_i, af = gv.y + bs_f, ag = gv.z + bs_g, ao = gv.w + bs_o;
      float* cp = cbuf + 16384 + bb*512 + u;
      float cn = sigf(af)*cp[0] + sigf(ai)*tanhf(ag);
      cp[0] = cn;
      h1p[wp*16384 + bb*512 + u] = sigf(ao)*tanhf(cn);
    }
    if (bid < 32 && t >= 1)
      attn_A(bid, &hst[bid*516], enc, ea, red, ctxb, tid);   // h1(t-1) is staged in hst
    gbar(bar);
  }
  // ================= EPILOGUE =================
  // EP1: attnB(62), h1(62) in buffer 1
  attnB_gemv(h1p + 16384, ctxb, wcs, rs, aul, abb, akq);
  __syncthreads();
  if (tid < 64) attnB_fin(rs, bcv, 62, bid*2 + (tid>>5), tid, oa);
  gbar(bar);
  // EP2: attnA(63), h1(63) in buffer 0
  if (bid < 32){
    for (int j = tid; j < 4096; j += 256){
      int row = j >> 7, c4 = (j & 127)*4;
      *(float4*)&hst[row*516 + c4] = *(const float4*)(h1p + row*512 + c4);
    }
    __syncthreads();
    attn_A(bid, &hst[bid*516], enc, ea, red, ctxb, tid);
  }
  gbar(bar);
  // EP3: attnB(63)
  attnB_gemv(h1p, ctxb, wcs, rs, aul, abb, akq);
  __syncthreads();
  if (tid < 64) attnB_fin(rs, bcv, 63, bid*2 + (tid>>5), tid, oa);
}

// ---------------- pred GEMM: XCD-pinned + swizzled LDS ----------------
__global__ __launch_bounds__(256) void pred_gemm_v2(const unsigned short* __restrict__ A,
    const unsigned short* __restrict__ Bm, const float* __restrict__ bo,
    float* __restrict__ out){
  __shared__ unsigned short As[128*32];
  __shared__ unsigned short Bs[128*32];
  int bid = blockIdx.x;
  int xcd = bid & 7, lin = bid >> 3;
  int ntile = xcd*32 + (lin & 31);
  int mtile = lin >> 5;
  if (ntile >= 250) return;
  int n0 = ntile*128, m0 = mtile*128;
  int tid = threadIdx.x, lane = tid & 63, wid = tid >> 6;
  f32x4 acc[4][4];
  #pragma unroll
  for (int i = 0; i < 4; i++)
    #pragma unroll
    for (int j = 0; j < 4; j++)
      #pragma unroll
      for (int r = 0; r < 4; r++) acc[i][j][r] = 0.f;

  int wm = wid >> 1, wn = wid & 1;
  int r16 = lane & 15, kgr = lane >> 4;

  for (int kt = 0; kt < Hz/32; kt++){
    __syncthreads();
    #pragma unroll
    for (int call = 0; call < 2; call++){
      int c = call*256 + tid;
      int row = c >> 2, kg = c & 3;
      int kgs = kg ^ ((row >> 1) & 3);
      *(int4*)&As[row*32 + kgs*8] = *(const int4*)(A  + (size_t)(m0+row)*Hz + kt*32 + kg*8);
      *(int4*)&Bs[row*32 + kgs*8] = *(const int4*)(Bm + (size_t)(n0+row)*Hz + kt*32 + kg*8);
    }
    __syncthreads();
    bf16x8 aF[4], bF[4];
    #pragma unroll
    for (int i = 0; i < 4; i++){
      int ra = wm*64 + i*16 + r16;
      int rb = wn*64 + i*16 + r16;
      aF[i] = *(const bf16x8*)&As[ra*32 + (kgr ^ ((ra>>1)&3))*8];
      bF[i] = *(const bf16x8*)&Bs[rb*32 + (kgr ^ ((rb>>1)&3))*8];
    }
    #pragma unroll
    for (int i = 0; i < 4; i++)
      #pragma unroll
      for (int j = 0; j < 4; j++)
        acc[i][j] = __builtin_amdgcn_mfma_f32_16x16x32_bf16(aF[i], bF[j], acc[i][j], 0, 0, 0);
  }

  int rg = lane >> 4;
  #pragma unroll
  for (int i = 0; i < 4; i++)
    #pragma unroll
    for (int j = 0; j < 4; j++){
      int col = n0 + wn*64 + j*16 + r16;
      float bias = bo[col];
      #pragma unroll
      for (int r = 0; r < 4; r++){
        int row = m0 + wm*64 + i*16 + rg*4 + r;   // row = b*64 + t (A relaid out)
        out[(size_t)row*Vz + col] = acc[i][j][r] + bias;
      }
    }
}

// ---------------- final h,c copy ----------------
__global__ __launch_bounds__(256) void copy_hc_v2(const float* __restrict__ h0p,
    const float* __restrict__ h1p, const float* __restrict__ cbuf,
    float* __restrict__ out_hc){
  int i = blockIdx.x*256 + threadIdx.x;   // grid 256 -> 65536
  float v;
  if (i < 16384)      v = h0p[i];
  else if (i < 32768) v = h1p[i-16384];
  else                v = cbuf[i-32768];
  out_hc[i] = v;
}

extern "C" void kernel_launch(void* const* d_in, const int* in_sizes, int n_in,
                              void* d_out, int out_size, void* d_ws, size_t ws_size,
                              hipStream_t stream){
  const int*   tgt = (const int*)  d_in[0];
  const float* h0  = (const float*)d_in[1];
  const float* c0  = (const float*)d_in[2];
  const float* enc = (const float*)d_in[3];
  const float* emb = (const float*)d_in[4];
  const float* Wih = (const float*)d_in[5];
  const float* Whh = (const float*)d_in[6];
  const float* bih = (const float*)d_in[7];
  const float* bhh = (const float*)d_in[8];
  const float* Wc  = (const float*)d_in[9];
  const float* bc  = (const float*)d_in[10];
  const float* Wo  = (const float*)d_in[11];
  const float* bo  = (const float*)d_in[12];
  float* out = (float*)d_out;

  // workspace layout (floats)
  float* x0g  = (float*)d_ws;                 // 4,194,304
  float* h0p  = x0g  + 4194304;               // 32,768  ([2][32][512])
  float* h1p  = h0p  + 32768;                 // 32,768
  float* cbuf = h1p  + 32768;                 // 32,768  ([2][32][512])
  float* ctxb = cbuf + 32768;                 // 16,384  ([32][512])
  float* WTp0 = ctxb + 16384;                 // 1,048,576 (4MB)
  float* WTp1 = WTp0 + 1048576;               // 2,097,152 (8MB)
  float* WcTp = WTp1 + 2097152;               // 524,288 (2MB)
  int*   bar  = (int*)(WcTp + 524288);        // 16
  unsigned short* oa    = (unsigned short*)((float*)bar + 16);  // 1,048,576 us  [b][t][h]
  unsigned short* wo_bf = oa + 1048576;       // 16,384,000 us (32MB)

  const int DLDS_BYTES = 31568 * 4;           // 123.3 KB dynamic LDS
  hipFuncSetAttribute((const void*)decoder_persistent,
      hipFuncAttributeMaxDynamicSharedMemorySize, DLDS_BYTES);

  init_state_v2<<<128, 256, 0, stream>>>(h0, c0, h0p, h1p, cbuf, bar);
  conv_bf16_kernel<<<16000, 256, 0, stream>>>(Wo, wo_bf);
  pack_l0_kernel<<<1024, 256, 0, stream>>>(Whh, WTp0);
  pack_l1_kernel<<<2048, 256, 0, stream>>>(Wih + (size_t)G4*Hz, Whh + (size_t)G4*Hz, WTp1);
  pack_wc_kernel<<<512, 256, 0, stream>>>(Wc, WcTp);
  x0g_v2<<<dim3(32, 32), 256, 0, stream>>>(tgt, emb, Wih, bih, bhh, x0g);

  decoder_persistent<<<NBLK, 256, DLDS_BYTES, stream>>>(
      WTp0, WTp1, WcTp, x0g, bih + G4, bhh + G4, bc, enc,
      h0p, h1p, cbuf, ctxb, oa, bar);

  pred_gemm_v2<<<4096, 256, 0, stream>>>(oa, wo_bf, bo, out);
  copy_hc_v2<<<256, 256, 0, stream>>>(h0p, h1p, cbuf, out + (size_t)Bz*Tz*Vz);

  (void)in_sizes; (void)n_in; (void)out_size; (void)ws_size;
}

// Round 4
// 5281.668 us; speedup vs baseline: 1.8399x; 1.8399x over previous
//
#include <hip/hip_runtime.h>
#include <hip/hip_bf16.h>

#define Bz 32
#define Tz 64
#define Sz 128
#define Hz 512
#define Vz 32000
#define G4 2048
#define NBLK 256

#define A_RLX __ATOMIC_RELAXED
#define A_ACQ __ATOMIC_ACQUIRE
#define SC_AG __HIP_MEMORY_SCOPE_AGENT

using bf16x8 = __attribute__((ext_vector_type(8))) short;
using f32x4  = __attribute__((ext_vector_type(4))) float;

__device__ __forceinline__ unsigned short f2bf(float f){
  unsigned int u = __float_as_uint(f);
  u += 0x7fffu + ((u >> 16) & 1u);
  return (unsigned short)(u >> 16);
}
__device__ __forceinline__ float sigf(float x){ return 1.f/(1.f + expf(-x)); }

// coherent helpers: write-through store / agent-scope load
__device__ __forceinline__ void stc(float* p, float v){
  __hip_atomic_store(p, v, A_RLX, SC_AG);
}

// ---------------- grid barrier: tree arrive (relaxed), inv-only acquire ----------------
__device__ __forceinline__ void gbar(unsigned int* bar, int bid){
  asm volatile("s_waitcnt vmcnt(0)" ::: "memory");   // drain this thread's stores
  __syncthreads();                                    // all threads of block drained
  if (threadIdx.x == 0){
    unsigned g0 = __hip_atomic_load(&bar[1], A_RLX, SC_AG);
    if ((__hip_atomic_fetch_add(&bar[2 + (bid >> 4)], 1u, A_RLX, SC_AG) & 15u) == 15u){
      if ((__hip_atomic_fetch_add(&bar[0], 1u, A_RLX, SC_AG) & 15u) == 15u){
        __hip_atomic_fetch_add(&bar[1], 1u, A_RLX, SC_AG);
      }
    }
    while (__hip_atomic_load(&bar[1], A_RLX, SC_AG) == g0)
      __builtin_amdgcn_s_sleep(1);
  }
  __syncthreads();
  if ((threadIdx.x & 63) == 0)                         // one acquire (buffer_inv) per wave
    (void)__hip_atomic_load(&bar[1], A_ACQ, SC_AG);
  __builtin_amdgcn_sched_barrier(0);
  __syncthreads();
}

// ---------------- register transpose-reduce: 64 lanes x 32 accs -> lane holds b=lane&31 sum ----
__device__ __forceinline__ void xreduce(float (&a)[32], int lane){
  #pragma unroll
  for (int j = 0; j < 32; j++) a[j] += __shfl_xor(a[j], 32);
  #pragma unroll
  for (int st = 0; st < 5; st++){
    const int o = 16 >> st;          // 16,8,4,2,1 ; cnt/2 == o
    bool hi = (lane & o) != 0;
    float tmp[16];
    #pragma unroll
    for (int j = 0; j < o; j++){
      float lo_v = a[j], hi_v = a[j + o];
      float sent = hi ? lo_v : hi_v;         // value select => static reg indices
      float recv = __shfl_xor(sent, o);
      tmp[j] = (hi ? hi_v : lo_v) + recv;
    }
    #pragma unroll
    for (int j = 0; j < o; j++) a[j] = tmp[j];
  }
}

// ---------------- LDS h staging: 64KB, row pad 2 float4 ----------------
__device__ __forceinline__ void stage(float* hst, const float* src, int tid){
  const float4* s4 = (const float4*)src;
  float4* d4 = (float4*)hst;
  #pragma unroll
  for (int i = 0; i < 8; i++){
    int idx = tid + i*512;
    d4[idx + ((idx >> 7) << 1)] = s4[idx];
  }
}

// dense gemv accumulate: lane's K-slice (4 floats) x 2 rows over 32 batches
__device__ __forceinline__ void gemv_acc(const float4* hp, float4 WA, float4 WB,
                                         float (&a0)[32], float (&a1)[32]){
  #pragma unroll
  for (int b = 0; b < 32; b++){
    float4 hv = hp[b*130];
    a0[b] = fmaf(hv.x,WA.x, fmaf(hv.y,WA.y, fmaf(hv.z,WA.z, fmaf(hv.w,WA.w, a0[b]))));
    a1[b] = fmaf(hv.x,WB.x, fmaf(hv.y,WB.y, fmaf(hv.z,WB.z, fmaf(hv.w,WB.w, a1[b]))));
  }
}

// wc gemv accumulate: lane's single K-float x 2 rows over 32 batches
__device__ __forceinline__ void wc_acc(const float* hstf, float wA, float wB,
                                       float (&a0)[32], float (&a1)[32], int tid){
  #pragma unroll
  for (int b = 0; b < 32; b++){
    float hv = hstf[b*520 + tid];
    a0[b] = fmaf(hv, wA, a0[b]);
    a1[b] = fmaf(hv, wB, a1[b]);
  }
}

// ---------------- init ----------------
__global__ __launch_bounds__(256) void init_state_v3(const float* __restrict__ h0,
    const float* __restrict__ c0, float* __restrict__ h0p, float* __restrict__ h1p,
    float* __restrict__ cbuf, unsigned int* __restrict__ bar){
  int i = blockIdx.x*256 + threadIdx.x;   // grid 128 -> 32768
  if (i < 16384) h0p[i] = h0[i];
  else           h1p[2*16384 + (i - 16384)] = h0[i];   // h1 initial -> slot 2 (= (-1)%3)
  cbuf[i] = c0[i];
  if (i < 32) bar[i] = 0u;
}

// ---------------- Wo -> bf16 ----------------
__global__ __launch_bounds__(256) void conv_bf16_kernel(const float* __restrict__ src,
    unsigned short* __restrict__ dst){
  int i = (blockIdx.x*256 + threadIdx.x)*4;
  float4 v = *(const float4*)(src + i);
  ushort4 o;
  o.x = f2bf(v.x); o.y = f2bf(v.y); o.z = f2bf(v.z); o.w = f2bf(v.w);
  *(ushort4*)(dst + i) = o;
}

// ---------------- weight packs: row-major, rows r = u*4+gate ----------------
__global__ __launch_bounds__(256) void pack_l0_v3(const float* __restrict__ W,
    float* __restrict__ out){
  int idx4 = blockIdx.x*256 + threadIdx.x;    // 1024 blocks -> 262144 f4
  int r = idx4 >> 7, k4 = idx4 & 127;
  int srow = (r & 3)*Hz + (r >> 2);
  ((float4*)out)[idx4] = ((const float4*)W)[srow*128 + k4];
}
__global__ __launch_bounds__(256) void pack_l1_v3(const float* __restrict__ Wi,
    const float* __restrict__ Wh, float* __restrict__ out){
  int idx4 = blockIdx.x*256 + threadIdx.x;    // 2048 blocks -> 524288 f4
  int r = idx4 >> 8, k4 = idx4 & 255;
  int srow = (r & 3)*Hz + (r >> 2);
  float4 v = (k4 < 128) ? ((const float4*)Wi)[srow*128 + k4]
                        : ((const float4*)Wh)[srow*128 + (k4 - 128)];
  ((float4*)out)[idx4] = v;
}

// ---------------- x0g: tiled fp32 GEMM ----------------
__global__ __launch_bounds__(256) void x0g_v2(const int* __restrict__ tgt,
    const float* __restrict__ emb, const float* __restrict__ W,
    const float* __restrict__ bi, const float* __restrict__ bh,
    float* __restrict__ out){
  __shared__ float As[32][68], Bs[32][68];
  __shared__ int tok_s[64];
  int tid = threadIdx.x;
  int m0 = blockIdx.y*64, n0 = blockIdx.x*64;
  if (tid < 64){ int tb = m0 + tid; tok_s[tid] = tgt[(tb & 31)*Tz + (tb >> 5)]; }
  __syncthreads();
  int lm = tid >> 2, lk = (tid & 3)*8;
  int ty = tid >> 4, tx = tid & 15;
  float acc[4][4] = {{0.f}};
  for (int kt = 0; kt < 16; kt++){
    float4 a0 = *(const float4*)(emb + (size_t)tok_s[lm]*Hz + kt*32 + lk);
    float4 a1 = *(const float4*)(emb + (size_t)tok_s[lm]*Hz + kt*32 + lk + 4);
    float4 b0 = *(const float4*)(W   + (size_t)(n0+lm)*Hz + kt*32 + lk);
    float4 b1 = *(const float4*)(W   + (size_t)(n0+lm)*Hz + kt*32 + lk + 4);
    __syncthreads();
    As[lk+0][lm]=a0.x; As[lk+1][lm]=a0.y; As[lk+2][lm]=a0.z; As[lk+3][lm]=a0.w;
    As[lk+4][lm]=a1.x; As[lk+5][lm]=a1.y; As[lk+6][lm]=a1.z; As[lk+7][lm]=a1.w;
    Bs[lk+0][lm]=b0.x; Bs[lk+1][lm]=b0.y; Bs[lk+2][lm]=b0.z; Bs[lk+3][lm]=b0.w;
    Bs[lk+4][lm]=b1.x; Bs[lk+5][lm]=b1.y; Bs[lk+6][lm]=b1.z; Bs[lk+7][lm]=b1.w;
    __syncthreads();
    #pragma unroll
    for (int k = 0; k < 32; k++){
      float4 av = *(const float4*)&As[k][ty*4];
      float4 bv = *(const float4*)&Bs[k][tx*4];
      acc[0][0]+=av.x*bv.x; acc[0][1]+=av.x*bv.y; acc[0][2]+=av.x*bv.z; acc[0][3]+=av.x*bv.w;
      acc[1][0]+=av.y*bv.x; acc[1][1]+=av.y*bv.y; acc[1][2]+=av.y*bv.z; acc[1][3]+=av.y*bv.w;
      acc[2][0]+=av.z*bv.x; acc[2][1]+=av.z*bv.y; acc[2][2]+=av.z*bv.z; acc[2][3]+=av.z*bv.w;
      acc[3][0]+=av.w*bv.x; acc[3][1]+=av.w*bv.y; acc[3][2]+=av.w*bv.z; acc[3][3]+=av.w*bv.w;
    }
  }
  #pragma unroll
  for (int j = 0; j < 4; j++){
    int col = n0 + tx*4 + j;
    float bias = bi[col] + bh[col];
    #pragma unroll
    for (int i = 0; i < 4; i++)
      out[(size_t)(m0 + ty*4 + i)*G4 + col] = acc[i][j] + bias;
  }
}

// ---------------- persistent decoder v3: weights in VGPRs ----------------
__global__ __launch_bounds__(512, 2) void decoder_persist_v3(
    const float* __restrict__ Wp0, const float* __restrict__ Wp1,
    const float* __restrict__ Wc,  const float* __restrict__ x0g,
    const float* __restrict__ bi1, const float* __restrict__ bh1,
    const float* __restrict__ bc,  const float* __restrict__ enc,
    float* __restrict__ h0p, float* __restrict__ h1p,
    float* __restrict__ cbuf, float* __restrict__ ctxb,
    unsigned int* __restrict__ oa32, unsigned int* __restrict__ bar){
  extern __shared__ float sm[];
  float* hst = sm;                 // [32][520]  16640 f
  float* gs  = sm + 16640;         // [2][8][32]   512 f
  float* gsw = gs + 512;           // [8][2][32]   512 f
  float* ea  = gsw + 512;          // [128]
  float* red = ea + 128;           // [8]
  float4* hst4 = (float4*)hst;

  const int bid = blockIdx.x, tid = threadIdx.x;
  const int w4 = tid >> 6, lane = tid & 63;
  const int kh = w4 >> 2, rpair = w4 & 3;
  const int r0 = bid*8 + rpair*2, r1 = r0 + 1;
  const int u0 = bid*2, u1 = u0 + 1;

  // ---- persistent weights -> VGPRs ----
  const float4* Wp0_4 = (const float4*)Wp0;
  const float4* Wp1_4 = (const float4*)Wp1;
  float4 w0A  = Wp0_4[r0*128 + kh*64 + lane];
  float4 w0B  = Wp0_4[r1*128 + kh*64 + lane];
  float4 w1xA = Wp1_4[r0*256 +       kh*64 + lane];
  float4 w1xB = Wp1_4[r1*256 +       kh*64 + lane];
  float4 w1hA = Wp1_4[r0*256 + 128 + kh*64 + lane];
  float4 w1hB = Wp1_4[r1*256 + 128 + kh*64 + lane];
  float wcA0 = Wc[(size_t)u0*1024 + tid];
  float wcB0 = Wc[(size_t)u1*1024 + tid];
  float wcA1 = Wc[(size_t)u0*1024 + 512 + tid];
  float wcB1 = Wc[(size_t)u1*1024 + 512 + tid];
  float bs_i=0.f, bs_f=0.f, bs_g=0.f, bs_o=0.f, bcv=0.f;
  if (tid < 64){
    int u = bid*2 + (tid >> 5);
    bs_i = bi1[u]        + bh1[u];
    bs_f = bi1[512+u]    + bh1[512+u];
    bs_g = bi1[1024+u]   + bh1[1024+u];
    bs_o = bi1[1536+u]   + bh1[1536+u];
    bcv  = bc[u];
  }
  __syncthreads();

  for (int t = 0; t < Tz; t++){
    const int rp = t & 1, wp = rp ^ 1;
    // ============ PHASE 1: l0(t)  +  attnB(t-2) ============
    stage(hst, h0p + rp*16384, tid);
    __syncthreads();
    {
      float a0[32], a1[32];
      #pragma unroll
      for (int b = 0; b < 32; b++){ a0[b] = 0.f; a1[b] = 0.f; }
      gemv_acc(hst4 + kh*64 + lane, w0A, w0B, a0, a1);
      xreduce(a0, lane); xreduce(a1, lane);
      int bb = lane & 31;
      gs[kh*256 + (rpair*2 + (lane >= 32 ? 1 : 0))*32 + bb] = (lane < 32) ? a0[0] : a1[0];
    }
    __syncthreads();
    if (tid < 64){
      int ul = tid >> 5, b = tid & 31, u = bid*2 + ul;
      int rl = ul*4;
      const float* xg = x0g + ((size_t)t*Bz + b)*G4;
      float gi = gs[(rl+0)*32+b] + gs[256+(rl+0)*32+b] + xg[u];
      float gf = gs[(rl+1)*32+b] + gs[256+(rl+1)*32+b] + xg[512+u];
      float gg = gs[(rl+2)*32+b] + gs[256+(rl+2)*32+b] + xg[1024+u];
      float go = gs[(rl+3)*32+b] + gs[256+(rl+3)*32+b] + xg[1536+u];
      float cn = sigf(gf)*cbuf[b*512 + u] + sigf(gi)*tanhf(gg);
      stc(cbuf + b*512 + u, cn);
      stc(h0p + wp*16384 + b*512 + u, sigf(go)*tanhf(cn));
    }
    if (t >= 2){
      const int tt = t - 2;
      __syncthreads();                       // cell done? (hst reads were already done; keep order clean)
      stage(hst, h1p + (tt % 3)*16384, tid);
      __syncthreads();
      float a0[32], a1[32];
      #pragma unroll
      for (int b = 0; b < 32; b++){ a0[b] = 0.f; a1[b] = 0.f; }
      wc_acc(hst, wcA0, wcB0, a0, a1, tid);
      __syncthreads();
      stage(hst, ctxb, tid);
      __syncthreads();
      wc_acc(hst, wcA1, wcB1, a0, a1, tid);
      xreduce(a0, lane); xreduce(a1, lane);
      int bb = lane & 31;
      gsw[w4*64 + (lane >= 32 ? 32 : 0) + bb] = (lane < 32) ? a0[0] : a1[0];
      __syncthreads();
      if (tid < 64){
        int ul = tid >> 5, b = tid & 31;
        float s = bcv;
        #pragma unroll
        for (int w = 0; w < 8; w++) s += gsw[w*64 + ul*32 + b];
        unsigned short me = f2bf(tanhf(s));
        unsigned other = (unsigned)__shfl((int)(unsigned)me, tid + 32);
        if (tid < 32)
          __hip_atomic_store(oa32 + ((size_t)b*Tz + tt)*256 + bid,
                             ((unsigned)me) | (other << 16), A_RLX, SC_AG);
      }
    }
    gbar(bar, bid);
    // ============ PHASE 2: l1(t)  +  attnA(t-1) ============
    stage(hst, h0p + wp*16384, tid);
    __syncthreads();
    {
      float a0[32], a1[32];
      #pragma unroll
      for (int b = 0; b < 32; b++){ a0[b] = 0.f; a1[b] = 0.f; }
      gemv_acc(hst4 + kh*64 + lane, w1xA, w1xB, a0, a1);
      __syncthreads();                       // done reading x-stage
      stage(hst, h1p + ((t + 2) % 3)*16384, tid);   // h1(t-1)
      __syncthreads();
      gemv_acc(hst4 + kh*64 + lane, w1hA, w1hB, a0, a1);
      xreduce(a0, lane); xreduce(a1, lane);
      int bb = lane & 31;
      gs[kh*256 + (rpair*2 + (lane >= 32 ? 1 : 0))*32 + bb] = (lane < 32) ? a0[0] : a1[0];
    }
    __syncthreads();
    if (tid < 64){
      int ul = tid >> 5, b = tid & 31, u = bid*2 + ul;
      int rl = ul*4;
      float gi = gs[(rl+0)*32+b] + gs[256+(rl+0)*32+b] + bs_i;
      float gf = gs[(rl+1)*32+b] + gs[256+(rl+1)*32+b] + bs_f;
      float gg = gs[(rl+2)*32+b] + gs[256+(rl+2)*32+b] + bs_g;
      float go = gs[(rl+3)*32+b] + gs[256+(rl+3)*32+b] + bs_o;
      float cn = sigf(gf)*cbuf[16384 + b*512 + u] + sigf(gi)*tanhf(gg);
      stc(cbuf + 16384 + b*512 + u, cn);
      stc(h1p + (t % 3)*16384 + b*512 + u, sigf(go)*tanhf(cn));
    }
    if (bid < 32 && t >= 1){
      // hst still holds h1(t-1) for all 32 b
      {
        int s = tid >> 2, q = tid & 3;
        const float4* e4 = (const float4*)(enc + ((size_t)bid*Sz + s)*Hz) + q*32;
        const float4* h4 = hst4 + bid*130 + q*32;
        float a = 0.f;
        #pragma unroll 8
        for (int i = 0; i < 32; i++){
          float4 e = e4[i], h = h4[i];
          a += e.x*h.x + e.y*h.y + e.z*h.z + e.w*h.w;
        }
        a += __shfl_xor(a, 1); a += __shfl_xor(a, 2);
        if (q == 0) ea[s] = a;
      }
      __syncthreads();
      if (tid < 64){
        float v = fmaxf(ea[tid], ea[tid+64]);
        #pragma unroll
        for (int o = 32; o; o >>= 1) v = fmaxf(v, __shfl_xor(v, o));
        if (tid == 0) red[0] = v;
      }
      __syncthreads();
      if (tid < 128) ea[tid] = expf(ea[tid] - red[0]);
      __syncthreads();
      if (tid < 64){
        float v = ea[tid] + ea[tid+64];
        #pragma unroll
        for (int o = 32; o; o >>= 1) v += __shfl_xor(v, o);
        if (tid == 0) red[1] = v;
      }
      __syncthreads();
      {
        float inv = 1.f/red[1];
        float c = 0.f;
        const float* ep = enc + (size_t)bid*Sz*Hz + tid;
        #pragma unroll 4
        for (int s = 0; s < Sz; s++) c = fmaf(ea[s], ep[(size_t)s*Hz], c);
        stc(ctxb + bid*512 + tid, c*inv);
      }
    }
    gbar(bar, bid);
  }
  // ============ EPILOGUE ============
  // E1: attnB(62)  (h1(62) in slot 62%3=2, ctx(62) written at P2 of t=63)
  {
    const int tt = 62;
    stage(hst, h1p + (tt % 3)*16384, tid);
    __syncthreads();
    float a0[32], a1[32];
    #pragma unroll
    for (int b = 0; b < 32; b++){ a0[b] = 0.f; a1[b] = 0.f; }
    wc_acc(hst, wcA0, wcB0, a0, a1, tid);
    __syncthreads();
    stage(hst, ctxb, tid);
    __syncthreads();
    wc_acc(hst, wcA1, wcB1, a0, a1, tid);
    xreduce(a0, lane); xreduce(a1, lane);
    int bb = lane & 31;
    gsw[w4*64 + (lane >= 32 ? 32 : 0) + bb] = (lane < 32) ? a0[0] : a1[0];
    __syncthreads();
    if (tid < 64){
      int ul = tid >> 5, b = tid & 31;
      float s = bcv;
      #pragma unroll
      for (int w = 0; w < 8; w++) s += gsw[w*64 + ul*32 + b];
      unsigned short me = f2bf(tanhf(s));
      unsigned other = (unsigned)__shfl((int)(unsigned)me, tid + 32);
      if (tid < 32)
        __hip_atomic_store(oa32 + ((size_t)b*Tz + tt)*256 + bid,
                           ((unsigned)me) | (other << 16), A_RLX, SC_AG);
    }
  }
  gbar(bar, bid);
  // E2: attnA(63) (h1(63) in slot 0)
  if (bid < 32){
    stage(hst, h1p + 0*16384, tid);
    __syncthreads();
    {
      int s = tid >> 2, q = tid & 3;
      const float4* e4 = (const float4*)(enc + ((size_t)bid*Sz + s)*Hz) + q*32;
      const float4* h4 = hst4 + bid*130 + q*32;
      float a = 0.f;
      #pragma unroll 8
      for (int i = 0; i < 32; i++){
        float4 e = e4[i], h = h4[i];
        a += e.x*h.x + e.y*h.y + e.z*h.z + e.w*h.w;
      }
      a += __shfl_xor(a, 1); a += __shfl_xor(a, 2);
      if (q == 0) ea[s] = a;
    }
    __syncthreads();
    if (tid < 64){
      float v = fmaxf(ea[tid], ea[tid+64]);
      #pragma unroll
      for (int o = 32; o; o >>= 1) v = fmaxf(v, __shfl_xor(v, o));
      if (tid == 0) red[0] = v;
    }
    __syncthreads();
    if (tid < 128) ea[tid] = expf(ea[tid] - red[0]);
    __syncthreads();
    if (tid < 64){
      float v = ea[tid] + ea[tid+64];
      #pragma unroll
      for (int o = 32; o; o >>= 1) v += __shfl_xor(v, o);
      if (tid == 0) red[1] = v;
    }
    __syncthreads();
    {
      float inv = 1.f/red[1];
      float c = 0.f;
      const float* ep = enc + (size_t)bid*Sz*Hz + tid;
      #pragma unroll 4
      for (int s = 0; s < Sz; s++) c = fmaf(ea[s], ep[(size_t)s*Hz], c);
      stc(ctxb + bid*512 + tid, c*inv);
    }
  }
  gbar(bar, bid);
  // E3: attnB(63) (h1(63) slot 0, ctx(63) fresh)
  {
    const int tt = 63;
    stage(hst, h1p + 0*16384, tid);
    __syncthreads();
    float a0[32], a1[32];
    #pragma unroll
    for (int b = 0; b < 32; b++){ a0[b] = 0.f; a1[b] = 0.f; }
    wc_acc(hst, wcA0, wcB0, a0, a1, tid);
    __syncthreads();
    stage(hst, ctxb, tid);
    __syncthreads();
    wc_acc(hst, wcA1, wcB1, a0, a1, tid);
    xreduce(a0, lane); xreduce(a1, lane);
    int bb = lane & 31;
    gsw[w4*64 + (lane >= 32 ? 32 : 0) + bb] = (lane < 32) ? a0[0] : a1[0];
    __syncthreads();
    if (tid < 64){
      int ul = tid >> 5, b = tid & 31;
      float s = bcv;
      #pragma unroll
      for (int w = 0; w < 8; w++) s += gsw[w*64 + ul*32 + b];
      unsigned short me = f2bf(tanhf(s));
      unsigned other = (unsigned)__shfl((int)(unsigned)me, tid + 32);
      if (tid < 32)
        __hip_atomic_store(oa32 + ((size_t)b*Tz + tt)*256 + bid,
                           ((unsigned)me) | (other << 16), A_RLX, SC_AG);
    }
  }
}

// ---------------- pred GEMM: XCD-pinned + swizzled LDS ----------------
__global__ __launch_bounds__(256) void pred_gemm_v2(const unsigned short* __restrict__ A,
    const unsigned short* __restrict__ Bm, const float* __restrict__ bo,
    float* __restrict__ out){
  __shared__ unsigned short As[128*32];
  __shared__ unsigned short Bs[128*32];
  int bid = blockIdx.x;
  int xcd = bid & 7, lin = bid >> 3;
  int ntile = xcd*32 + (lin & 31);
  int mtile = lin >> 5;
  if (ntile >= 250) return;
  int n0 = ntile*128, m0 = mtile*128;
  int tid = threadIdx.x, lane = tid & 63, wid = tid >> 6;
  f32x4 acc[4][4];
  #pragma unroll
  for (int i = 0; i < 4; i++)
    #pragma unroll
    for (int j = 0; j < 4; j++)
      #pragma unroll
      for (int r = 0; r < 4; r++) acc[i][j][r] = 0.f;

  int wm = wid >> 1, wn = wid & 1;
  int r16 = lane & 15, kgr = lane >> 4;

  for (int kt = 0; kt < Hz/32; kt++){
    __syncthreads();
    #pragma unroll
    for (int call = 0; call < 2; call++){
      int c = call*256 + tid;
      int row = c >> 2, kg = c & 3;
      int kgs = kg ^ ((row >> 1) & 3);
      *(int4*)&As[row*32 + kgs*8] = *(const int4*)(A  + (size_t)(m0+row)*Hz + kt*32 + kg*8);
      *(int4*)&Bs[row*32 + kgs*8] = *(const int4*)(Bm + (size_t)(n0+row)*Hz + kt*32 + kg*8);
    }
    __syncthreads();
    bf16x8 aF[4], bF[4];
    #pragma unroll
    for (int i = 0; i < 4; i++){
      int ra = wm*64 + i*16 + r16;
      int rb = wn*64 + i*16 + r16;
      aF[i] = *(const bf16x8*)&As[ra*32 + (kgr ^ ((ra>>1)&3))*8];
      bF[i] = *(const bf16x8*)&Bs[rb*32 + (kgr ^ ((rb>>1)&3))*8];
    }
    #pragma unroll
    for (int i = 0; i < 4; i++)
      #pragma unroll
      for (int j = 0; j < 4; j++)
        acc[i][j] = __builtin_amdgcn_mfma_f32_16x16x32_bf16(aF[i], bF[j], acc[i][j], 0, 0, 0);
  }

  int rg = lane >> 4;
  #pragma unroll
  for (int i = 0; i < 4; i++)
    #pragma unroll
    for (int j = 0; j < 4; j++){
      int col = n0 + wn*64 + j*16 + r16;
      float bias = bo[col];
      #pragma unroll
      for (int r = 0; r < 4; r++){
        int row = m0 + wm*64 + i*16 + rg*4 + r;   // row = b*64 + t
        out[(size_t)row*Vz + col] = acc[i][j][r] + bias;
      }
    }
}

// ---------------- final h,c copy ----------------
__global__ __launch_bounds__(256) void copy_hc_v2(const float* __restrict__ h0p,
    const float* __restrict__ h1p, const float* __restrict__ cbuf,
    float* __restrict__ out_hc){
  int i = blockIdx.x*256 + threadIdx.x;   // grid 256 -> 65536
  float v;
  if (i < 16384)      v = h0p[i];
  else if (i < 32768) v = h1p[i-16384];
  else                v = cbuf[i-32768];
  out_hc[i] = v;
}

extern "C" void kernel_launch(void* const* d_in, const int* in_sizes, int n_in,
                              void* d_out, int out_size, void* d_ws, size_t ws_size,
                              hipStream_t stream){
  const int*   tgt = (const int*)  d_in[0];
  const float* h0  = (const float*)d_in[1];
  const float* c0  = (const float*)d_in[2];
  const float* enc = (const float*)d_in[3];
  const float* emb = (const float*)d_in[4];
  const float* Wih = (const float*)d_in[5];
  const float* Whh = (const float*)d_in[6];
  const float* bih = (const float*)d_in[7];
  const float* bhh = (const float*)d_in[8];
  const float* Wc  = (const float*)d_in[9];
  const float* bc  = (const float*)d_in[10];
  const float* Wo  = (const float*)d_in[11];
  const float* bo  = (const float*)d_in[12];
  float* out = (float*)d_out;

  // workspace layout (floats)
  float* x0g  = (float*)d_ws;                 // 4,194,304
  float* h0p  = x0g  + 4194304;               // 32,768  [2][32][512]
  float* h1p  = h0p  + 32768;                 // 49,152  [3][32][512]
  float* cbuf = h1p  + 49152;                 // 32,768  [2][32][512]
  float* ctxb = cbuf + 32768;                 // 16,384  [32][512]
  float* Wp0  = ctxb + 16384;                 // 1,048,576
  float* Wp1  = Wp0  + 1048576;               // 2,097,152
  unsigned int* bar = (unsigned int*)(Wp1 + 2097152);           // 32
  unsigned short* oa    = (unsigned short*)(bar + 32);          // 1,048,576 us  [b][t][u]
  unsigned short* wo_bf = oa + 1048576;       // 16,384,000 us (32MB)

  const int DLDS_BYTES = 17800 * 4;           // 71.2 KB dynamic LDS
  hipFuncSetAttribute((const void*)decoder_persist_v3,
      hipFuncAttributeMaxDynamicSharedMemorySize, DLDS_BYTES);

  init_state_v3<<<128, 256, 0, stream>>>(h0, c0, h0p, h1p, cbuf, bar);
  conv_bf16_kernel<<<16000, 256, 0, stream>>>(Wo, wo_bf);
  pack_l0_v3<<<1024, 256, 0, stream>>>(Whh, Wp0);
  pack_l1_v3<<<2048, 256, 0, stream>>>(Wih + (size_t)G4*Hz, Whh + (size_t)G4*Hz, Wp1);
  x0g_v2<<<dim3(32, 32), 256, 0, stream>>>(tgt, emb, Wih, bih, bhh, x0g);

  decoder_persist_v3<<<NBLK, 512, DLDS_BYTES, stream>>>(
      Wp0, Wp1, Wc, x0g, bih + G4, bhh + G4, bc, enc,
      h0p, h1p, cbuf, ctxb, (unsigned int*)oa, bar);

  pred_gemm_v2<<<4096, 256, 0, stream>>>(oa, wo_bf, bo, out);
  copy_hc_v2<<<256, 256, 0, stream>>>(h0p, h1p, cbuf, out + (size_t)Bz*Tz*Vz);

  (void)in_sizes; (void)n_in; (void)out_size; (void)ws_size;
}

// Round 5
// 4403.590 us; speedup vs baseline: 2.2068x; 1.1994x over previous
//
#include <hip/hip_runtime.h>
#include <hip/hip_bf16.h>

#define Bz 32
#define Tz 64
#define Sz 128
#define Hz 512
#define Vz 32000
#define G4 2048
#define NBLK 256

#define A_RLX __ATOMIC_RELAXED
#define A_ACQ __ATOMIC_ACQUIRE
#define SC_AG __HIP_MEMORY_SCOPE_AGENT

using bf16x8 = __attribute__((ext_vector_type(8))) short;
using f32x4  = __attribute__((ext_vector_type(4))) float;

__device__ __forceinline__ unsigned short f2bf(float f){
  unsigned int u = __float_as_uint(f);
  u += 0x7fffu + ((u >> 16) & 1u);
  return (unsigned short)(u >> 16);
}
__device__ __forceinline__ float sigf(float x){ return 1.f/(1.f + expf(-x)); }

__device__ __forceinline__ void stc(float* p, float v){
  __hip_atomic_store(p, v, A_RLX, SC_AG);
}

// ---------------- grid barrier: 16 groups x 16 blocks, spread cachelines ----------------
// layout (uint words): arr[g] @ g*16 (g<16) ; root @ 256 ; rel[g] @ 272+g*16  -> 528 words
__device__ __forceinline__ void gbar(unsigned int* bar, int bid, unsigned int* ep){
  asm volatile("s_waitcnt vmcnt(0)" ::: "memory");   // drain this thread's stores
  __syncthreads();
  const unsigned e = ++(*ep);
  if (threadIdx.x == 0){
    const int g = bid >> 4;
    unsigned int* arr  = bar + g*16;
    unsigned int* root = bar + 256;
    unsigned int* rel  = bar + 272 + g*16;
    if ((__hip_atomic_fetch_add(arr, 1u, A_RLX, SC_AG) & 15u) == 15u){
      if ((__hip_atomic_fetch_add(root, 1u, A_RLX, SC_AG) & 15u) == 15u){
        #pragma unroll
        for (int g2 = 0; g2 < 16; g2++)
          __hip_atomic_store(bar + 272 + g2*16, e, A_RLX, SC_AG);
      }
    }
    while (__hip_atomic_load(rel, A_RLX, SC_AG) != e)
      __builtin_amdgcn_s_sleep(4);
  }
  __syncthreads();
  if ((threadIdx.x & 63) == 0)                       // one acquire (inv) per wave
    (void)__hip_atomic_load(bar + 272, A_ACQ, SC_AG);
  __builtin_amdgcn_sched_barrier(0);
  __syncthreads();
}

// ---------------- register transpose-reduce: 64 lanes x 32 accs -> lane holds b=lane&31 sum ----
__device__ __forceinline__ void xreduce(float (&a)[32], int lane){
  #pragma unroll
  for (int j = 0; j < 32; j++) a[j] += __shfl_xor(a[j], 32);
  #pragma unroll
  for (int st = 0; st < 5; st++){
    const int o = 16 >> st;
    bool hi = (lane & o) != 0;
    float tmp[16];
    #pragma unroll
    for (int j = 0; j < o; j++){
      float lo_v = a[j], hi_v = a[j + o];
      float sent = hi ? lo_v : hi_v;
      float recv = __shfl_xor(sent, o);
      tmp[j] = (hi ? hi_v : lo_v) + recv;
    }
    #pragma unroll
    for (int j = 0; j < o; j++) a[j] = tmp[j];
  }
}

// ---------------- LDS h staging ----------------
__device__ __forceinline__ void stage(float* dst, const float* src, int tid){
  const float4* s4 = (const float4*)src;
  float4* d4 = (float4*)dst;
  #pragma unroll
  for (int i = 0; i < 8; i++){
    int idx = tid + i*512;
    d4[idx + ((idx >> 7) << 1)] = s4[idx];
  }
}
// dual stage: issue all 16 loads before LDS writes (one L3 latency)
__device__ __forceinline__ void stage2(float* dA, const float* sA,
                                       float* dB, const float* sB, int tid){
  const float4* a4 = (const float4*)sA;
  const float4* b4 = (const float4*)sB;
  float4 ra[8], rb[8];
  #pragma unroll
  for (int i = 0; i < 8; i++) ra[i] = a4[tid + i*512];
  #pragma unroll
  for (int i = 0; i < 8; i++) rb[i] = b4[tid + i*512];
  float4* dA4 = (float4*)dA; float4* dB4 = (float4*)dB;
  #pragma unroll
  for (int i = 0; i < 8; i++){ int idx = tid + i*512; dA4[idx + ((idx >> 7) << 1)] = ra[i]; }
  #pragma unroll
  for (int i = 0; i < 8; i++){ int idx = tid + i*512; dB4[idx + ((idx >> 7) << 1)] = rb[i]; }
}

// dense gemv accumulate: lane's K-slice (float4) x 2 rows over 32 batches
__device__ __forceinline__ void gemv_acc(const float4* hp, float4 WA, float4 WB,
                                         float (&a0)[32], float (&a1)[32]){
  #pragma unroll
  for (int b = 0; b < 32; b++){
    float4 hv = hp[b*130];
    a0[b] = fmaf(hv.x,WA.x, fmaf(hv.y,WA.y, fmaf(hv.z,WA.z, fmaf(hv.w,WA.w, a0[b]))));
    a1[b] = fmaf(hv.x,WB.x, fmaf(hv.y,WB.y, fmaf(hv.z,WB.z, fmaf(hv.w,WB.w, a1[b]))));
  }
}
// wc gemv accumulate: lane's single K-float x 2 rows over 32 batches
__device__ __forceinline__ void wc_acc(const float* hstf, float wA, float wB,
                                       float (&a0)[32], float (&a1)[32], int tid){
  #pragma unroll
  for (int b = 0; b < 32; b++){
    float hv = hstf[b*520 + tid];
    a0[b] = fmaf(hv, wA, a0[b]);
    a1[b] = fmaf(hv, wB, a1[b]);
  }
}

// ---------------- init ----------------
__global__ __launch_bounds__(256) void init_state_v4(const float* __restrict__ h0,
    float* __restrict__ h0p, float* __restrict__ h1p, unsigned int* __restrict__ bar){
  int i = blockIdx.x*256 + threadIdx.x;   // grid 128 -> 32768
  if (i < 16384) h0p[i] = h0[i];
  else           h1p[2*16384 + (i - 16384)] = h0[i];   // h1 initial -> slot 2
  if (i < 528) bar[i] = 0u;
}

// ---------------- Wo -> bf16 ----------------
__global__ __launch_bounds__(256) void conv_bf16_kernel(const float* __restrict__ src,
    unsigned short* __restrict__ dst){
  int i = (blockIdx.x*256 + threadIdx.x)*4;
  float4 v = *(const float4*)(src + i);
  ushort4 o;
  o.x = f2bf(v.x); o.y = f2bf(v.y); o.z = f2bf(v.z); o.w = f2bf(v.w);
  *(ushort4*)(dst + i) = o;
}

// ---------------- weight packs: row-major, rows r = u*4+gate ----------------
__global__ __launch_bounds__(256) void pack_l0_v3(const float* __restrict__ W,
    float* __restrict__ out){
  int idx4 = blockIdx.x*256 + threadIdx.x;
  int r = idx4 >> 7, k4 = idx4 & 127;
  int srow = (r & 3)*Hz + (r >> 2);
  ((float4*)out)[idx4] = ((const float4*)W)[srow*128 + k4];
}
__global__ __launch_bounds__(256) void pack_l1_v3(const float* __restrict__ Wi,
    const float* __restrict__ Wh, float* __restrict__ out){
  int idx4 = blockIdx.x*256 + threadIdx.x;
  int r = idx4 >> 8, k4 = idx4 & 255;
  int srow = (r & 3)*Hz + (r >> 2);
  float4 v = (k4 < 128) ? ((const float4*)Wi)[srow*128 + k4]
                        : ((const float4*)Wh)[srow*128 + (k4 - 128)];
  ((float4*)out)[idx4] = v;
}

// ---------------- x0g: tiled fp32 GEMM ----------------
__global__ __launch_bounds__(256) void x0g_v2(const int* __restrict__ tgt,
    const float* __restrict__ emb, const float* __restrict__ W,
    const float* __restrict__ bi, const float* __restrict__ bh,
    float* __restrict__ out){
  __shared__ float As[32][68], Bs[32][68];
  __shared__ int tok_s[64];
  int tid = threadIdx.x;
  int m0 = blockIdx.y*64, n0 = blockIdx.x*64;
  if (tid < 64){ int tb = m0 + tid; tok_s[tid] = tgt[(tb & 31)*Tz + (tb >> 5)]; }
  __syncthreads();
  int lm = tid >> 2, lk = (tid & 3)*8;
  int ty = tid >> 4, tx = tid & 15;
  float acc[4][4] = {{0.f}};
  for (int kt = 0; kt < 16; kt++){
    float4 a0 = *(const float4*)(emb + (size_t)tok_s[lm]*Hz + kt*32 + lk);
    float4 a1 = *(const float4*)(emb + (size_t)tok_s[lm]*Hz + kt*32 + lk + 4);
    float4 b0 = *(const float4*)(W   + (size_t)(n0+lm)*Hz + kt*32 + lk);
    float4 b1 = *(const float4*)(W   + (size_t)(n0+lm)*Hz + kt*32 + lk + 4);
    __syncthreads();
    As[lk+0][lm]=a0.x; As[lk+1][lm]=a0.y; As[lk+2][lm]=a0.z; As[lk+3][lm]=a0.w;
    As[lk+4][lm]=a1.x; As[lk+5][lm]=a1.y; As[lk+6][lm]=a1.z; As[lk+7][lm]=a1.w;
    Bs[lk+0][lm]=b0.x; Bs[lk+1][lm]=b0.y; Bs[lk+2][lm]=b0.z; Bs[lk+3][lm]=b0.w;
    Bs[lk+4][lm]=b1.x; Bs[lk+5][lm]=b1.y; Bs[lk+6][lm]=b1.z; Bs[lk+7][lm]=b1.w;
    __syncthreads();
    #pragma unroll
    for (int k = 0; k < 32; k++){
      float4 av = *(const float4*)&As[k][ty*4];
      float4 bv = *(const float4*)&Bs[k][tx*4];
      acc[0][0]+=av.x*bv.x; acc[0][1]+=av.x*bv.y; acc[0][2]+=av.x*bv.z; acc[0][3]+=av.x*bv.w;
      acc[1][0]+=av.y*bv.x; acc[1][1]+=av.y*bv.y; acc[1][2]+=av.y*bv.z; acc[1][3]+=av.y*bv.w;
      acc[2][0]+=av.z*bv.x; acc[2][1]+=av.z*bv.y; acc[2][2]+=av.z*bv.z; acc[2][3]+=av.z*bv.w;
      acc[3][0]+=av.w*bv.x; acc[3][1]+=av.w*bv.y; acc[3][2]+=av.w*bv.z; acc[3][3]+=av.w*bv.w;
    }
  }
  #pragma unroll
  for (int j = 0; j < 4; j++){
    int col = n0 + tx*4 + j;
    float bias = bi[col] + bh[col];
    #pragma unroll
    for (int i = 0; i < 4; i++)
      out[(size_t)(m0 + ty*4 + i)*G4 + col] = acc[i][j] + bias;
  }
}

// ---------------- persistent decoder v4 ----------------
__global__ __launch_bounds__(512, 1) void decoder_persist_v4(
    const float* __restrict__ Wp0, const float* __restrict__ Wp1,
    const float* __restrict__ Wc,  const float* __restrict__ x0g,
    const float* __restrict__ bi1, const float* __restrict__ bh1,
    const float* __restrict__ bc,  const float* __restrict__ c0in,
    const float* __restrict__ enc,
    float* __restrict__ h0p, float* __restrict__ h1p,
    float* __restrict__ cbuf, float* __restrict__ ctxb,
    unsigned int* __restrict__ oa32, unsigned int* __restrict__ bar){
  extern __shared__ float sm[];
  float* hstA = sm;                  // [32][520] 16640 f
  float* hstB = sm + 16640;          // [32][520] 16640 f
  float* gs   = sm + 33280;          // [2][8][32]  512 f
  float* gsw  = gs + 512;            // [8][2][32]  512 f
  float* ea   = gsw + 512;           // [128]
  float* red  = ea + 128;            // [8]
  float4* hA4 = (float4*)hstA;
  float4* hB4 = (float4*)hstB;

  const int bid = blockIdx.x, tid = threadIdx.x;
  const int w4 = tid >> 6, lane = tid & 63;
  const int kh = w4 >> 2, rpair = w4 & 3;
  const int r0 = bid*8 + rpair*2, r1 = r0 + 1;
  const int u0 = bid*2, u1 = u0 + 1;
  unsigned int ep = 0;

  // ---- persistent weights -> VGPRs ----
  const float4* Wp0_4 = (const float4*)Wp0;
  const float4* Wp1_4 = (const float4*)Wp1;
  float4 w0A  = Wp0_4[r0*128 + kh*64 + lane];
  float4 w0B  = Wp0_4[r1*128 + kh*64 + lane];
  float4 w1xA = Wp1_4[r0*256 +       kh*64 + lane];
  float4 w1xB = Wp1_4[r1*256 +       kh*64 + lane];
  float4 w1hA = Wp1_4[r0*256 + 128 + kh*64 + lane];
  float4 w1hB = Wp1_4[r1*256 + 128 + kh*64 + lane];
  float wcA0 = Wc[(size_t)u0*1024 + tid];
  float wcB0 = Wc[(size_t)u1*1024 + tid];
  float wcA1 = Wc[(size_t)u0*1024 + 512 + tid];
  float wcB1 = Wc[(size_t)u1*1024 + 512 + tid];
  float bs_i=0.f, bs_f=0.f, bs_g=0.f, bs_o=0.f, bcv=0.f;
  float c0_reg=0.f, c1_reg=0.f;
  if (tid < 64){
    int ul = tid >> 5, b = tid & 31, u = bid*2 + ul;
    bs_i = bi1[u]        + bh1[u];
    bs_f = bi1[512+u]    + bh1[512+u];
    bs_g = bi1[1024+u]   + bh1[1024+u];
    bs_o = bi1[1536+u]   + bh1[1536+u];
    bcv  = bc[u];
    c0_reg = c0in[b*512 + u];            // layer0 c
    c1_reg = c0in[16384 + b*512 + u];    // layer1 c
  }
  __syncthreads();

  for (int t = 0; t < Tz; t++){
    const int rp = t & 1, wp = rp ^ 1;
    // ============ PHASE 1: l0(t) + attnB(t-2) ============
    stage2(hstA, h0p + rp*16384, hstB, h1p + ((t+1)%3)*16384, tid);
    float xgi=0.f, xgf=0.f, xgg=0.f, xgo=0.f;
    if (tid < 64){
      int ul = tid >> 5, b = tid & 31, u = bid*2 + ul;
      const float* xg = x0g + ((size_t)t*Bz + b)*G4;
      xgi = xg[u]; xgf = xg[512+u]; xgg = xg[1024+u]; xgo = xg[1536+u];
    }
    float4 cr[8];
    {
      const float4* c4 = (const float4*)ctxb;
      #pragma unroll
      for (int i = 0; i < 8; i++) cr[i] = c4[tid + i*512];
    }
    __syncthreads();
    {   // l0 gemv on hstA
      float a0[32], a1[32];
      #pragma unroll
      for (int b = 0; b < 32; b++){ a0[b] = 0.f; a1[b] = 0.f; }
      gemv_acc(hA4 + kh*64 + lane, w0A, w0B, a0, a1);
      xreduce(a0, lane); xreduce(a1, lane);
      int bb = lane & 31;
      gs[kh*256 + (rpair*2 + (lane >= 32 ? 1 : 0))*32 + bb] = (lane < 32) ? a0[0] : a1[0];
    }
    // attnB part1 on hstB (h1(t-2))
    float wa0[32], wa1[32];
    #pragma unroll
    for (int b = 0; b < 32; b++){ wa0[b] = 0.f; wa1[b] = 0.f; }
    wc_acc(hstB, wcA0, wcB0, wa0, wa1, tid);
    __syncthreads();                 // all waves done reading hstB
    {   // drop ctx regs into hstB
      float4* dB4 = (float4*)hstB;
      #pragma unroll
      for (int i = 0; i < 8; i++){ int idx = tid + i*512; dB4[idx + ((idx >> 7) << 1)] = cr[i]; }
    }
    __syncthreads();
    wc_acc(hstB, wcA1, wcB1, wa0, wa1, tid);
    xreduce(wa0, lane); xreduce(wa1, lane);
    gsw[w4*64 + (lane >= 32 ? 32 : 0) + (lane & 31)] = (lane < 32) ? wa0[0] : wa1[0];
    __syncthreads();
    if (tid < 64){
      int ul = tid >> 5, b = tid & 31, u = bid*2 + ul, rl = ul*4;
      float gi = gs[(rl+0)*32+b] + gs[256+(rl+0)*32+b] + xgi;
      float gf = gs[(rl+1)*32+b] + gs[256+(rl+1)*32+b] + xgf;
      float gg = gs[(rl+2)*32+b] + gs[256+(rl+2)*32+b] + xgg;
      float go = gs[(rl+3)*32+b] + gs[256+(rl+3)*32+b] + xgo;
      float cn = sigf(gf)*c0_reg + sigf(gi)*tanhf(gg);
      c0_reg = cn;
      stc(h0p + wp*16384 + b*512 + u, sigf(go)*tanhf(cn));
      if (t >= 2){
        float s = bcv;
        #pragma unroll
        for (int w = 0; w < 8; w++) s += gsw[w*64 + ul*32 + b];
        unsigned short me = f2bf(tanhf(s));
        unsigned other = (unsigned)__shfl((int)(unsigned)me, tid + 32);
        if (tid < 32)
          __hip_atomic_store(oa32 + ((size_t)b*Tz + (t-2))*256 + bid,
                             ((unsigned)me) | (other << 16), A_RLX, SC_AG);
      }
    }
    gbar(bar, bid, &ep);
    // ============ PHASE 2: l1(t) + attnA(t-1) ============
    stage2(hstA, h0p + wp*16384, hstB, h1p + ((t+2)%3)*16384, tid);
    __syncthreads();
    {
      float a0[32], a1[32];
      #pragma unroll
      for (int b = 0; b < 32; b++){ a0[b] = 0.f; a1[b] = 0.f; }
      gemv_acc(hA4 + kh*64 + lane, w1xA, w1xB, a0, a1);
      gemv_acc(hB4 + kh*64 + lane, w1hA, w1hB, a0, a1);
      xreduce(a0, lane); xreduce(a1, lane);
      int bb = lane & 31;
      gs[kh*256 + (rpair*2 + (lane >= 32 ? 1 : 0))*32 + bb] = (lane < 32) ? a0[0] : a1[0];
    }
    __syncthreads();
    if (tid < 64){
      int ul = tid >> 5, b = tid & 31, u = bid*2 + ul, rl = ul*4;
      float gi = gs[(rl+0)*32+b] + gs[256+(rl+0)*32+b] + bs_i;
      float gf = gs[(rl+1)*32+b] + gs[256+(rl+1)*32+b] + bs_f;
      float gg = gs[(rl+2)*32+b] + gs[256+(rl+2)*32+b] + bs_g;
      float go = gs[(rl+3)*32+b] + gs[256+(rl+3)*32+b] + bs_o;
      float cn = sigf(gf)*c1_reg + sigf(gi)*tanhf(gg);
      c1_reg = cn;
      stc(h1p + (t%3)*16384 + b*512 + u, sigf(go)*tanhf(cn));
    }
    if (bid < 32 && t >= 1){
      // hstB holds h1(t-1)
      {
        int s = tid >> 2, q = tid & 3;
        const float4* e4 = (const float4*)(enc + ((size_t)bid*Sz + s)*Hz) + q*32;
        const float4* h4 = hB4 + bid*130 + q*32;
        float a = 0.f;
        #pragma unroll 8
        for (int i = 0; i < 32; i++){
          float4 e = e4[i], h = h4[i];
          a += e.x*h.x + e.y*h.y + e.z*h.z + e.w*h.w;
        }
        a += __shfl_xor(a, 1); a += __shfl_xor(a, 2);
        if (q == 0) ea[s] = a;
      }
      __syncthreads();
      if (tid < 64){
        float v = fmaxf(ea[tid], ea[tid+64]);
        #pragma unroll
        for (int o = 32; o; o >>= 1) v = fmaxf(v, __shfl_xor(v, o));
        if (tid == 0) red[0] = v;
      }
      __syncthreads();
      if (tid < 128) ea[tid] = expf(ea[tid] - red[0]);
      __syncthreads();
      if (tid < 64){
        float v = ea[tid] + ea[tid+64];
        #pragma unroll
        for (int o = 32; o; o >>= 1) v += __shfl_xor(v, o);
        if (tid == 0) red[1] = v;
      }
      __syncthreads();
      {
        float inv = 1.f/red[1];
        float c = 0.f;
        const float* epp = enc + (size_t)bid*Sz*Hz + tid;
        #pragma unroll 4
        for (int s = 0; s < Sz; s++) c = fmaf(ea[s], epp[(size_t)s*Hz], c);
        stc(ctxb + bid*512 + tid, c*inv);
      }
    }
    gbar(bar, bid, &ep);
  }
  // ============ EPILOGUE ============
  // E1: attnB(62): h1(62) slot 2, ctxb = ctx(62)
  {
    stage(hstB, h1p + 2*16384, tid);
    __syncthreads();
    float wa0[32], wa1[32];
    #pragma unroll
    for (int b = 0; b < 32; b++){ wa0[b] = 0.f; wa1[b] = 0.f; }
    wc_acc(hstB, wcA0, wcB0, wa0, wa1, tid);
    __syncthreads();
    stage(hstB, ctxb, tid);
    __syncthreads();
    wc_acc(hstB, wcA1, wcB1, wa0, wa1, tid);
    xreduce(wa0, lane); xreduce(wa1, lane);
    gsw[w4*64 + (lane >= 32 ? 32 : 0) + (lane & 31)] = (lane < 32) ? wa0[0] : wa1[0];
    __syncthreads();
    if (tid < 64){
      int ul = tid >> 5, b = tid & 31;
      float s = bcv;
      #pragma unroll
      for (int w = 0; w < 8; w++) s += gsw[w*64 + ul*32 + b];
      unsigned short me = f2bf(tanhf(s));
      unsigned other = (unsigned)__shfl((int)(unsigned)me, tid + 32);
      if (tid < 32)
        __hip_atomic_store(oa32 + ((size_t)b*Tz + 62)*256 + bid,
                           ((unsigned)me) | (other << 16), A_RLX, SC_AG);
    }
  }
  gbar(bar, bid, &ep);
  // E2: attnA(63): h1(63) slot 0
  if (bid < 32){
    stage(hstB, h1p + 0*16384, tid);
    __syncthreads();
    {
      int s = tid >> 2, q = tid & 3;
      const float4* e4 = (const float4*)(enc + ((size_t)bid*Sz + s)*Hz) + q*32;
      const float4* h4 = hB4 + bid*130 + q*32;
      float a = 0.f;
      #pragma unroll 8
      for (int i = 0; i < 32; i++){
        float4 e = e4[i], h = h4[i];
        a += e.x*h.x + e.y*h.y + e.z*h.z + e.w*h.w;
      }
      a += __shfl_xor(a, 1); a += __shfl_xor(a, 2);
      if (q == 0) ea[s] = a;
    }
    __syncthreads();
    if (tid < 64){
      float v = fmaxf(ea[tid], ea[tid+64]);
      #pragma unroll
      for (int o = 32; o; o >>= 1) v = fmaxf(v, __shfl_xor(v, o));
      if (tid == 0) red[0] = v;
    }
    __syncthreads();
    if (tid < 128) ea[tid] = expf(ea[tid] - red[0]);
    __syncthreads();
    if (tid < 64){
      float v = ea[tid] + ea[tid+64];
      #pragma unroll
      for (int o = 32; o; o >>= 1) v += __shfl_xor(v, o);
      if (tid == 0) red[1] = v;
    }
    __syncthreads();
    {
      float inv = 1.f/red[1];
      float c = 0.f;
      const float* epp = enc + (size_t)bid*Sz*Hz + tid;
      #pragma unroll 4
      for (int s = 0; s < Sz; s++) c = fmaf(ea[s], epp[(size_t)s*Hz], c);
      stc(ctxb + bid*512 + tid, c*inv);
    }
  }
  gbar(bar, bid, &ep);
  // E3: attnB(63): h1(63) slot 0, ctx(63) fresh
  {
    stage(hstB, h1p + 0*16384, tid);
    __syncthreads();
    float wa0[32], wa1[32];
    #pragma unroll
    for (int b = 0; b < 32; b++){ wa0[b] = 0.f; wa1[b] = 0.f; }
    wc_acc(hstB, wcA0, wcB0, wa0, wa1, tid);
    __syncthreads();
    stage(hstB, ctxb, tid);
    __syncthreads();
    wc_acc(hstB, wcA1, wcB1, wa0, wa1, tid);
    xreduce(wa0, lane); xreduce(wa1, lane);
    gsw[w4*64 + (lane >= 32 ? 32 : 0) + (lane & 31)] = (lane < 32) ? wa0[0] : wa1[0];
    __syncthreads();
    if (tid < 64){
      int ul = tid >> 5, b = tid & 31;
      float s = bcv;
      #pragma unroll
      for (int w = 0; w < 8; w++) s += gsw[w*64 + ul*32 + b];
      unsigned short me = f2bf(tanhf(s));
      unsigned other = (unsigned)__shfl((int)(unsigned)me, tid + 32);
      if (tid < 32)
        __hip_atomic_store(oa32 + ((size_t)b*Tz + 63)*256 + bid,
                           ((unsigned)me) | (other << 16), A_RLX, SC_AG);
    }
  }
  // write back final c state
  if (tid < 64){
    int ul = tid >> 5, b = tid & 31, u = bid*2 + ul;
    cbuf[b*512 + u] = c0_reg;
    cbuf[16384 + b*512 + u] = c1_reg;
  }
}

// ---------------- pred GEMM: XCD-pinned + swizzled LDS ----------------
__global__ __launch_bounds__(256) void pred_gemm_v2(const unsigned short* __restrict__ A,
    const unsigned short* __restrict__ Bm, const float* __restrict__ bo,
    float* __restrict__ out){
  __shared__ unsigned short As[128*32];
  __shared__ unsigned short Bs[128*32];
  int bid = blockIdx.x;
  int xcd = bid & 7, lin = bid >> 3;
  int ntile = xcd*32 + (lin & 31);
  int mtile = lin >> 5;
  if (ntile >= 250) return;
  int n0 = ntile*128, m0 = mtile*128;
  int tid = threadIdx.x, lane = tid & 63, wid = tid >> 6;
  f32x4 acc[4][4];
  #pragma unroll
  for (int i = 0; i < 4; i++)
    #pragma unroll
    for (int j = 0; j < 4; j++)
      #pragma unroll
      for (int r = 0; r < 4; r++) acc[i][j][r] = 0.f;

  int wm = wid >> 1, wn = wid & 1;
  int r16 = lane & 15, kgr = lane >> 4;

  for (int kt = 0; kt < Hz/32; kt++){
    __syncthreads();
    #pragma unroll
    for (int call = 0; call < 2; call++){
      int c = call*256 + tid;
      int row = c >> 2, kg = c & 3;
      int kgs = kg ^ ((row >> 1) & 3);
      *(int4*)&As[row*32 + kgs*8] = *(const int4*)(A  + (size_t)(m0+row)*Hz + kt*32 + kg*8);
      *(int4*)&Bs[row*32 + kgs*8] = *(const int4*)(Bm + (size_t)(n0+row)*Hz + kt*32 + kg*8);
    }
    __syncthreads();
    bf16x8 aF[4], bF[4];
    #pragma unroll
    for (int i = 0; i < 4; i++){
      int ra = wm*64 + i*16 + r16;
      int rb = wn*64 + i*16 + r16;
      aF[i] = *(const bf16x8*)&As[ra*32 + (kgr ^ ((ra>>1)&3))*8];
      bF[i] = *(const bf16x8*)&Bs[rb*32 + (kgr ^ ((rb>>1)&3))*8];
    }
    #pragma unroll
    for (int i = 0; i < 4; i++)
      #pragma unroll
      for (int j = 0; j < 4; j++)
        acc[i][j] = __builtin_amdgcn_mfma_f32_16x16x32_bf16(aF[i], bF[j], acc[i][j], 0, 0, 0);
  }

  int rg = lane >> 4;
  #pragma unroll
  for (int i = 0; i < 4; i++)
    #pragma unroll
    for (int j = 0; j < 4; j++){
      int col = n0 + wn*64 + j*16 + r16;
      float bias = bo[col];
      #pragma unroll
      for (int r = 0; r < 4; r++){
        int row = m0 + wm*64 + i*16 + rg*4 + r;   // row = b*64 + t
        out[(size_t)row*Vz + col] = acc[i][j][r] + bias;
      }
    }
}

// ---------------- final h,c copy ----------------
__global__ __launch_bounds__(256) void copy_hc_v2(const float* __restrict__ h0p,
    const float* __restrict__ h1p, const float* __restrict__ cbuf,
    float* __restrict__ out_hc){
  int i = blockIdx.x*256 + threadIdx.x;
  float v;
  if (i < 16384)      v = h0p[i];
  else if (i < 32768) v = h1p[i-16384];
  else                v = cbuf[i-32768];
  out_hc[i] = v;
}

extern "C" void kernel_launch(void* const* d_in, const int* in_sizes, int n_in,
                              void* d_out, int out_size, void* d_ws, size_t ws_size,
                              hipStream_t stream){
  const int*   tgt = (const int*)  d_in[0];
  const float* h0  = (const float*)d_in[1];
  const float* c0  = (const float*)d_in[2];
  const float* enc = (const float*)d_in[3];
  const float* emb = (const float*)d_in[4];
  const float* Wih = (const float*)d_in[5];
  const float* Whh = (const float*)d_in[6];
  const float* bih = (const float*)d_in[7];
  const float* bhh = (const float*)d_in[8];
  const float* Wc  = (const float*)d_in[9];
  const float* bc  = (const float*)d_in[10];
  const float* Wo  = (const float*)d_in[11];
  const float* bo  = (const float*)d_in[12];
  float* out = (float*)d_out;

  // workspace layout (floats)
  float* x0g  = (float*)d_ws;                 // 4,194,304
  float* h0p  = x0g  + 4194304;               // 32,768  [2][32][512]
  float* h1p  = h0p  + 32768;                 // 49,152  [3][32][512]
  float* cbuf = h1p  + 49152;                 // 32,768  [L][32][512]
  float* ctxb = cbuf + 32768;                 // 16,384  [32][512]
  float* Wp0  = ctxb + 16384;                 // 1,048,576
  float* Wp1  = Wp0  + 1048576;               // 2,097,152
  unsigned int* bar = (unsigned int*)(Wp1 + 2097152);           // 528 words
  unsigned short* oa    = (unsigned short*)(bar + 544);         // 1,048,576 us [b][t][u]
  unsigned short* wo_bf = oa + 1048576;       // 16,384,000 us (32MB)

  const int DLDS_BYTES = 34440 * 4;           // 137.8 KB dynamic LDS
  hipFuncSetAttribute((const void*)decoder_persist_v4,
      hipFuncAttributeMaxDynamicSharedMemorySize, DLDS_BYTES);

  init_state_v4<<<128, 256, 0, stream>>>(h0, h0p, h1p, bar);
  conv_bf16_kernel<<<16000, 256, 0, stream>>>(Wo, wo_bf);
  pack_l0_v3<<<1024, 256, 0, stream>>>(Whh, Wp0);
  pack_l1_v3<<<2048, 256, 0, stream>>>(Wih + (size_t)G4*Hz, Whh + (size_t)G4*Hz, Wp1);
  x0g_v2<<<dim3(32, 32), 256, 0, stream>>>(tgt, emb, Wih, bih, bhh, x0g);

  decoder_persist_v4<<<NBLK, 512, DLDS_BYTES, stream>>>(
      Wp0, Wp1, Wc, x0g, bih + G4, bhh + G4, bc, c0, enc,
      h0p, h1p, cbuf, ctxb, (unsigned int*)oa, bar);

  pred_gemm_v2<<<4096, 256, 0, stream>>>(oa, wo_bf, bo, out);
  copy_hc_v2<<<256, 256, 0, stream>>>(h0p, h1p, cbuf, out + (size_t)Bz*Tz*Vz);

  (void)in_sizes; (void)n_in; (void)out_size; (void)ws_size;
}

// Round 6
// 3560.276 us; speedup vs baseline: 2.7295x; 1.2369x over previous
//
#include <hip/hip_runtime.h>
#include <hip/hip_bf16.h>

#define Bz 32
#define Tz 64
#define Sz 128
#define Hz 512
#define Vz 32000
#define G4 2048
#define NBLK 256
#define NPH 67

#define A_RLX __ATOMIC_RELAXED
#define A_ACQ __ATOMIC_ACQUIRE
#define SC_AG __HIP_MEMORY_SCOPE_AGENT

using bf16x8 = __attribute__((ext_vector_type(8))) short;
using f32x4  = __attribute__((ext_vector_type(4))) float;

__device__ __forceinline__ unsigned short f2bf(float f){
  unsigned int u = __float_as_uint(f);
  u += 0x7fffu + ((u >> 16) & 1u);
  return (unsigned short)(u >> 16);
}
__device__ __forceinline__ float sigf(float x){ return 1.f/(1.f + expf(-x)); }

__device__ __forceinline__ void stc(float* p, float v){
  __hip_atomic_store(p, v, A_RLX, SC_AG);
}

// ---------------- grid barrier: single-writer epochs, no atomic RMW ----------------
// bar words: arrive: group g line = words [g*16 .. g*16+15], word m = epoch of block g*16+m
//            root line: words [256..271], word g = epoch posted by leader g
//            release: word 288
__device__ __forceinline__ void gbar(unsigned* bar, int bid, unsigned* ep){
  asm volatile("s_waitcnt vmcnt(0)" ::: "memory");   // drain this thread's stores
  __syncthreads();                                    // whole block drained
  const unsigned e = ++(*ep);
  if (threadIdx.x == 0){
    const int g = bid >> 4, m = bid & 15;
    if (m != 0){
      __hip_atomic_store(&bar[g*16 + m], e, A_RLX, SC_AG);
    } else {
      // leader: wait for 15 members (15 independent loads per round)
      for (;;){
        bool done = true;
        #pragma unroll
        for (int i = 1; i < 16; i++)
          done &= (__hip_atomic_load(&bar[g*16 + i], A_RLX, SC_AG) == e);
        if (done) break;
        __builtin_amdgcn_s_sleep(1);
      }
      __hip_atomic_store(&bar[256 + g], e, A_RLX, SC_AG);
      if (bid == 0){
        for (;;){
          bool done = true;
          #pragma unroll
          for (int i = 0; i < 16; i++)
            done &= (__hip_atomic_load(&bar[256 + i], A_RLX, SC_AG) == e);
          if (done) break;
          __builtin_amdgcn_s_sleep(1);
        }
        __hip_atomic_store(&bar[288], e, A_RLX, SC_AG);
      }
    }
    while (__hip_atomic_load(&bar[288], A_RLX, SC_AG) != e)
      __builtin_amdgcn_s_sleep(1);
  }
  __syncthreads();
  if ((threadIdx.x & 63) == 0)                       // one acquire (inv) per wave
    (void)__hip_atomic_load(&bar[288], A_ACQ, SC_AG);
  __builtin_amdgcn_sched_barrier(0);
  __syncthreads();
}

// ---------------- register transpose-reduce: 64 lanes x 32 accs -> lane holds b=lane&31 sum ----
__device__ __forceinline__ void xreduce(float (&a)[32], int lane){
  #pragma unroll
  for (int j = 0; j < 32; j++) a[j] += __shfl_xor(a[j], 32);
  #pragma unroll
  for (int st = 0; st < 5; st++){
    const int o = 16 >> st;
    bool hi = (lane & o) != 0;
    float tmp[16];
    #pragma unroll
    for (int j = 0; j < o; j++){
      float lo_v = a[j], hi_v = a[j + o];
      float sent = hi ? lo_v : hi_v;
      float recv = __shfl_xor(sent, o);
      tmp[j] = (hi ? hi_v : lo_v) + recv;
    }
    #pragma unroll
    for (int j = 0; j < o; j++) a[j] = tmp[j];
  }
}

// ---------------- dual LDS staging: all 16 loads issued before LDS writes ----------------
__device__ __forceinline__ void stage2(float* dA, const float* sA,
                                       float* dB, const float* sB, int tid){
  const float4* a4 = (const float4*)sA;
  const float4* b4 = (const float4*)sB;
  float4 ra[8], rb[8];
  #pragma unroll
  for (int i = 0; i < 8; i++) ra[i] = a4[tid + i*512];
  #pragma unroll
  for (int i = 0; i < 8; i++) rb[i] = b4[tid + i*512];
  float4* dA4 = (float4*)dA; float4* dB4 = (float4*)dB;
  #pragma unroll
  for (int i = 0; i < 8; i++){ int idx = tid + i*512; dA4[idx + ((idx >> 7) << 1)] = ra[i]; }
  #pragma unroll
  for (int i = 0; i < 8; i++){ int idx = tid + i*512; dB4[idx + ((idx >> 7) << 1)] = rb[i]; }
}

// ---------------- init ----------------
__global__ __launch_bounds__(256) void init_state_v5(const float* __restrict__ h0,
    float* __restrict__ h0p, float* __restrict__ h1p, unsigned int* __restrict__ bar){
  int i = blockIdx.x*256 + threadIdx.x;   // grid 128 -> 32768
  if (i < 16384) h0p[16384 + i] = h0[i];            // h0(-1) -> slot 1
  else           h1p[3*16384 + (i - 16384)] = h0[i]; // h1(-1) -> slot 3
  if (i < 512) bar[i] = 0u;
}

// ---------------- Wo -> bf16 ----------------
__global__ __launch_bounds__(256) void conv_bf16_kernel(const float* __restrict__ src,
    unsigned short* __restrict__ dst){
  int i = (blockIdx.x*256 + threadIdx.x)*4;
  float4 v = *(const float4*)(src + i);
  ushort4 o;
  o.x = f2bf(v.x); o.y = f2bf(v.y); o.z = f2bf(v.z); o.w = f2bf(v.w);
  *(ushort4*)(dst + i) = o;
}

// ---------------- weight packs: row-major, rows r = u*4+gate ----------------
__global__ __launch_bounds__(256) void pack_l0_v3(const float* __restrict__ W,
    float* __restrict__ out){
  int idx4 = blockIdx.x*256 + threadIdx.x;
  int r = idx4 >> 7, k4 = idx4 & 127;
  int srow = (r & 3)*Hz + (r >> 2);
  ((float4*)out)[idx4] = ((const float4*)W)[srow*128 + k4];
}
__global__ __launch_bounds__(256) void pack_l1_v3(const float* __restrict__ Wi,
    const float* __restrict__ Wh, float* __restrict__ out){
  int idx4 = blockIdx.x*256 + threadIdx.x;
  int r = idx4 >> 8, k4 = idx4 & 255;
  int srow = (r & 3)*Hz + (r >> 2);
  float4 v = (k4 < 128) ? ((const float4*)Wi)[srow*128 + k4]
                        : ((const float4*)Wh)[srow*128 + (k4 - 128)];
  ((float4*)out)[idx4] = v;
}

// ---------------- x0g: tiled fp32 GEMM ----------------
__global__ __launch_bounds__(256) void x0g_v2(const int* __restrict__ tgt,
    const float* __restrict__ emb, const float* __restrict__ W,
    const float* __restrict__ bi, const float* __restrict__ bh,
    float* __restrict__ out){
  __shared__ float As[32][68], Bs[32][68];
  __shared__ int tok_s[64];
  int tid = threadIdx.x;
  int m0 = blockIdx.y*64, n0 = blockIdx.x*64;
  if (tid < 64){ int tb = m0 + tid; tok_s[tid] = tgt[(tb & 31)*Tz + (tb >> 5)]; }
  __syncthreads();
  int lm = tid >> 2, lk = (tid & 3)*8;
  int ty = tid >> 4, tx = tid & 15;
  float acc[4][4] = {{0.f}};
  for (int kt = 0; kt < 16; kt++){
    float4 a0 = *(const float4*)(emb + (size_t)tok_s[lm]*Hz + kt*32 + lk);
    float4 a1 = *(const float4*)(emb + (size_t)tok_s[lm]*Hz + kt*32 + lk + 4);
    float4 b0 = *(const float4*)(W   + (size_t)(n0+lm)*Hz + kt*32 + lk);
    float4 b1 = *(const float4*)(W   + (size_t)(n0+lm)*Hz + kt*32 + lk + 4);
    __syncthreads();
    As[lk+0][lm]=a0.x; As[lk+1][lm]=a0.y; As[lk+2][lm]=a0.z; As[lk+3][lm]=a0.w;
    As[lk+4][lm]=a1.x; As[lk+5][lm]=a1.y; As[lk+6][lm]=a1.z; As[lk+7][lm]=a1.w;
    Bs[lk+0][lm]=b0.x; Bs[lk+1][lm]=b0.y; Bs[lk+2][lm]=b0.z; Bs[lk+3][lm]=b0.w;
    Bs[lk+4][lm]=b1.x; Bs[lk+5][lm]=b1.y; Bs[lk+6][lm]=b1.z; Bs[lk+7][lm]=b1.w;
    __syncthreads();
    #pragma unroll
    for (int k = 0; k < 32; k++){
      float4 av = *(const float4*)&As[k][ty*4];
      float4 bv = *(const float4*)&Bs[k][tx*4];
      acc[0][0]+=av.x*bv.x; acc[0][1]+=av.x*bv.y; acc[0][2]+=av.x*bv.z; acc[0][3]+=av.x*bv.w;
      acc[1][0]+=av.y*bv.x; acc[1][1]+=av.y*bv.y; acc[1][2]+=av.y*bv.z; acc[1][3]+=av.y*bv.w;
      acc[2][0]+=av.z*bv.x; acc[2][1]+=av.z*bv.y; acc[2][2]+=av.z*bv.z; acc[2][3]+=av.z*bv.w;
      acc[3][0]+=av.w*bv.x; acc[3][1]+=av.w*bv.y; acc[3][2]+=av.w*bv.z; acc[3][3]+=av.w*bv.w;
    }
  }
  #pragma unroll
  for (int j = 0; j < 4; j++){
    int col = n0 + tx*4 + j;
    float bias = bi[col] + bh[col];
    #pragma unroll
    for (int i = 0; i < 4; i++)
      out[(size_t)(m0 + ty*4 + i)*G4 + col] = acc[i][j] + bias;
  }
}

// ---------------- persistent decoder v5: skewed pipeline, 1 barrier/phase ----------------
// phase tau: l0(tau) | l1(tau-1) | attnA(tau-2) | attnB(tau-3)
__global__ __launch_bounds__(512, 1) void decoder_persist_v5(
    const float* __restrict__ Wp0, const float* __restrict__ Wp1,
    const float* __restrict__ Wc,  const float* __restrict__ x0g,
    const float* __restrict__ bi1, const float* __restrict__ bh1,
    const float* __restrict__ bc,  const float* __restrict__ c0in,
    const float* __restrict__ enc,
    float* __restrict__ h0p,   // [2][16384]
    float* __restrict__ h1p,   // [4][16384]
    float* __restrict__ cbuf,  // [2][16384] (final c out)
    float* __restrict__ ctx2,  // [2][16384]
    unsigned* __restrict__ oa32, unsigned* __restrict__ bar){
  extern __shared__ float sm[];
  float* hstA = sm;              // [32][520] 16640
  float* hstB = sm + 16640;      // [32][520] 16640
  float* gsA  = sm + 33280;      // 512
  float* gsB  = sm + 33792;      // 512
  float* gsw  = sm + 34304;      // 512
  float* ea   = sm + 34816;      // 128
  float* red  = sm + 34944;      // 8
  float4* hA4 = (float4*)hstA;
  float4* hB4 = (float4*)hstB;

  const int bid = blockIdx.x, tid = threadIdx.x;
  const int w4 = tid >> 6, lane = tid & 63;
  const int kh = w4 >> 2, rpair = w4 & 3;
  const int r0 = bid*8 + rpair*2, r1 = r0 + 1;
  const int u0 = bid*2, u1 = u0 + 1;
  unsigned ep = 0;

  // ---- persistent weights -> VGPRs ----
  const float4* Wp0_4 = (const float4*)Wp0;
  const float4* Wp1_4 = (const float4*)Wp1;
  float4 w0A  = Wp0_4[r0*128 + kh*64 + lane];
  float4 w0B  = Wp0_4[r1*128 + kh*64 + lane];
  float4 w1xA = Wp1_4[r0*256 +       kh*64 + lane];
  float4 w1xB = Wp1_4[r1*256 +       kh*64 + lane];
  float4 w1hA = Wp1_4[r0*256 + 128 + kh*64 + lane];
  float4 w1hB = Wp1_4[r1*256 + 128 + kh*64 + lane];
  float wcA0 = Wc[(size_t)u0*1024 + tid];
  float wcB0 = Wc[(size_t)u1*1024 + tid];
  float wcA1 = Wc[(size_t)u0*1024 + 512 + tid];
  float wcB1 = Wc[(size_t)u1*1024 + 512 + tid];
  float bs_i=0.f, bs_f=0.f, bs_g=0.f, bs_o=0.f, bcv=0.f;
  float c0_reg=0.f, c1_reg=0.f;
  if (tid < 64){
    int ul = tid >> 5, b = tid & 31, u = bid*2 + ul;
    bs_i = bi1[u]        + bh1[u];
    bs_f = bi1[512+u]    + bh1[512+u];
    bs_g = bi1[1024+u]   + bh1[1024+u];
    bs_o = bi1[1536+u]   + bh1[1536+u];
    bcv  = bc[u];
    c0_reg = c0in[b*512 + u];
    c1_reg = c0in[16384 + b*512 + u];
  }
  __syncthreads();

  for (int tau = 0; tau < NPH; ++tau){
    // ---- stage h0(tau-1)->hstA, h1(tau-2)->hstB ----
    stage2(hstA, h0p + ((tau+1)&1)*16384, hstB, h1p + ((tau+2)&3)*16384, tid);
    // ---- x0g(tau) prefetch ----
    float xgi=0.f, xgf=0.f, xgg=0.f, xgo=0.f;
    if (tau < 64 && tid < 64){
      int b = tid & 31, u = bid*2 + (tid >> 5);
      const float* xg = x0g + ((size_t)tau*Bz + b)*G4;
      xgi = xg[u]; xgf = xg[512+u]; xgg = xg[1024+u]; xgo = xg[1536+u];
    }
    // ---- attnB(tau-3): all-global reads (coalesced per b) ----
    if (tau >= 3){
      const float* h1g = h1p + ((tau+1)&3)*16384;
      const float* ctg = ctx2 + ((tau+1)&1)*16384;
      float wa0[32], wa1[32];
      #pragma unroll
      for (int b = 0; b < 32; b++){
        float hv = h1g[b*512 + tid];
        float cv = ctg[b*512 + tid];
        wa0[b] = fmaf(hv, wcA0, cv*wcA1);
        wa1[b] = fmaf(hv, wcB0, cv*wcB1);
      }
      xreduce(wa0, lane); xreduce(wa1, lane);
      gsw[w4*64 + (lane >= 32 ? 32 : 0) + (lane & 31)] = (lane < 32) ? wa0[0] : wa1[0];
    }
    __syncthreads();
    // ---- combined gemv: l0(tau) rows + l1(tau-1) rows (one hstA read serves both) ----
    {
      float aL0A[32], aL0B[32], aL1A[32], aL1B[32];
      #pragma unroll
      for (int b = 0; b < 32; b++){ aL0A[b]=0.f; aL0B[b]=0.f; aL1A[b]=0.f; aL1B[b]=0.f; }
      const float4* pA = hA4 + kh*64 + lane;
      const float4* pB = hB4 + kh*64 + lane;
      #pragma unroll
      for (int b = 0; b < 32; b++){
        float4 ha = pA[b*130];
        float4 hb = pB[b*130];
        aL0A[b] = fmaf(ha.x,w0A.x, fmaf(ha.y,w0A.y, fmaf(ha.z,w0A.z, fmaf(ha.w,w0A.w, aL0A[b]))));
        aL0B[b] = fmaf(ha.x,w0B.x, fmaf(ha.y,w0B.y, fmaf(ha.z,w0B.z, fmaf(ha.w,w0B.w, aL0B[b]))));
        float t1 = fmaf(ha.x,w1xA.x, fmaf(ha.y,w1xA.y, fmaf(ha.z,w1xA.z, fmaf(ha.w,w1xA.w, aL1A[b]))));
        aL1A[b] = fmaf(hb.x,w1hA.x, fmaf(hb.y,w1hA.y, fmaf(hb.z,w1hA.z, fmaf(hb.w,w1hA.w, t1))));
        float t2 = fmaf(ha.x,w1xB.x, fmaf(ha.y,w1xB.y, fmaf(ha.z,w1xB.z, fmaf(ha.w,w1xB.w, aL1B[b]))));
        aL1B[b] = fmaf(hb.x,w1hB.x, fmaf(hb.y,w1hB.y, fmaf(hb.z,w1hB.z, fmaf(hb.w,w1hB.w, t2))));
      }
      xreduce(aL0A, lane); xreduce(aL0B, lane);
      gsA[kh*256 + (rpair*2 + (lane >= 32 ? 1 : 0))*32 + (lane & 31)] = (lane < 32) ? aL0A[0] : aL0B[0];
      xreduce(aL1A, lane); xreduce(aL1B, lane);
      gsB[kh*256 + (rpair*2 + (lane >= 32 ? 1 : 0))*32 + (lane & 31)] = (lane < 32) ? aL1A[0] : aL1B[0];
    }
    __syncthreads();
    // ---- cells + attnB finalize (tid<64) ----
    if (tid < 64){
      int ul = tid >> 5, b = tid & 31, u = bid*2 + ul, rl = ul*4;
      if (tau < 64){
        float gi = gsA[(rl+0)*32+b] + gsA[256+(rl+0)*32+b] + xgi;
        float gf = gsA[(rl+1)*32+b] + gsA[256+(rl+1)*32+b] + xgf;
        float gg = gsA[(rl+2)*32+b] + gsA[256+(rl+2)*32+b] + xgg;
        float go = gsA[(rl+3)*32+b] + gsA[256+(rl+3)*32+b] + xgo;
        float cn = sigf(gf)*c0_reg + sigf(gi)*tanhf(gg);
        c0_reg = cn;
        stc(h0p + (tau&1)*16384 + b*512 + u, sigf(go)*tanhf(cn));
      }
      if (tau >= 1 && tau <= 64){
        float gi = gsB[(rl+0)*32+b] + gsB[256+(rl+0)*32+b] + bs_i;
        float gf = gsB[(rl+1)*32+b] + gsB[256+(rl+1)*32+b] + bs_f;
        float gg = gsB[(rl+2)*32+b] + gsB[256+(rl+2)*32+b] + bs_g;
        float go = gsB[(rl+3)*32+b] + gsB[256+(rl+3)*32+b] + bs_o;
        float cn = sigf(gf)*c1_reg + sigf(gi)*tanhf(gg);
        c1_reg = cn;
        stc(h1p + ((tau-1)&3)*16384 + b*512 + u, sigf(go)*tanhf(cn));
      }
      if (tau >= 3){
        float s = bcv;
        #pragma unroll
        for (int w = 0; w < 8; w++) s += gsw[w*64 + ul*32 + b];
        unsigned short me = f2bf(tanhf(s));
        unsigned other = (unsigned)__shfl((int)(unsigned)me, tid + 32);
        if (tid < 32)
          __hip_atomic_store(oa32 + ((size_t)b*Tz + (tau-3))*256 + bid,
                             ((unsigned)me) | (other << 16), A_RLX, SC_AG);
      }
    }
    // ---- attnA(tau-2) on blocks 0..31 (hstB = h1(tau-2)) ----
    if (bid < 32 && tau >= 2 && tau <= 65){
      {
        int s = tid >> 2, q = tid & 3;
        const float4* e4 = (const float4*)(enc + ((size_t)bid*Sz + s)*Hz) + q*32;
        const float4* h4 = hB4 + bid*130 + q*32;
        float a = 0.f;
        #pragma unroll 8
        for (int i = 0; i < 32; i++){
          float4 e = e4[i], h = h4[i];
          a += e.x*h.x + e.y*h.y + e.z*h.z + e.w*h.w;
        }
        a += __shfl_xor(a, 1); a += __shfl_xor(a, 2);
        if (q == 0) ea[s] = a;
      }
      __syncthreads();
      if (tid < 64){
        float v = fmaxf(ea[tid], ea[tid+64]);
        #pragma unroll
        for (int o = 32; o; o >>= 1) v = fmaxf(v, __shfl_xor(v, o));
        if (tid == 0) red[0] = v;
      }
      __syncthreads();
      if (tid < 128) ea[tid] = expf(ea[tid] - red[0]);
      __syncthreads();
      if (tid < 64){
        float v = ea[tid] + ea[tid+64];
        #pragma unroll
        for (int o = 32; o; o >>= 1) v += __shfl_xor(v, o);
        if (tid == 0) red[1] = v;
      }
      __syncthreads();
      {
        float inv = 1.f/red[1];
        float c = 0.f;
        const float* epp = enc + (size_t)bid*Sz*Hz + tid;
        #pragma unroll 4
        for (int s = 0; s < Sz; s++) c = fmaf(ea[s], epp[(size_t)s*Hz], c);
        stc(ctx2 + (tau&1)*16384 + bid*512 + tid, c*inv);
      }
    }
    gbar(bar, bid, &ep);
  }
  // ---- final c writeback ----
  if (tid < 64){
    int ul = tid >> 5, b = tid & 31, u = bid*2 + ul;
    cbuf[b*512 + u] = c0_reg;
    cbuf[16384 + b*512 + u] = c1_reg;
  }
}

// ---------------- pred GEMM: XCD-pinned + swizzled LDS ----------------
__global__ __launch_bounds__(256) void pred_gemm_v2(const unsigned short* __restrict__ A,
    const unsigned short* __restrict__ Bm, const float* __restrict__ bo,
    float* __restrict__ out){
  __shared__ unsigned short As[128*32];
  __shared__ unsigned short Bs[128*32];
  int bid = blockIdx.x;
  int xcd = bid & 7, lin = bid >> 3;
  int ntile = xcd*32 + (lin & 31);
  int mtile = lin >> 5;
  if (ntile >= 250) return;
  int n0 = ntile*128, m0 = mtile*128;
  int tid = threadIdx.x, lane = tid & 63, wid = tid >> 6;
  f32x4 acc[4][4];
  #pragma unroll
  for (int i = 0; i < 4; i++)
    #pragma unroll
    for (int j = 0; j < 4; j++)
      #pragma unroll
      for (int r = 0; r < 4; r++) acc[i][j][r] = 0.f;

  int wm = wid >> 1, wn = wid & 1;
  int r16 = lane & 15, kgr = lane >> 4;

  for (int kt = 0; kt < Hz/32; kt++){
    __syncthreads();
    #pragma unroll
    for (int call = 0; call < 2; call++){
      int c = call*256 + tid;
      int row = c >> 2, kg = c & 3;
      int kgs = kg ^ ((row >> 1) & 3);
      *(int4*)&As[row*32 + kgs*8] = *(const int4*)(A  + (size_t)(m0+row)*Hz + kt*32 + kg*8);
      *(int4*)&Bs[row*32 + kgs*8] = *(const int4*)(Bm + (size_t)(n0+row)*Hz + kt*32 + kg*8);
    }
    __syncthreads();
    bf16x8 aF[4], bF[4];
    #pragma unroll
    for (int i = 0; i < 4; i++){
      int ra = wm*64 + i*16 + r16;
      int rb = wn*64 + i*16 + r16;
      aF[i] = *(const bf16x8*)&As[ra*32 + (kgr ^ ((ra>>1)&3))*8];
      bF[i] = *(const bf16x8*)&Bs[rb*32 + (kgr ^ ((rb>>1)&3))*8];
    }
    #pragma unroll
    for (int i = 0; i < 4; i++)
      #pragma unroll
      for (int j = 0; j < 4; j++)
        acc[i][j] = __builtin_amdgcn_mfma_f32_16x16x32_bf16(aF[i], bF[j], acc[i][j], 0, 0, 0);
  }

  int rg = lane >> 4;
  #pragma unroll
  for (int i = 0; i < 4; i++)
    #pragma unroll
    for (int j = 0; j < 4; j++){
      int col = n0 + wn*64 + j*16 + r16;
      float bias = bo[col];
      #pragma unroll
      for (int r = 0; r < 4; r++){
        int row = m0 + wm*64 + i*16 + rg*4 + r;   // row = b*64 + t
        out[(size_t)row*Vz + col] = acc[i][j][r] + bias;
      }
    }
}

// ---------------- final h,c copy ----------------
__global__ __launch_bounds__(256) void copy_hc_v3(const float* __restrict__ h0fin,
    const float* __restrict__ h1fin, const float* __restrict__ cbuf,
    float* __restrict__ out_hc){
  int i = blockIdx.x*256 + threadIdx.x;   // grid 256 -> 65536
  float v;
  if (i < 16384)      v = h0fin[i];
  else if (i < 32768) v = h1fin[i-16384];
  else                v = cbuf[i-32768];
  out_hc[i] = v;
}

extern "C" void kernel_launch(void* const* d_in, const int* in_sizes, int n_in,
                              void* d_out, int out_size, void* d_ws, size_t ws_size,
                              hipStream_t stream){
  const int*   tgt = (const int*)  d_in[0];
  const float* h0  = (const float*)d_in[1];
  const float* c0  = (const float*)d_in[2];
  const float* enc = (const float*)d_in[3];
  const float* emb = (const float*)d_in[4];
  const float* Wih = (const float*)d_in[5];
  const float* Whh = (const float*)d_in[6];
  const float* bih = (const float*)d_in[7];
  const float* bhh = (const float*)d_in[8];
  const float* Wc  = (const float*)d_in[9];
  const float* bc  = (const float*)d_in[10];
  const float* Wo  = (const float*)d_in[11];
  const float* bo  = (const float*)d_in[12];
  float* out = (float*)d_out;

  // workspace layout (floats)
  float* x0g  = (float*)d_ws;                 // 4,194,304
  float* h0p  = x0g  + 4194304;               // 32,768  [2][16384]
  float* h1p  = h0p  + 32768;                 // 65,536  [4][16384]
  float* cbuf = h1p  + 65536;                 // 32,768  [2][16384]
  float* ctx2 = cbuf + 32768;                 // 32,768  [2][16384]
  float* Wp0  = ctx2 + 32768;                 // 1,048,576
  float* Wp1  = Wp0  + 1048576;               // 2,097,152
  unsigned int* bar = (unsigned int*)(Wp1 + 2097152);           // 512 words
  unsigned short* oa    = (unsigned short*)(bar + 512);         // 1,048,576 us [b][t][u]
  unsigned short* wo_bf = oa + 1048576;       // 16,384,000 us (32MB)

  const int DLDS_BYTES = 34952 * 4;           // 139.8 KB dynamic LDS
  hipFuncSetAttribute((const void*)decoder_persist_v5,
      hipFuncAttributeMaxDynamicSharedMemorySize, DLDS_BYTES);

  init_state_v5<<<128, 256, 0, stream>>>(h0, h0p, h1p, bar);
  conv_bf16_kernel<<<16000, 256, 0, stream>>>(Wo, wo_bf);
  pack_l0_v3<<<1024, 256, 0, stream>>>(Whh, Wp0);
  pack_l1_v3<<<2048, 256, 0, stream>>>(Wih + (size_t)G4*Hz, Whh + (size_t)G4*Hz, Wp1);
  x0g_v2<<<dim3(32, 32), 256, 0, stream>>>(tgt, emb, Wih, bih, bhh, x0g);

  decoder_persist_v5<<<NBLK, 512, DLDS_BYTES, stream>>>(
      Wp0, Wp1, Wc, x0g, bih + G4, bhh + G4, bc, c0, enc,
      h0p, h1p, cbuf, ctx2, (unsigned int*)oa, bar);

  pred_gemm_v2<<<4096, 256, 0, stream>>>(oa, wo_bf, bo, out);
  copy_hc_v3<<<256, 256, 0, stream>>>(h0p + 16384, h1p + 3*16384, cbuf,
                                      out + (size_t)Bz*Tz*Vz);

  (void)in_sizes; (void)n_in; (void)out_size; (void)ws_size;
}

// Round 7
// 3407.639 us; speedup vs baseline: 2.8518x; 1.0448x over previous
//
#include <hip/hip_runtime.h>
#include <hip/hip_bf16.h>

#define Bz 32
#define Tz 64
#define Sz 128
#define Hz 512
#define Vz 32000
#define G4 2048
#define NBLK 256
#define NPH 67

#define A_RLX __ATOMIC_RELAXED
#define A_ACQ __ATOMIC_ACQUIRE
#define SC_AG __HIP_MEMORY_SCOPE_AGENT

using bf16x8 = __attribute__((ext_vector_type(8))) short;
using f32x4  = __attribute__((ext_vector_type(4))) float;

__device__ __forceinline__ unsigned short f2bf(float f){
  unsigned int u = __float_as_uint(f);
  u += 0x7fffu + ((u >> 16) & 1u);
  return (unsigned short)(u >> 16);
}
__device__ __forceinline__ float sigf(float x){ return 1.f/(1.f + expf(-x)); }

__device__ __forceinline__ void stc(float* p, float v){
  __hip_atomic_store(p, v, A_RLX, SC_AG);
}

// ---------------- grid barrier: tree, every polled word has exactly ONE poller ----------------
// words: arrive member m of group g -> bar[g*16+m] (m=1..15), leader line per group
//        root line: bar[256+g] (g=0..15)
//        release leader g: bar[320 + g*16]
//        release member bid: bar[576 + bid*16]
__device__ __forceinline__ void gbar(unsigned* bar, int bid, unsigned* ep){
  asm volatile("s_waitcnt vmcnt(0)" ::: "memory");   // drain this thread's stores
  __syncthreads();                                    // whole block drained
  const unsigned e = ++(*ep);
  const int tid = threadIdx.x;
  const int g = bid >> 4, m = bid & 15;
  if (m != 0){
    if (tid == 0){
      __hip_atomic_store(&bar[g*16 + m], e, A_RLX, SC_AG);
      while (__hip_atomic_load(&bar[576 + bid*16], A_RLX, SC_AG) != e)
        __builtin_amdgcn_s_sleep(1);
    }
  } else {
    // leader: threads 1..15 poll member words in parallel
    if (tid >= 1 && tid <= 15){
      while (__hip_atomic_load(&bar[g*16 + tid], A_RLX, SC_AG) != e)
        __builtin_amdgcn_s_sleep(1);
    }
    __syncthreads();
    if (bid == 0){
      if (tid == 0) __hip_atomic_store(&bar[256 + 0], e, A_RLX, SC_AG);
      if (tid < 16){
        while (__hip_atomic_load(&bar[256 + tid], A_RLX, SC_AG) != e)
          __builtin_amdgcn_s_sleep(1);
      }
      __syncthreads();
      if (tid < 16) __hip_atomic_store(&bar[320 + tid*16], e, A_RLX, SC_AG);
    } else {
      if (tid == 0){
        __hip_atomic_store(&bar[256 + g], e, A_RLX, SC_AG);
        while (__hip_atomic_load(&bar[320 + g*16], A_RLX, SC_AG) != e)
          __builtin_amdgcn_s_sleep(1);
      }
      __syncthreads();
    }
    if (tid < 16) __hip_atomic_store(&bar[576 + (g*16 + tid)*16], e, A_RLX, SC_AG);
    if (tid == 0){
      while (__hip_atomic_load(&bar[576 + bid*16], A_RLX, SC_AG) != e)
        __builtin_amdgcn_s_sleep(1);
    }
  }
  __syncthreads();
  if ((tid & 63) == 0)                               // one acquire (inv) per wave
    (void)__hip_atomic_load(&bar[576], A_ACQ, SC_AG);
  __builtin_amdgcn_sched_barrier(0);
  __syncthreads();
}

// ---------------- register transpose-reduce: 64 lanes x 32 accs -> lane holds b=lane&31 sum ----
__device__ __forceinline__ void xreduce(float (&a)[32], int lane){
  #pragma unroll
  for (int j = 0; j < 32; j++) a[j] += __shfl_xor(a[j], 32);
  #pragma unroll
  for (int st = 0; st < 5; st++){
    const int o = 16 >> st;
    bool hi = (lane & o) != 0;
    float tmp[16];
    #pragma unroll
    for (int j = 0; j < o; j++){
      float lo_v = a[j], hi_v = a[j + o];
      float sent = hi ? lo_v : hi_v;
      float recv = __shfl_xor(sent, o);
      tmp[j] = (hi ? hi_v : lo_v) + recv;
    }
    #pragma unroll
    for (int j = 0; j < o; j++) a[j] = tmp[j];
  }
}

// ---------------- dual LDS staging: all 16 loads issued before LDS writes ----------------
__device__ __forceinline__ void stage2(float* dA, const float* sA,
                                       float* dB, const float* sB, int tid){
  const float4* a4 = (const float4*)sA;
  const float4* b4 = (const float4*)sB;
  float4 ra[8], rb[8];
  #pragma unroll
  for (int i = 0; i < 8; i++) ra[i] = a4[tid + i*512];
  #pragma unroll
  for (int i = 0; i < 8; i++) rb[i] = b4[tid + i*512];
  float4* dA4 = (float4*)dA; float4* dB4 = (float4*)dB;
  #pragma unroll
  for (int i = 0; i < 8; i++){ int idx = tid + i*512; dA4[idx + ((idx >> 7) << 1)] = ra[i]; }
  #pragma unroll
  for (int i = 0; i < 8; i++){ int idx = tid + i*512; dB4[idx + ((idx >> 7) << 1)] = rb[i]; }
}

// ---------------- init ----------------
__global__ __launch_bounds__(256) void init_state_v6(const float* __restrict__ h0,
    float* __restrict__ h0p, float* __restrict__ h1p, unsigned int* __restrict__ bar){
  int i = blockIdx.x*256 + threadIdx.x;   // grid 128 -> 32768
  if (i < 16384) h0p[16384 + i] = h0[i];            // h0(-1) -> slot 1
  else           h1p[3*16384 + (i - 16384)] = h0[i]; // h1(-1) -> slot 3
  if (i < 4704) bar[i] = 0u;
}

// ---------------- Wo -> bf16 ----------------
__global__ __launch_bounds__(256) void conv_bf16_kernel(const float* __restrict__ src,
    unsigned short* __restrict__ dst){
  int i = (blockIdx.x*256 + threadIdx.x)*4;
  float4 v = *(const float4*)(src + i);
  ushort4 o;
  o.x = f2bf(v.x); o.y = f2bf(v.y); o.z = f2bf(v.z); o.w = f2bf(v.w);
  *(ushort4*)(dst + i) = o;
}

// ---------------- weight packs: row-major, rows r = u*4+gate ----------------
__global__ __launch_bounds__(256) void pack_l0_v3(const float* __restrict__ W,
    float* __restrict__ out){
  int idx4 = blockIdx.x*256 + threadIdx.x;
  int r = idx4 >> 7, k4 = idx4 & 127;
  int srow = (r & 3)*Hz + (r >> 2);
  ((float4*)out)[idx4] = ((const float4*)W)[srow*128 + k4];
}
__global__ __launch_bounds__(256) void pack_l1_v3(const float* __restrict__ Wi,
    const float* __restrict__ Wh, float* __restrict__ out){
  int idx4 = blockIdx.x*256 + threadIdx.x;
  int r = idx4 >> 8, k4 = idx4 & 255;
  int srow = (r & 3)*Hz + (r >> 2);
  float4 v = (k4 < 128) ? ((const float4*)Wi)[srow*128 + k4]
                        : ((const float4*)Wh)[srow*128 + (k4 - 128)];
  ((float4*)out)[idx4] = v;
}

// ---------------- x0g: tiled fp32 GEMM, OUTPUT TRANSPOSED [t][col][b] ----------------
__global__ __launch_bounds__(256) void x0g_v3(const int* __restrict__ tgt,
    const float* __restrict__ emb, const float* __restrict__ W,
    const float* __restrict__ bi, const float* __restrict__ bh,
    float* __restrict__ out){
  __shared__ float As[32][68], Bs[32][68];
  __shared__ int tok_s[64];
  int tid = threadIdx.x;
  int m0 = blockIdx.y*64, n0 = blockIdx.x*64;
  if (tid < 64){ int tb = m0 + tid; tok_s[tid] = tgt[(tb & 31)*Tz + (tb >> 5)]; }
  __syncthreads();
  int lm = tid >> 2, lk = (tid & 3)*8;
  int ty = tid >> 4, tx = tid & 15;
  float acc[4][4] = {{0.f}};
  for (int kt = 0; kt < 16; kt++){
    float4 a0 = *(const float4*)(emb + (size_t)tok_s[lm]*Hz + kt*32 + lk);
    float4 a1 = *(const float4*)(emb + (size_t)tok_s[lm]*Hz + kt*32 + lk + 4);
    float4 b0 = *(const float4*)(W   + (size_t)(n0+lm)*Hz + kt*32 + lk);
    float4 b1 = *(const float4*)(W   + (size_t)(n0+lm)*Hz + kt*32 + lk + 4);
    __syncthreads();
    As[lk+0][lm]=a0.x; As[lk+1][lm]=a0.y; As[lk+2][lm]=a0.z; As[lk+3][lm]=a0.w;
    As[lk+4][lm]=a1.x; As[lk+5][lm]=a1.y; As[lk+6][lm]=a1.z; As[lk+7][lm]=a1.w;
    Bs[lk+0][lm]=b0.x; Bs[lk+1][lm]=b0.y; Bs[lk+2][lm]=b0.z; Bs[lk+3][lm]=b0.w;
    Bs[lk+4][lm]=b1.x; Bs[lk+5][lm]=b1.y; Bs[lk+6][lm]=b1.z; Bs[lk+7][lm]=b1.w;
    __syncthreads();
    #pragma unroll
    for (int k = 0; k < 32; k++){
      float4 av = *(const float4*)&As[k][ty*4];
      float4 bv = *(const float4*)&Bs[k][tx*4];
      acc[0][0]+=av.x*bv.x; acc[0][1]+=av.x*bv.y; acc[0][2]+=av.x*bv.z; acc[0][3]+=av.x*bv.w;
      acc[1][0]+=av.y*bv.x; acc[1][1]+=av.y*bv.y; acc[1][2]+=av.y*bv.z; acc[1][3]+=av.y*bv.w;
      acc[2][0]+=av.z*bv.x; acc[2][1]+=av.z*bv.y; acc[2][2]+=av.z*bv.z; acc[2][3]+=av.z*bv.w;
      acc[3][0]+=av.w*bv.x; acc[3][1]+=av.w*bv.y; acc[3][2]+=av.w*bv.z; acc[3][3]+=av.w*bv.w;
    }
  }
  #pragma unroll
  for (int j = 0; j < 4; j++){
    int col = n0 + tx*4 + j;
    float bias = bi[col] + bh[col];
    #pragma unroll
    for (int i = 0; i < 4; i++){
      int tb = m0 + ty*4 + i;
      int tt = tb >> 5, bb = tb & 31;
      out[((size_t)tt*2048 + col)*32 + bb] = acc[i][j] + bias;
    }
  }
}

// ---------------- persistent decoder v6: skewed pipeline, tree barrier ----------------
// phase tau: l0(tau) | l1(tau-1) | attnA(tau-2) | attnB(tau-3)
__global__ __launch_bounds__(512, 1) void decoder_persist_v6(
    const float* __restrict__ Wp0, const float* __restrict__ Wp1,
    const float* __restrict__ Wc,  const float* __restrict__ x0gT,
    const float* __restrict__ bi1, const float* __restrict__ bh1,
    const float* __restrict__ bc,  const float* __restrict__ c0in,
    const float* __restrict__ enc,
    float* __restrict__ h0p,   // [2][16384]
    float* __restrict__ h1p,   // [4][16384]
    float* __restrict__ cbuf,  // [2][16384] (final c out)
    float* __restrict__ ctx2,  // [2][16384]
    unsigned* __restrict__ oa32, unsigned* __restrict__ bar){
  extern __shared__ float sm[];
  float* hstA = sm;              // [32][520] 16640 (also attnA ctx-partial scratch)
  float* hstB = sm + 16640;      // [32][520] 16640
  float* gsA  = sm + 33280;      // 512
  float* gsB  = sm + 33792;      // 512
  float* gsw  = sm + 34304;      // 512
  float* ea   = sm + 34816;      // 128
  float* red  = sm + 34944;      // 8
  float4* hA4 = (float4*)hstA;
  float4* hB4 = (float4*)hstB;

  const int bid = blockIdx.x, tid = threadIdx.x;
  const int w4 = tid >> 6, lane = tid & 63;
  const int kh = w4 >> 2, rpair = w4 & 3;
  const int r0 = bid*8 + rpair*2, r1 = r0 + 1;
  const int u0 = bid*2, u1 = u0 + 1;
  unsigned ep = 0;

  // ---- persistent weights -> VGPRs ----
  const float4* Wp0_4 = (const float4*)Wp0;
  const float4* Wp1_4 = (const float4*)Wp1;
  float4 w0A  = Wp0_4[r0*128 + kh*64 + lane];
  float4 w0B  = Wp0_4[r1*128 + kh*64 + lane];
  float4 w1xA = Wp1_4[r0*256 +       kh*64 + lane];
  float4 w1xB = Wp1_4[r1*256 +       kh*64 + lane];
  float4 w1hA = Wp1_4[r0*256 + 128 + kh*64 + lane];
  float4 w1hB = Wp1_4[r1*256 + 128 + kh*64 + lane];
  float wcA0 = Wc[(size_t)u0*1024 + tid];
  float wcB0 = Wc[(size_t)u1*1024 + tid];
  float wcA1 = Wc[(size_t)u0*1024 + 512 + tid];
  float wcB1 = Wc[(size_t)u1*1024 + 512 + tid];
  float bs_i=0.f, bs_f=0.f, bs_g=0.f, bs_o=0.f, bcv=0.f;
  float c0_reg=0.f, c1_reg=0.f;
  if (tid < 64){
    int ul = tid >> 5, b = tid & 31, u = bid*2 + ul;
    bs_i = bi1[u]        + bh1[u];
    bs_f = bi1[512+u]    + bh1[512+u];
    bs_g = bi1[1024+u]   + bh1[1024+u];
    bs_o = bi1[1536+u]   + bh1[1536+u];
    bcv  = bc[u];
    c0_reg = c0in[b*512 + u];
    c1_reg = c0in[16384 + b*512 + u];
  }
  __syncthreads();

  for (int tau = 0; tau < NPH; ++tau){
    // ---- stage h0(tau-1)->hstA, h1(tau-2)->hstB ----
    stage2(hstA, h0p + ((tau+1)&1)*16384, hstB, h1p + ((tau+2)&3)*16384, tid);
    // ---- x0gT(tau) prefetch: coalesced over b ----
    float xgi=0.f, xgf=0.f, xgg=0.f, xgo=0.f;
    if (tau < 64 && tid < 64){
      int b = tid & 31, u = bid*2 + (tid >> 5);
      const float* xg = x0gT + (size_t)tau*2048*32;
      xgi = xg[(u       )*32 + b];
      xgf = xg[(512  + u)*32 + b];
      xgg = xg[(1024 + u)*32 + b];
      xgo = xg[(1536 + u)*32 + b];
    }
    // ---- attnB(tau-3): global reads (coalesced per b) ----
    if (tau >= 3){
      const float* h1g = h1p + ((tau+1)&3)*16384;
      const float* ctg = ctx2 + ((tau+1)&1)*16384;
      float wa0[32], wa1[32];
      #pragma unroll
      for (int b = 0; b < 32; b++){
        float hv = h1g[b*512 + tid];
        float cv = ctg[b*512 + tid];
        wa0[b] = fmaf(hv, wcA0, cv*wcA1);
        wa1[b] = fmaf(hv, wcB0, cv*wcB1);
      }
      xreduce(wa0, lane); xreduce(wa1, lane);
      gsw[w4*64 + (lane >= 32 ? 32 : 0) + (lane & 31)] = (lane < 32) ? wa0[0] : wa1[0];
    }
    __syncthreads();
    // ---- combined gemv: l0(tau) rows + l1(tau-1) rows ----
    {
      float aL0A[32], aL0B[32], aL1A[32], aL1B[32];
      #pragma unroll
      for (int b = 0; b < 32; b++){ aL0A[b]=0.f; aL0B[b]=0.f; aL1A[b]=0.f; aL1B[b]=0.f; }
      const float4* pA = hA4 + kh*64 + lane;
      const float4* pB = hB4 + kh*64 + lane;
      #pragma unroll
      for (int b = 0; b < 32; b++){
        float4 ha = pA[b*130];
        float4 hb = pB[b*130];
        aL0A[b] = fmaf(ha.x,w0A.x, fmaf(ha.y,w0A.y, fmaf(ha.z,w0A.z, fmaf(ha.w,w0A.w, aL0A[b]))));
        aL0B[b] = fmaf(ha.x,w0B.x, fmaf(ha.y,w0B.y, fmaf(ha.z,w0B.z, fmaf(ha.w,w0B.w, aL0B[b]))));
        float t1 = fmaf(ha.x,w1xA.x, fmaf(ha.y,w1xA.y, fmaf(ha.z,w1xA.z, fmaf(ha.w,w1xA.w, aL1A[b]))));
        aL1A[b] = fmaf(hb.x,w1hA.x, fmaf(hb.y,w1hA.y, fmaf(hb.z,w1hA.z, fmaf(hb.w,w1hA.w, t1))));
        float t2 = fmaf(ha.x,w1xB.x, fmaf(ha.y,w1xB.y, fmaf(ha.z,w1xB.z, fmaf(ha.w,w1xB.w, aL1B[b]))));
        aL1B[b] = fmaf(hb.x,w1hB.x, fmaf(hb.y,w1hB.y, fmaf(hb.z,w1hB.z, fmaf(hb.w,w1hB.w, t2))));
      }
      xreduce(aL0A, lane); xreduce(aL0B, lane);
      gsA[kh*256 + (rpair*2 + (lane >= 32 ? 1 : 0))*32 + (lane & 31)] = (lane < 32) ? aL0A[0] : aL0B[0];
      xreduce(aL1A, lane); xreduce(aL1B, lane);
      gsB[kh*256 + (rpair*2 + (lane >= 32 ? 1 : 0))*32 + (lane & 31)] = (lane < 32) ? aL1A[0] : aL1B[0];
    }
    __syncthreads();
    // ---- cells + attnB finalize (tid<64) ----
    if (tid < 64){
      int ul = tid >> 5, b = tid & 31, u = bid*2 + ul, rl = ul*4;
      if (tau < 64){
        float gi = gsA[(rl+0)*32+b] + gsA[256+(rl+0)*32+b] + xgi;
        float gf = gsA[(rl+1)*32+b] + gsA[256+(rl+1)*32+b] + xgf;
        float gg = gsA[(rl+2)*32+b] + gsA[256+(rl+2)*32+b] + xgg;
        float go = gsA[(rl+3)*32+b] + gsA[256+(rl+3)*32+b] + xgo;
        float cn = sigf(gf)*c0_reg + sigf(gi)*tanhf(gg);
        c0_reg = cn;
        stc(h0p + (tau&1)*16384 + b*512 + u, sigf(go)*tanhf(cn));
      }
      if (tau >= 1 && tau <= 64){
        float gi = gsB[(rl+0)*32+b] + gsB[256+(rl+0)*32+b] + bs_i;
        float gf = gsB[(rl+1)*32+b] + gsB[256+(rl+1)*32+b] + bs_f;
        float gg = gsB[(rl+2)*32+b] + gsB[256+(rl+2)*32+b] + bs_g;
        float go = gsB[(rl+3)*32+b] + gsB[256+(rl+3)*32+b] + bs_o;
        float cn = sigf(gf)*c1_reg + sigf(gi)*tanhf(gg);
        c1_reg = cn;
        stc(h1p + ((tau-1)&3)*16384 + b*512 + u, sigf(go)*tanhf(cn));
      }
      if (tau >= 3){
        float s = bcv;
        #pragma unroll
        for (int w = 0; w < 8; w++) s += gsw[w*64 + ul*32 + b];
        unsigned short me = f2bf(tanhf(s));
        unsigned other = (unsigned)__shfl((int)(unsigned)me, tid + 32);
        if (tid < 32)
          __hip_atomic_store(oa32 + ((size_t)b*Tz + (tau-3))*256 + bid,
                             ((unsigned)me) | (other << 16), A_RLX, SC_AG);
      }
    }
    // ---- attnA(tau-2) on blocks 0..31 (hstB = h1(tau-2)) ----
    if (bid < 32 && tau >= 2 && tau <= 65){
      {
        int s = tid >> 2, q = tid & 3;
        const float4* e4 = (const float4*)(enc + ((size_t)bid*Sz + s)*Hz) + q*32;
        const float4* h4 = hB4 + bid*130 + q*32;
        float a = 0.f;
        #pragma unroll 16
        for (int i = 0; i < 32; i++){
          float4 e = e4[i], h = h4[i];
          a += e.x*h.x + e.y*h.y + e.z*h.z + e.w*h.w;
        }
        a += __shfl_xor(a, 1); a += __shfl_xor(a, 2);
        if (q == 0) ea[s] = a;
      }
      __syncthreads();
      if (tid < 64){
        float v = fmaxf(ea[tid], ea[tid+64]);
        #pragma unroll
        for (int o = 32; o; o >>= 1) v = fmaxf(v, __shfl_xor(v, o));
        if (tid == 0) red[0] = v;
      }
      __syncthreads();
      if (tid < 128) ea[tid] = expf(ea[tid] - red[0]);
      __syncthreads();
      if (tid < 64){
        float v = ea[tid] + ea[tid+64];
        #pragma unroll
        for (int o = 32; o; o >>= 1) v += __shfl_xor(v, o);
        if (tid == 0) red[1] = v;
      }
      __syncthreads();
      {   // context: 4 s-groups x 128 k4-threads, partials in hstA (free now)
        int sg = tid >> 7, kk = tid & 127;
        const float4* epp = (const float4*)(enc + (size_t)bid*Sz*Hz) + kk;
        float4 c = {0.f, 0.f, 0.f, 0.f};
        #pragma unroll 16
        for (int i = 0; i < 32; i++){
          int s = sg*32 + i;
          float4 ev = epp[(size_t)s*128];
          float pr = ea[s];
          c.x = fmaf(pr, ev.x, c.x); c.y = fmaf(pr, ev.y, c.y);
          c.z = fmaf(pr, ev.z, c.z); c.w = fmaf(pr, ev.w, c.w);
        }
        ((float4*)hstA)[sg*128 + kk] = c;
      }
      __syncthreads();
      if (tid < 128){
        float4 p0 = ((float4*)hstA)[tid],       p1 = ((float4*)hstA)[128 + tid];
        float4 p2 = ((float4*)hstA)[256 + tid], p3 = ((float4*)hstA)[384 + tid];
        float inv = 1.f/red[1];
        float* dst = ctx2 + (tau&1)*16384 + bid*512 + tid*4;
        stc(dst + 0, (p0.x+p1.x+p2.x+p3.x)*inv);
        stc(dst + 1, (p0.y+p1.y+p2.y+p3.y)*inv);
        stc(dst + 2, (p0.z+p1.z+p2.z+p3.z)*inv);
        stc(dst + 3, (p0.w+p1.w+p2.w+p3.w)*inv);
      }
    }
    gbar(bar, bid, &ep);
  }
  // ---- final c writeback ----
  if (tid < 64){
    int ul = tid >> 5, b = tid & 31, u = bid*2 + ul;
    cbuf[b*512 + u] = c0_reg;
    cbuf[16384 + b*512 + u] = c1_reg;
  }
}

// ---------------- pred GEMM: XCD-pinned + swizzled LDS ----------------
__global__ __launch_bounds__(256) void pred_gemm_v2(const unsigned short* __restrict__ A,
    const unsigned short* __restrict__ Bm, const float* __restrict__ bo,
    float* __restrict__ out){
  __shared__ unsigned short As[128*32];
  __shared__ unsigned short Bs[128*32];
  int bid = blockIdx.x;
  int xcd = bid & 7, lin = bid >> 3;
  int ntile = xcd*32 + (lin & 31);
  int mtile = lin >> 5;
  if (ntile >= 250) return;
  int n0 = ntile*128, m0 = mtile*128;
  int tid = threadIdx.x, lane = tid & 63, wid = tid >> 6;
  f32x4 acc[4][4];
  #pragma unroll
  for (int i = 0; i < 4; i++)
    #pragma unroll
    for (int j = 0; j < 4; j++)
      #pragma unroll
      for (int r = 0; r < 4; r++) acc[i][j][r] = 0.f;

  int wm = wid >> 1, wn = wid & 1;
  int r16 = lane & 15, kgr = lane >> 4;

  for (int kt = 0; kt < Hz/32; kt++){
    __syncthreads();
    #pragma unroll
    for (int call = 0; call < 2; call++){
      int c = call*256 + tid;
      int row = c >> 2, kg = c & 3;
      int kgs = kg ^ ((row >> 1) & 3);
      *(int4*)&As[row*32 + kgs*8] = *(const int4*)(A  + (size_t)(m0+row)*Hz + kt*32 + kg*8);
      *(int4*)&Bs[row*32 + kgs*8] = *(const int4*)(Bm + (size_t)(n0+row)*Hz + kt*32 + kg*8);
    }
    __syncthreads();
    bf16x8 aF[4], bF[4];
    #pragma unroll
    for (int i = 0; i < 4; i++){
      int ra = wm*64 + i*16 + r16;
      int rb = wn*64 + i*16 + r16;
      aF[i] = *(const bf16x8*)&As[ra*32 + (kgr ^ ((ra>>1)&3))*8];
      bF[i] = *(const bf16x8*)&Bs[rb*32 + (kgr ^ ((rb>>1)&3))*8];
    }
    #pragma unroll
    for (int i = 0; i < 4; i++)
      #pragma unroll
      for (int j = 0; j < 4; j++)
        acc[i][j] = __builtin_amdgcn_mfma_f32_16x16x32_bf16(aF[i], bF[j], acc[i][j], 0, 0, 0);
  }

  int rg = lane >> 4;
  #pragma unroll
  for (int i = 0; i < 4; i++)
    #pragma unroll
    for (int j = 0; j < 4; j++){
      int col = n0 + wn*64 + j*16 + r16;
      float bias = bo[col];
      #pragma unroll
      for (int r = 0; r < 4; r++){
        int row = m0 + wm*64 + i*16 + rg*4 + r;   // row = b*64 + t
        out[(size_t)row*Vz + col] = acc[i][j][r] + bias;
      }
    }
}

// ---------------- final h,c copy ----------------
__global__ __launch_bounds__(256) void copy_hc_v3(const float* __restrict__ h0fin,
    const float* __restrict__ h1fin, const float* __restrict__ cbuf,
    float* __restrict__ out_hc){
  int i = blockIdx.x*256 + threadIdx.x;
  float v;
  if (i < 16384)      v = h0fin[i];
  else if (i < 32768) v = h1fin[i-16384];
  else                v = cbuf[i-32768];
  out_hc[i] = v;
}

extern "C" void kernel_launch(void* const* d_in, const int* in_sizes, int n_in,
                              void* d_out, int out_size, void* d_ws, size_t ws_size,
                              hipStream_t stream){
  const int*   tgt = (const int*)  d_in[0];
  const float* h0  = (const float*)d_in[1];
  const float* c0  = (const float*)d_in[2];
  const float* enc = (const float*)d_in[3];
  const float* emb = (const float*)d_in[4];
  const float* Wih = (const float*)d_in[5];
  const float* Whh = (const float*)d_in[6];
  const float* bih = (const float*)d_in[7];
  const float* bhh = (const float*)d_in[8];
  const float* Wc  = (const float*)d_in[9];
  const float* bc  = (const float*)d_in[10];
  const float* Wo  = (const float*)d_in[11];
  const float* bo  = (const float*)d_in[12];
  float* out = (float*)d_out;

  // workspace layout (floats)
  float* x0g  = (float*)d_ws;                 // 4,194,304  [t][col][b]
  float* h0p  = x0g  + 4194304;               // 32,768  [2][16384]
  float* h1p  = h0p  + 32768;                 // 65,536  [4][16384]
  float* cbuf = h1p  + 65536;                 // 32,768  [2][16384]
  float* ctx2 = cbuf + 32768;                 // 32,768  [2][16384]
  float* Wp0  = ctx2 + 32768;                 // 1,048,576
  float* Wp1  = Wp0  + 1048576;               // 2,097,152
  unsigned int* bar = (unsigned int*)(Wp1 + 2097152);           // 4704 words
  unsigned short* oa    = (unsigned short*)(bar + 4704);        // 1,048,576 us [b][t][u]
  unsigned short* wo_bf = oa + 1048576;       // 16,384,000 us (32MB)

  const int DLDS_BYTES = 34952 * 4;           // 139.8 KB dynamic LDS
  hipFuncSetAttribute((const void*)decoder_persist_v6,
      hipFuncAttributeMaxDynamicSharedMemorySize, DLDS_BYTES);

  init_state_v6<<<128, 256, 0, stream>>>(h0, h0p, h1p, bar);
  conv_bf16_kernel<<<16000, 256, 0, stream>>>(Wo, wo_bf);
  pack_l0_v3<<<1024, 256, 0, stream>>>(Whh, Wp0);
  pack_l1_v3<<<2048, 256, 0, stream>>>(Wih + (size_t)G4*Hz, Whh + (size_t)G4*Hz, Wp1);
  x0g_v3<<<dim3(32, 32), 256, 0, stream>>>(tgt, emb, Wih, bih, bhh, x0g);

  decoder_persist_v6<<<NBLK, 512, DLDS_BYTES, stream>>>(
      Wp0, Wp1, Wc, x0g, bih + G4, bhh + G4, bc, c0, enc,
      h0p, h1p, cbuf, ctx2, (unsigned int*)oa, bar);

  pred_gemm_v2<<<4096, 256, 0, stream>>>(oa, wo_bf, bo, out);
  copy_hc_v3<<<256, 256, 0, stream>>>(h0p + 16384, h1p + 3*16384, cbuf,
                                      out + (size_t)Bz*Tz*Vz);

  (void)in_sizes; (void)n_in; (void)out_size; (void)ws_size;
}

// Round 8
// 1189.930 us; speedup vs baseline: 8.1667x; 2.8637x over previous
//
#include <hip/hip_runtime.h>
#include <hip/hip_bf16.h>

#define Bz 32
#define Tz 64
#define Sz 128
#define Hz 512
#define Vz 32000
#define G4 2048
#define NBLK 256
#define NPH 65

#define A_RLX __ATOMIC_RELAXED
#define SC_AG __HIP_MEMORY_SCOPE_AGENT

using bf16x8 = __attribute__((ext_vector_type(8))) short;
using f32x4  = __attribute__((ext_vector_type(4))) float;

__device__ __forceinline__ unsigned short f2bf(float f){
  unsigned int u = __float_as_uint(f);
  u += 0x7fffu + ((u >> 16) & 1u);
  return (unsigned short)(u >> 16);
}
__device__ __forceinline__ float sigf(float x){ return 1.f/(1.f + expf(-x)); }

__device__ __forceinline__ void stc(float* p, float v){
  __hip_atomic_store(p, v, A_RLX, SC_AG);
}
__device__ __forceinline__ float ldc(const float* p){
  return __hip_atomic_load(p, A_RLX, SC_AG);
}

// ---------------- grid barrier: tree, single-writer words, NO cache invalidate ----------------
// (all cross-block data is read via sc1 loads, so no acquire/inv is needed)
__device__ __forceinline__ void gbar(unsigned* bar, int bid, unsigned* ep){
  asm volatile("s_waitcnt vmcnt(0)" ::: "memory");   // drain this thread's stores
  __syncthreads();                                    // whole block drained
  const unsigned e = ++(*ep);
  const int tid = threadIdx.x;
  const int g = bid >> 4, m = bid & 15;
  if (m != 0){
    if (tid == 0){
      __hip_atomic_store(&bar[g*16 + m], e, A_RLX, SC_AG);
      while (__hip_atomic_load(&bar[576 + bid*16], A_RLX, SC_AG) != e)
        __builtin_amdgcn_s_sleep(1);
    }
  } else {
    if (tid >= 1 && tid <= 15){
      while (__hip_atomic_load(&bar[g*16 + tid], A_RLX, SC_AG) != e)
        __builtin_amdgcn_s_sleep(1);
    }
    __syncthreads();
    if (bid == 0){
      if (tid == 0) __hip_atomic_store(&bar[256 + 0], e, A_RLX, SC_AG);
      if (tid < 16){
        while (__hip_atomic_load(&bar[256 + tid], A_RLX, SC_AG) != e)
          __builtin_amdgcn_s_sleep(1);
      }
      __syncthreads();
      if (tid < 16) __hip_atomic_store(&bar[320 + tid*16], e, A_RLX, SC_AG);
    } else {
      if (tid == 0){
        __hip_atomic_store(&bar[256 + g], e, A_RLX, SC_AG);
        while (__hip_atomic_load(&bar[320 + g*16], A_RLX, SC_AG) != e)
          __builtin_amdgcn_s_sleep(1);
      }
      __syncthreads();
    }
    if (tid < 16) __hip_atomic_store(&bar[576 + (g*16 + tid)*16], e, A_RLX, SC_AG);
    if (tid == 0){
      while (__hip_atomic_load(&bar[576 + bid*16], A_RLX, SC_AG) != e)
        __builtin_amdgcn_s_sleep(1);
    }
  }
  __syncthreads();
  __builtin_amdgcn_sched_barrier(0);
}

// ---------------- register transpose-reduce ----------------
__device__ __forceinline__ void xreduce(float (&a)[32], int lane){
  #pragma unroll
  for (int j = 0; j < 32; j++) a[j] += __shfl_xor(a[j], 32);
  #pragma unroll
  for (int st = 0; st < 5; st++){
    const int o = 16 >> st;
    bool hi = (lane & o) != 0;
    float tmp[16];
    #pragma unroll
    for (int j = 0; j < o; j++){
      float lo_v = a[j], hi_v = a[j + o];
      float sent = hi ? lo_v : hi_v;
      float recv = __shfl_xor(sent, o);
      tmp[j] = (hi ? hi_v : lo_v) + recv;
    }
    #pragma unroll
    for (int j = 0; j < o; j++) a[j] = tmp[j];
  }
}

// ---------------- dual LDS staging via coherent (sc1) dword loads ----------------
__device__ __forceinline__ void stage2c(float* dA, const float* sA,
                                        float* dB, const float* sB, int tid){
  #pragma unroll
  for (int h = 0; h < 2; h++){
    float ra[16], rb[16];
    #pragma unroll
    for (int i = 0; i < 16; i++) ra[i] = ldc(sA + tid + (h*16 + i)*512);
    #pragma unroll
    for (int i = 0; i < 16; i++) rb[i] = ldc(sB + tid + (h*16 + i)*512);
    #pragma unroll
    for (int i = 0; i < 16; i++){
      int f = tid + (h*16 + i)*512;
      dA[(f >> 9)*520 + (f & 511)] = ra[i];
    }
    #pragma unroll
    for (int i = 0; i < 16; i++){
      int f = tid + (h*16 + i)*512;
      dB[(f >> 9)*520 + (f & 511)] = rb[i];
    }
  }
}

// ---------------- init ----------------
__global__ __launch_bounds__(256) void init_state_v7(const float* __restrict__ h0,
    float* __restrict__ h0p, float* __restrict__ h1p, unsigned int* __restrict__ bar){
  int i = blockIdx.x*256 + threadIdx.x;   // grid 128 -> 32768
  if (i < 16384) h0p[16384 + i] = h0[i];            // h0(-1) -> slot 1
  else           h1p[3*16384 + (i - 16384)] = h0[i]; // h1(-1) -> slot 3
  if (i < 4704) bar[i] = 0u;
}

// ---------------- Wo -> bf16 ----------------
__global__ __launch_bounds__(256) void conv_bf16_kernel(const float* __restrict__ src,
    unsigned short* __restrict__ dst){
  int i = (blockIdx.x*256 + threadIdx.x)*4;
  float4 v = *(const float4*)(src + i);
  ushort4 o;
  o.x = f2bf(v.x); o.y = f2bf(v.y); o.z = f2bf(v.z); o.w = f2bf(v.w);
  *(ushort4*)(dst + i) = o;
}

// ---------------- weight packs: row-major, rows r = u*4+gate ----------------
__global__ __launch_bounds__(256) void pack_l0_v3(const float* __restrict__ W,
    float* __restrict__ out){
  int idx4 = blockIdx.x*256 + threadIdx.x;
  int r = idx4 >> 7, k4 = idx4 & 127;
  int srow = (r & 3)*Hz + (r >> 2);
  ((float4*)out)[idx4] = ((const float4*)W)[srow*128 + k4];
}
__global__ __launch_bounds__(256) void pack_l1_v3(const float* __restrict__ Wi,
    const float* __restrict__ Wh, float* __restrict__ out){
  int idx4 = blockIdx.x*256 + threadIdx.x;
  int r = idx4 >> 8, k4 = idx4 & 255;
  int srow = (r & 3)*Hz + (r >> 2);
  float4 v = (k4 < 128) ? ((const float4*)Wi)[srow*128 + k4]
                        : ((const float4*)Wh)[srow*128 + (k4 - 128)];
  ((float4*)out)[idx4] = v;
}

// ---------------- x0g: tiled fp32 GEMM, OUTPUT TRANSPOSED [t][col][b] ----------------
__global__ __launch_bounds__(256) void x0g_v3(const int* __restrict__ tgt,
    const float* __restrict__ emb, const float* __restrict__ W,
    const float* __restrict__ bi, const float* __restrict__ bh,
    float* __restrict__ out){
  __shared__ float As[32][68], Bs[32][68];
  __shared__ int tok_s[64];
  int tid = threadIdx.x;
  int m0 = blockIdx.y*64, n0 = blockIdx.x*64;
  if (tid < 64){ int tb = m0 + tid; tok_s[tid] = tgt[(tb & 31)*Tz + (tb >> 5)]; }
  __syncthreads();
  int lm = tid >> 2, lk = (tid & 3)*8;
  int ty = tid >> 4, tx = tid & 15;
  float acc[4][4] = {{0.f}};
  for (int kt = 0; kt < 16; kt++){
    float4 a0 = *(const float4*)(emb + (size_t)tok_s[lm]*Hz + kt*32 + lk);
    float4 a1 = *(const float4*)(emb + (size_t)tok_s[lm]*Hz + kt*32 + lk + 4);
    float4 b0 = *(const float4*)(W   + (size_t)(n0+lm)*Hz + kt*32 + lk);
    float4 b1 = *(const float4*)(W   + (size_t)(n0+lm)*Hz + kt*32 + lk + 4);
    __syncthreads();
    As[lk+0][lm]=a0.x; As[lk+1][lm]=a0.y; As[lk+2][lm]=a0.z; As[lk+3][lm]=a0.w;
    As[lk+4][lm]=a1.x; As[lk+5][lm]=a1.y; As[lk+6][lm]=a1.z; As[lk+7][lm]=a1.w;
    Bs[lk+0][lm]=b0.x; Bs[lk+1][lm]=b0.y; Bs[lk+2][lm]=b0.z; Bs[lk+3][lm]=b0.w;
    Bs[lk+4][lm]=b1.x; Bs[lk+5][lm]=b1.y; Bs[lk+6][lm]=b1.z; Bs[lk+7][lm]=b1.w;
    __syncthreads();
    #pragma unroll
    for (int k = 0; k < 32; k++){
      float4 av = *(const float4*)&As[k][ty*4];
      float4 bv = *(const float4*)&Bs[k][tx*4];
      acc[0][0]+=av.x*bv.x; acc[0][1]+=av.x*bv.y; acc[0][2]+=av.x*bv.z; acc[0][3]+=av.x*bv.w;
      acc[1][0]+=av.y*bv.x; acc[1][1]+=av.y*bv.y; acc[1][2]+=av.y*bv.z; acc[1][3]+=av.y*bv.w;
      acc[2][0]+=av.z*bv.x; acc[2][1]+=av.z*bv.y; acc[2][2]+=av.z*bv.z; acc[2][3]+=av.z*bv.w;
      acc[3][0]+=av.w*bv.x; acc[3][1]+=av.w*bv.y; acc[3][2]+=av.w*bv.z; acc[3][3]+=av.w*bv.w;
    }
  }
  #pragma unroll
  for (int j = 0; j < 4; j++){
    int col = n0 + tx*4 + j;
    float bias = bi[col] + bh[col];
    #pragma unroll
    for (int i = 0; i < 4; i++){
      int tb = m0 + ty*4 + i;
      int tt = tb >> 5, bb = tb & 31;
      out[((size_t)tt*2048 + col)*32 + bb] = acc[i][j] + bias;
    }
  }
}

// ---------------- persistent decoder v7: LSTM only, skewed, no-inv coherence ----------------
// phase tau (0..64): l0(tau) [tau<64] | l1(tau-1) [tau>=1]
// hist rows for step t live in x0g slot t's front 16384 floats (slot consumed at phase t).
__global__ __launch_bounds__(512, 1) void decoder_persist_v7(
    const float* __restrict__ Wp0, const float* __restrict__ Wp1,
    const float* x0gT,            // NO restrict: hist aliases into it
    const float* __restrict__ bi1, const float* __restrict__ bh1,
    const float* __restrict__ c0in,
    float* __restrict__ h0p,      // [2][16384]
    float* __restrict__ h1p,      // [4][16384]
    float* hist,                  // = x0g base (front 16384 of slot t)
    float* __restrict__ cbuf,     // [2][16384] final c out
    unsigned* __restrict__ bar){
  extern __shared__ float sm[];
  float* hstA = sm;              // [32][520] 16640
  float* hstB = sm + 16640;      // [32][520] 16640
  float* gsA  = sm + 33280;      // 512
  float* gsB  = sm + 33792;      // 512
  float4* hA4 = (float4*)hstA;
  float4* hB4 = (float4*)hstB;

  const int bid = blockIdx.x, tid = threadIdx.x;
  const int w4 = tid >> 6, lane = tid & 63;
  const int kh = w4 >> 2, rpair = w4 & 3;
  const int r0 = bid*8 + rpair*2, r1 = r0 + 1;
  unsigned ep = 0;

  // ---- persistent weights -> VGPRs ----
  const float4* Wp0_4 = (const float4*)Wp0;
  const float4* Wp1_4 = (const float4*)Wp1;
  float4 w0A  = Wp0_4[r0*128 + kh*64 + lane];
  float4 w0B  = Wp0_4[r1*128 + kh*64 + lane];
  float4 w1xA = Wp1_4[r0*256 +       kh*64 + lane];
  float4 w1xB = Wp1_4[r1*256 +       kh*64 + lane];
  float4 w1hA = Wp1_4[r0*256 + 128 + kh*64 + lane];
  float4 w1hB = Wp1_4[r1*256 + 128 + kh*64 + lane];
  float bs_i=0.f, bs_f=0.f, bs_g=0.f, bs_o=0.f;
  float c0_reg=0.f, c1_reg=0.f;
  if (tid < 64){
    int b = tid & 31, u = bid*2 + (tid >> 5);
    bs_i = bi1[u]        + bh1[u];
    bs_f = bi1[512+u]    + bh1[512+u];
    bs_g = bi1[1024+u]   + bh1[1024+u];
    bs_o = bi1[1536+u]   + bh1[1536+u];
    c0_reg = c0in[b*512 + u];
    c1_reg = c0in[16384 + b*512 + u];
  }
  __syncthreads();

  for (int tau = 0; tau < NPH; ++tau){
    // ---- stage h0(tau-1)->hstA, h1(tau-2)->hstB (coherent loads, no inv needed) ----
    stage2c(hstA, h0p + ((tau+1)&1)*16384, hstB, h1p + ((tau+2)&3)*16384, tid);
    // ---- x0gT(tau) prefetch: coalesced over b (plain cached loads, const data) ----
    float xgi=0.f, xgf=0.f, xgg=0.f, xgo=0.f;
    if (tau < 64 && tid < 64){
      int b = tid & 31, u = bid*2 + (tid >> 5);
      const float* xg = x0gT + (size_t)tau*65536;
      xgi = xg[(u       )*32 + b];
      xgf = xg[(512  + u)*32 + b];
      xgg = xg[(1024 + u)*32 + b];
      xgo = xg[(1536 + u)*32 + b];
    }
    __syncthreads();
    // ---- combined gemv: l0(tau) rows + l1(tau-1) rows ----
    {
      float aL0A[32], aL0B[32], aL1A[32], aL1B[32];
      #pragma unroll
      for (int b = 0; b < 32; b++){ aL0A[b]=0.f; aL0B[b]=0.f; aL1A[b]=0.f; aL1B[b]=0.f; }
      const float4* pA = hA4 + kh*64 + lane;
      const float4* pB = hB4 + kh*64 + lane;
      #pragma unroll
      for (int b = 0; b < 32; b++){
        float4 ha = pA[b*130];
        float4 hb = pB[b*130];
        aL0A[b] = fmaf(ha.x,w0A.x, fmaf(ha.y,w0A.y, fmaf(ha.z,w0A.z, fmaf(ha.w,w0A.w, aL0A[b]))));
        aL0B[b] = fmaf(ha.x,w0B.x, fmaf(ha.y,w0B.y, fmaf(ha.z,w0B.z, fmaf(ha.w,w0B.w, aL0B[b]))));
        float t1 = fmaf(ha.x,w1xA.x, fmaf(ha.y,w1xA.y, fmaf(ha.z,w1xA.z, fmaf(ha.w,w1xA.w, aL1A[b]))));
        aL1A[b] = fmaf(hb.x,w1hA.x, fmaf(hb.y,w1hA.y, fmaf(hb.z,w1hA.z, fmaf(hb.w,w1hA.w, t1))));
        float t2 = fmaf(ha.x,w1xB.x, fmaf(ha.y,w1xB.y, fmaf(ha.z,w1xB.z, fmaf(ha.w,w1xB.w, aL1B[b]))));
        aL1B[b] = fmaf(hb.x,w1hB.x, fmaf(hb.y,w1hB.y, fmaf(hb.z,w1hB.z, fmaf(hb.w,w1hB.w, t2))));
      }
      xreduce(aL0A, lane); xreduce(aL0B, lane);
      gsA[kh*256 + (rpair*2 + (lane >= 32 ? 1 : 0))*32 + (lane & 31)] = (lane < 32) ? aL0A[0] : aL0B[0];
      xreduce(aL1A, lane); xreduce(aL1B, lane);
      gsB[kh*256 + (rpair*2 + (lane >= 32 ? 1 : 0))*32 + (lane & 31)] = (lane < 32) ? aL1A[0] : aL1B[0];
    }
    __syncthreads();
    // ---- cells (tid<64) ----
    if (tid < 64){
      int ul = tid >> 5, b = tid & 31, u = bid*2 + ul, rl = ul*4;
      if (tau < 64){
        float gi = gsA[(rl+0)*32+b] + gsA[256+(rl+0)*32+b] + xgi;
        float gf = gsA[(rl+1)*32+b] + gsA[256+(rl+1)*32+b] + xgf;
        float gg = gsA[(rl+2)*32+b] + gsA[256+(rl+2)*32+b] + xgg;
        float go = gsA[(rl+3)*32+b] + gsA[256+(rl+3)*32+b] + xgo;
        float cn = sigf(gf)*c0_reg + sigf(gi)*tanhf(gg);
        c0_reg = cn;
        stc(h0p + (tau&1)*16384 + b*512 + u, sigf(go)*tanhf(cn));
      }
      if (tau >= 1){
        int t1s = tau - 1;
        float gi = gsB[(rl+0)*32+b] + gsB[256+(rl+0)*32+b] + bs_i;
        float gf = gsB[(rl+1)*32+b] + gsB[256+(rl+1)*32+b] + bs_f;
        float gg = gsB[(rl+2)*32+b] + gsB[256+(rl+2)*32+b] + bs_g;
        float go = gsB[(rl+3)*32+b] + gsB[256+(rl+3)*32+b] + bs_o;
        float cn = sigf(gf)*c1_reg + sigf(gi)*tanhf(gg);
        c1_reg = cn;
        float hv = sigf(go)*tanhf(cn);
        stc(h1p + (t1s&3)*16384 + b*512 + u, hv);
        hist[(size_t)t1s*65536 + b*512 + u] = hv;   // plain; read after kernel end
      }
    }
    gbar(bar, bid, &ep);
  }
  // ---- final c writeback ----
  if (tid < 64){
    int b = tid & 31, u = bid*2 + (tid >> 5);
    cbuf[b*512 + u] = c0_reg;
    cbuf[16384 + b*512 + u] = c1_reg;
  }
}

// ---------------- batched attention: scores+softmax+ctx per (t,b) ----------------
__global__ __launch_bounds__(256) void attn_batch(const float* hist,
    const float* __restrict__ enc, float* ctxout){
  __shared__ float h_s[Hz], e_s[Sz], red_s[2];
  const int bid = blockIdx.x;             // 2048: t*32 + b  (b%8 pins enc[b] to one XCD)
  const int t = bid >> 5, b = bid & 31, tid = threadIdx.x;
  const float* h1 = hist + (size_t)t*65536 + b*512;
  *(float2*)(h_s + tid*2) = *(const float2*)(h1 + tid*2);
  __syncthreads();
  {
    int s = tid >> 1, half = tid & 1;
    const float4* e4 = (const float4*)(enc + ((size_t)b*Sz + s)*Hz + half*256);
    const float4* h4 = (const float4*)(h_s + half*256);
    float a = 0.f;
    #pragma unroll 16
    for (int k = 0; k < 64; k++){
      float4 e = e4[k], h = h4[k];
      a += e.x*h.x + e.y*h.y + e.z*h.z + e.w*h.w;
    }
    a += __shfl_xor(a, 1);
    if (!half) e_s[s] = a;
  }
  __syncthreads();
  if (tid < 64){
    float v = fmaxf(e_s[tid], e_s[tid+64]);
    #pragma unroll
    for (int o = 32; o; o >>= 1) v = fmaxf(v, __shfl_xor(v, o));
    if (tid == 0) red_s[0] = v;
  }
  __syncthreads();
  if (tid < Sz) e_s[tid] = expf(e_s[tid] - red_s[0]);
  __syncthreads();
  if (tid < 64){
    float v = e_s[tid] + e_s[tid+64];
    #pragma unroll
    for (int o = 32; o; o >>= 1) v += __shfl_xor(v, o);
    if (tid == 0) red_s[1] = v;
  }
  __syncthreads();
  {
    float inv = 1.f/red_s[1];
    int k0 = tid*2;
    float c0 = 0.f, c1 = 0.f;
    const float* ep = enc + (size_t)b*Sz*Hz + k0;
    #pragma unroll 8
    for (int s = 0; s < Sz; s++){
      float2 ev = *(const float2*)(ep + (size_t)s*Hz);
      float pr = e_s[s];
      c0 += pr*ev.x; c1 += pr*ev.y;
    }
    float2 o; o.x = c0*inv; o.y = c1*inv;
    *(float2*)(ctxout + (size_t)t*65536 + 32768 + b*512 + k0) = o;
  }
}

// ---------------- out_att GEMM: [2048 x 512] = [hist|ctx][2048x1024] @ Wc^T, tanh, ->bf16 ----
__global__ __launch_bounds__(256) void outatt_gemm(const float* xg,
    const float* __restrict__ Wc, const float* __restrict__ bc,
    unsigned short* __restrict__ oa){
  __shared__ float As[32][68], Bs[32][68];
  int tid = threadIdx.x;
  int m0 = blockIdx.y*64, n0 = blockIdx.x*64;
  int lm = tid >> 2, lk = (tid & 3)*8;
  int ty = tid >> 4, tx = tid & 15;
  int am = m0 + lm, at = am >> 5, ab = am & 31;
  const float* arow = xg + (size_t)at*65536 + ab*512;   // k<512: hist (front of slot)
  float acc[4][4] = {{0.f}};
  for (int kt = 0; kt < 32; kt++){
    int k = kt*32 + lk;
    const float* asrc = (k < 512) ? (arow + k) : (arow + 32768 + (k - 512));
    float4 a0 = *(const float4*)asrc;
    float4 a1 = *(const float4*)(asrc + 4);
    float4 b0 = *(const float4*)(Wc + (size_t)(n0+lm)*1024 + k);
    float4 b1 = *(const float4*)(Wc + (size_t)(n0+lm)*1024 + k + 4);
    __syncthreads();
    As[lk+0][lm]=a0.x; As[lk+1][lm]=a0.y; As[lk+2][lm]=a0.z; As[lk+3][lm]=a0.w;
    As[lk+4][lm]=a1.x; As[lk+5][lm]=a1.y; As[lk+6][lm]=a1.z; As[lk+7][lm]=a1.w;
    Bs[lk+0][lm]=b0.x; Bs[lk+1][lm]=b0.y; Bs[lk+2][lm]=b0.z; Bs[lk+3][lm]=b0.w;
    Bs[lk+4][lm]=b1.x; Bs[lk+5][lm]=b1.y; Bs[lk+6][lm]=b1.z; Bs[lk+7][lm]=b1.w;
    __syncthreads();
    #pragma unroll
    for (int k2 = 0; k2 < 32; k2++){
      float4 av = *(const float4*)&As[k2][ty*4];
      float4 bv = *(const float4*)&Bs[k2][tx*4];
      acc[0][0]+=av.x*bv.x; acc[0][1]+=av.x*bv.y; acc[0][2]+=av.x*bv.z; acc[0][3]+=av.x*bv.w;
      acc[1][0]+=av.y*bv.x; acc[1][1]+=av.y*bv.y; acc[1][2]+=av.y*bv.z; acc[1][3]+=av.y*bv.w;
      acc[2][0]+=av.z*bv.x; acc[2][1]+=av.z*bv.y; acc[2][2]+=av.z*bv.z; acc[2][3]+=av.z*bv.w;
      acc[3][0]+=av.w*bv.x; acc[3][1]+=av.w*bv.y; acc[3][2]+=av.w*bv.z; acc[3][3]+=av.w*bv.w;
    }
  }
  #pragma unroll
  for (int j = 0; j < 4; j++){
    int col = n0 + tx*4 + j;
    float bias = bc[col];
    #pragma unroll
    for (int i = 0; i < 4; i++){
      int m = m0 + ty*4 + i;
      int t = m >> 5, b = m & 31;
      oa[((size_t)(b*64 + t))*512 + col] = f2bf(tanhf(acc[i][j] + bias));
    }
  }
}

// ---------------- pred GEMM: XCD-pinned + swizzled LDS ----------------
__global__ __launch_bounds__(256) void pred_gemm_v2(const unsigned short* __restrict__ A,
    const unsigned short* __restrict__ Bm, const float* __restrict__ bo,
    float* __restrict__ out){
  __shared__ unsigned short As[128*32];
  __shared__ unsigned short Bs[128*32];
  int bid = blockIdx.x;
  int xcd = bid & 7, lin = bid >> 3;
  int ntile = xcd*32 + (lin & 31);
  int mtile = lin >> 5;
  if (ntile >= 250) return;
  int n0 = ntile*128, m0 = mtile*128;
  int tid = threadIdx.x, lane = tid & 63, wid = tid >> 6;
  f32x4 acc[4][4];
  #pragma unroll
  for (int i = 0; i < 4; i++)
    #pragma unroll
    for (int j = 0; j < 4; j++)
      #pragma unroll
      for (int r = 0; r < 4; r++) acc[i][j][r] = 0.f;

  int wm = wid >> 1, wn = wid & 1;
  int r16 = lane & 15, kgr = lane >> 4;

  for (int kt = 0; kt < Hz/32; kt++){
    __syncthreads();
    #pragma unroll
    for (int call = 0; call < 2; call++){
      int c = call*256 + tid;
      int row = c >> 2, kg = c & 3;
      int kgs = kg ^ ((row >> 1) & 3);
      *(int4*)&As[row*32 + kgs*8] = *(const int4*)(A  + (size_t)(m0+row)*Hz + kt*32 + kg*8);
      *(int4*)&Bs[row*32 + kgs*8] = *(const int4*)(Bm + (size_t)(n0+row)*Hz + kt*32 + kg*8);
    }
    __syncthreads();
    bf16x8 aF[4], bF[4];
    #pragma unroll
    for (int i = 0; i < 4; i++){
      int ra = wm*64 + i*16 + r16;
      int rb = wn*64 + i*16 + r16;
      aF[i] = *(const bf16x8*)&As[ra*32 + (kgr ^ ((ra>>1)&3))*8];
      bF[i] = *(const bf16x8*)&Bs[rb*32 + (kgr ^ ((rb>>1)&3))*8];
    }
    #pragma unroll
    for (int i = 0; i < 4; i++)
      #pragma unroll
      for (int j = 0; j < 4; j++)
        acc[i][j] = __builtin_amdgcn_mfma_f32_16x16x32_bf16(aF[i], bF[j], acc[i][j], 0, 0, 0);
  }

  int rg = lane >> 4;
  #pragma unroll
  for (int i = 0; i < 4; i++)
    #pragma unroll
    for (int j = 0; j < 4; j++){
      int col = n0 + wn*64 + j*16 + r16;
      float bias = bo[col];
      #pragma unroll
      for (int r = 0; r < 4; r++){
        int row = m0 + wm*64 + i*16 + rg*4 + r;   // row = b*64 + t
        out[(size_t)row*Vz + col] = acc[i][j][r] + bias;
      }
    }
}

// ---------------- final h,c copy ----------------
__global__ __launch_bounds__(256) void copy_hc_v4(const float* __restrict__ h0fin,
    const float* __restrict__ h1fin, const float* __restrict__ cbuf,
    float* __restrict__ out_hc){
  int i = blockIdx.x*256 + threadIdx.x;   // grid 256 -> 65536
  float v;
  if (i < 16384)      v = h0fin[i];
  else if (i < 32768) v = h1fin[i-16384];
  else                v = cbuf[i-32768];
  out_hc[i] = v;
}

extern "C" void kernel_launch(void* const* d_in, const int* in_sizes, int n_in,
                              void* d_out, int out_size, void* d_ws, size_t ws_size,
                              hipStream_t stream){
  const int*   tgt = (const int*)  d_in[0];
  const float* h0  = (const float*)d_in[1];
  const float* c0  = (const float*)d_in[2];
  const float* enc = (const float*)d_in[3];
  const float* emb = (const float*)d_in[4];
  const float* Wih = (const float*)d_in[5];
  const float* Whh = (const float*)d_in[6];
  const float* bih = (const float*)d_in[7];
  const float* bhh = (const float*)d_in[8];
  const float* Wc  = (const float*)d_in[9];
  const float* bc  = (const float*)d_in[10];
  const float* Wo  = (const float*)d_in[11];
  const float* bo  = (const float*)d_in[12];
  float* out = (float*)d_out;

  // workspace layout (floats)
  // x0g slot t (65536 f): [0:16384) hist(t) after phase t | [32768:49152) ctx(t) | gates consumed at phase t
  float* x0g  = (float*)d_ws;                 // 4,194,304
  float* h0p  = x0g  + 4194304;               // 32,768  [2][16384]
  float* h1p  = h0p  + 32768;                 // 65,536  [4][16384]
  float* cbuf = h1p  + 65536;                 // 32,768
  float* Wp0  = cbuf + 32768;                 // 1,048,576
  float* Wp1  = Wp0  + 1048576;               // 2,097,152
  unsigned int* bar = (unsigned int*)(Wp1 + 2097152);           // 4704 words
  unsigned short* oa    = (unsigned short*)(bar + 4704);        // 1,048,576 us [b][t][u]
  unsigned short* wo_bf = oa + 1048576;       // 16,384,000 us (32MB)

  const int DLDS_BYTES = 34304 * 4;           // 137.2 KB dynamic LDS
  hipFuncSetAttribute((const void*)decoder_persist_v7,
      hipFuncAttributeMaxDynamicSharedMemorySize, DLDS_BYTES);

  init_state_v7<<<128, 256, 0, stream>>>(h0, h0p, h1p, bar);
  conv_bf16_kernel<<<16000, 256, 0, stream>>>(Wo, wo_bf);
  pack_l0_v3<<<1024, 256, 0, stream>>>(Whh, Wp0);
  pack_l1_v3<<<2048, 256, 0, stream>>>(Wih + (size_t)G4*Hz, Whh + (size_t)G4*Hz, Wp1);
  x0g_v3<<<dim3(32, 32), 256, 0, stream>>>(tgt, emb, Wih, bih, bhh, x0g);

  decoder_persist_v7<<<NBLK, 512, DLDS_BYTES, stream>>>(
      Wp0, Wp1, x0g, bih + G4, bhh + G4, c0,
      h0p, h1p, /*hist=*/x0g, cbuf, (unsigned int*)bar);

  attn_batch<<<2048, 256, 0, stream>>>(x0g, enc, x0g);
  outatt_gemm<<<dim3(8, 32), 256, 0, stream>>>(x0g, Wc, bc, oa);
  pred_gemm_v2<<<4096, 256, 0, stream>>>(oa, wo_bf, bo, out);
  copy_hc_v4<<<256, 256, 0, stream>>>(h0p + 16384, x0g + (size_t)63*65536, cbuf,
                                      out + (size_t)Bz*Tz*Vz);

  (void)in_sizes; (void)n_in; (void)out_size; (void)ws_size;
}

// Round 9
// 1115.099 us; speedup vs baseline: 8.7147x; 1.0671x over previous
//
#include <hip/hip_runtime.h>
#include <hip/hip_bf16.h>

#define Bz 32
#define Tz 64
#define Sz 128
#define Hz 512
#define Vz 32000
#define G4 2048
#define NBLK 256
#define NPH 65

#define A_RLX __ATOMIC_RELAXED
#define SC_AG __HIP_MEMORY_SCOPE_AGENT

using bf16x8 = __attribute__((ext_vector_type(8))) short;
using f32x4  = __attribute__((ext_vector_type(4))) float;

__device__ __forceinline__ unsigned short f2bf(float f){
  unsigned int u = __float_as_uint(f);
  u += 0x7fffu + ((u >> 16) & 1u);
  return (unsigned short)(u >> 16);
}
__device__ __forceinline__ float sigf(float x){ return 1.f/(1.f + expf(-x)); }

__device__ __forceinline__ void stc(float* p, float v){
  __hip_atomic_store(p, v, A_RLX, SC_AG);
}
__device__ __forceinline__ float ldc(const float* p){
  return __hip_atomic_load(p, A_RLX, SC_AG);
}

// ---------------- grid barrier: FLAT 2-round-trip, single-writer/single-poller words ----
// arrive: bar[bid*4] (bid=1..255), polled by block0 thread tid=bid (coalesced lines)
// release: bar[1024 + bid*16], written by block0 thread bid, polled by block bid's t0
__device__ __forceinline__ void gbar(unsigned* bar, int bid, unsigned* ep){
  asm volatile("s_waitcnt vmcnt(0)" ::: "memory");   // drain this thread's stores
  __syncthreads();                                    // whole block drained
  const unsigned e = ++(*ep);
  const int tid = threadIdx.x;
  if (bid == 0){
    if (tid >= 1 && tid < 256){                       // parallel poll of all arrivals
      while (__hip_atomic_load(&bar[tid*4], A_RLX, SC_AG) != e)
        __builtin_amdgcn_s_sleep(1);
    }
    __syncthreads();
    if (tid < 256)                                    // fan-out release
      __hip_atomic_store(&bar[1024 + tid*16], e, A_RLX, SC_AG);
  } else {
    if (tid == 0){
      __hip_atomic_store(&bar[bid*4], e, A_RLX, SC_AG);
      while (__hip_atomic_load(&bar[1024 + bid*16], A_RLX, SC_AG) != e)
        __builtin_amdgcn_s_sleep(1);
    }
  }
  __syncthreads();
  __builtin_amdgcn_sched_barrier(0);
}

// ---------------- register transpose-reduce ----------------
__device__ __forceinline__ void xreduce(float (&a)[32], int lane){
  #pragma unroll
  for (int j = 0; j < 32; j++) a[j] += __shfl_xor(a[j], 32);
  #pragma unroll
  for (int st = 0; st < 5; st++){
    const int o = 16 >> st;
    bool hi = (lane & o) != 0;
    float tmp[16];
    #pragma unroll
    for (int j = 0; j < o; j++){
      float lo_v = a[j], hi_v = a[j + o];
      float sent = hi ? lo_v : hi_v;
      float recv = __shfl_xor(sent, o);
      tmp[j] = (hi ? hi_v : lo_v) + recv;
    }
    #pragma unroll
    for (int j = 0; j < o; j++) a[j] = tmp[j];
  }
}

// ---------------- dual LDS staging: ALL 64 coherent loads in flight ----------------
__device__ __forceinline__ void stage2c(float* dA, const float* sA,
                                        float* dB, const float* sB, int tid){
  float ra[32], rb[32];
  #pragma unroll
  for (int i = 0; i < 32; i++) ra[i] = ldc(sA + tid + i*512);
  #pragma unroll
  for (int i = 0; i < 32; i++) rb[i] = ldc(sB + tid + i*512);
  #pragma unroll
  for (int i = 0; i < 32; i++){
    int f = tid + i*512;
    dA[(f >> 9)*520 + (f & 511)] = ra[i];
  }
  #pragma unroll
  for (int i = 0; i < 32; i++){
    int f = tid + i*512;
    dB[(f >> 9)*520 + (f & 511)] = rb[i];
  }
}

// ---------------- init ----------------
__global__ __launch_bounds__(256) void init_state_v8(const float* __restrict__ h0,
    float* __restrict__ h0p, float* __restrict__ h1p, unsigned int* __restrict__ bar){
  int i = blockIdx.x*256 + threadIdx.x;   // grid 128 -> 32768
  if (i < 16384) h0p[16384 + i] = h0[i];            // h0(-1) -> slot 1
  else           h1p[3*16384 + (i - 16384)] = h0[i]; // h1(-1) -> slot 3
  if (i < 5120) bar[i] = 0u;
}

// ---------------- Wo -> bf16 ----------------
__global__ __launch_bounds__(256) void conv_bf16_kernel(const float* __restrict__ src,
    unsigned short* __restrict__ dst){
  int i = (blockIdx.x*256 + threadIdx.x)*4;
  float4 v = *(const float4*)(src + i);
  ushort4 o;
  o.x = f2bf(v.x); o.y = f2bf(v.y); o.z = f2bf(v.z); o.w = f2bf(v.w);
  *(ushort4*)(dst + i) = o;
}

// ---------------- weight packs: row-major, rows r = u*4+gate ----------------
__global__ __launch_bounds__(256) void pack_l0_v3(const float* __restrict__ W,
    float* __restrict__ out){
  int idx4 = blockIdx.x*256 + threadIdx.x;
  int r = idx4 >> 7, k4 = idx4 & 127;
  int srow = (r & 3)*Hz + (r >> 2);
  ((float4*)out)[idx4] = ((const float4*)W)[srow*128 + k4];
}
__global__ __launch_bounds__(256) void pack_l1_v3(const float* __restrict__ Wi,
    const float* __restrict__ Wh, float* __restrict__ out){
  int idx4 = blockIdx.x*256 + threadIdx.x;
  int r = idx4 >> 8, k4 = idx4 & 255;
  int srow = (r & 3)*Hz + (r >> 2);
  float4 v = (k4 < 128) ? ((const float4*)Wi)[srow*128 + k4]
                        : ((const float4*)Wh)[srow*128 + (k4 - 128)];
  ((float4*)out)[idx4] = v;
}

// ---------------- x0g: tiled fp32 GEMM, OUTPUT TRANSPOSED [t][col][b] ----------------
__global__ __launch_bounds__(256) void x0g_v3(const int* __restrict__ tgt,
    const float* __restrict__ emb, const float* __restrict__ W,
    const float* __restrict__ bi, const float* __restrict__ bh,
    float* __restrict__ out){
  __shared__ float As[32][68], Bs[32][68];
  __shared__ int tok_s[64];
  int tid = threadIdx.x;
  int m0 = blockIdx.y*64, n0 = blockIdx.x*64;
  if (tid < 64){ int tb = m0 + tid; tok_s[tid] = tgt[(tb & 31)*Tz + (tb >> 5)]; }
  __syncthreads();
  int lm = tid >> 2, lk = (tid & 3)*8;
  int ty = tid >> 4, tx = tid & 15;
  float acc[4][4] = {{0.f}};
  for (int kt = 0; kt < 16; kt++){
    float4 a0 = *(const float4*)(emb + (size_t)tok_s[lm]*Hz + kt*32 + lk);
    float4 a1 = *(const float4*)(emb + (size_t)tok_s[lm]*Hz + kt*32 + lk + 4);
    float4 b0 = *(const float4*)(W   + (size_t)(n0+lm)*Hz + kt*32 + lk);
    float4 b1 = *(const float4*)(W   + (size_t)(n0+lm)*Hz + kt*32 + lk + 4);
    __syncthreads();
    As[lk+0][lm]=a0.x; As[lk+1][lm]=a0.y; As[lk+2][lm]=a0.z; As[lk+3][lm]=a0.w;
    As[lk+4][lm]=a1.x; As[lk+5][lm]=a1.y; As[lk+6][lm]=a1.z; As[lk+7][lm]=a1.w;
    Bs[lk+0][lm]=b0.x; Bs[lk+1][lm]=b0.y; Bs[lk+2][lm]=b0.z; Bs[lk+3][lm]=b0.w;
    Bs[lk+4][lm]=b1.x; Bs[lk+5][lm]=b1.y; Bs[lk+6][lm]=b1.z; Bs[lk+7][lm]=b1.w;
    __syncthreads();
    #pragma unroll
    for (int k = 0; k < 32; k++){
      float4 av = *(const float4*)&As[k][ty*4];
      float4 bv = *(const float4*)&Bs[k][tx*4];
      acc[0][0]+=av.x*bv.x; acc[0][1]+=av.x*bv.y; acc[0][2]+=av.x*bv.z; acc[0][3]+=av.x*bv.w;
      acc[1][0]+=av.y*bv.x; acc[1][1]+=av.y*bv.y; acc[1][2]+=av.y*bv.z; acc[1][3]+=av.y*bv.w;
      acc[2][0]+=av.z*bv.x; acc[2][1]+=av.z*bv.y; acc[2][2]+=av.z*bv.z; acc[2][3]+=av.z*bv.w;
      acc[3][0]+=av.w*bv.x; acc[3][1]+=av.w*bv.y; acc[3][2]+=av.w*bv.z; acc[3][3]+=av.w*bv.w;
    }
  }
  #pragma unroll
  for (int j = 0; j < 4; j++){
    int col = n0 + tx*4 + j;
    float bias = bi[col] + bh[col];
    #pragma unroll
    for (int i = 0; i < 4; i++){
      int tb = m0 + ty*4 + i;
      int tt = tb >> 5, bb = tb & 31;
      out[((size_t)tt*2048 + col)*32 + bb] = acc[i][j] + bias;
    }
  }
}

// ---------------- persistent decoder v8: LSTM only, skewed, flat barrier ----------------
// phase tau (0..64): l0(tau) [tau<64] | l1(tau-1) [tau>=1]
__global__ __launch_bounds__(512, 1) void decoder_persist_v8(
    const float* __restrict__ Wp0, const float* __restrict__ Wp1,
    const float* x0gT,            // NO restrict: hist aliases into it
    const float* __restrict__ bi1, const float* __restrict__ bh1,
    const float* __restrict__ c0in,
    float* __restrict__ h0p,      // [2][16384]
    float* __restrict__ h1p,      // [4][16384]
    float* hist,                  // = x0g base (front 16384 of slot t)
    float* __restrict__ cbuf,     // [2][16384] final c out
    unsigned* __restrict__ bar){
  extern __shared__ float sm[];
  float* hstA = sm;              // [32][520] 16640
  float* hstB = sm + 16640;      // [32][520] 16640
  float* gsA  = sm + 33280;      // 512
  float* gsB  = sm + 33792;      // 512
  float4* hA4 = (float4*)hstA;
  float4* hB4 = (float4*)hstB;

  const int bid = blockIdx.x, tid = threadIdx.x;
  const int w4 = tid >> 6, lane = tid & 63;
  const int kh = w4 >> 2, rpair = w4 & 3;
  const int r0 = bid*8 + rpair*2, r1 = r0 + 1;
  unsigned ep = 0;

  // ---- persistent weights -> VGPRs ----
  const float4* Wp0_4 = (const float4*)Wp0;
  const float4* Wp1_4 = (const float4*)Wp1;
  float4 w0A  = Wp0_4[r0*128 + kh*64 + lane];
  float4 w0B  = Wp0_4[r1*128 + kh*64 + lane];
  float4 w1xA = Wp1_4[r0*256 +       kh*64 + lane];
  float4 w1xB = Wp1_4[r1*256 +       kh*64 + lane];
  float4 w1hA = Wp1_4[r0*256 + 128 + kh*64 + lane];
  float4 w1hB = Wp1_4[r1*256 + 128 + kh*64 + lane];
  float bs_i=0.f, bs_f=0.f, bs_g=0.f, bs_o=0.f;
  float c0_reg=0.f, c1_reg=0.f;
  if (tid < 64){
    int b = tid & 31, u = bid*2 + (tid >> 5);
    bs_i = bi1[u]        + bh1[u];
    bs_f = bi1[512+u]    + bh1[512+u];
    bs_g = bi1[1024+u]   + bh1[1024+u];
    bs_o = bi1[1536+u]   + bh1[1536+u];
    c0_reg = c0in[b*512 + u];
    c1_reg = c0in[16384 + b*512 + u];
  }
  __syncthreads();

  for (int tau = 0; tau < NPH; ++tau){
    // ---- stage h0(tau-1)->hstA, h1(tau-2)->hstB (coherent loads) ----
    stage2c(hstA, h0p + ((tau+1)&1)*16384, hstB, h1p + ((tau+2)&3)*16384, tid);
    // ---- x0gT(tau) prefetch: coalesced over b ----
    float xgi=0.f, xgf=0.f, xgg=0.f, xgo=0.f;
    if (tau < 64 && tid < 64){
      int b = tid & 31, u = bid*2 + (tid >> 5);
      const float* xg = x0gT + (size_t)tau*65536;
      xgi = xg[(u       )*32 + b];
      xgf = xg[(512  + u)*32 + b];
      xgg = xg[(1024 + u)*32 + b];
      xgo = xg[(1536 + u)*32 + b];
    }
    __syncthreads();
    // ---- combined gemv: l0(tau) rows + l1(tau-1) rows ----
    {
      float aL0A[32], aL0B[32], aL1A[32], aL1B[32];
      #pragma unroll
      for (int b = 0; b < 32; b++){ aL0A[b]=0.f; aL0B[b]=0.f; aL1A[b]=0.f; aL1B[b]=0.f; }
      const float4* pA = hA4 + kh*64 + lane;
      const float4* pB = hB4 + kh*64 + lane;
      #pragma unroll
      for (int b = 0; b < 32; b++){
        float4 ha = pA[b*130];
        float4 hb = pB[b*130];
        aL0A[b] = fmaf(ha.x,w0A.x, fmaf(ha.y,w0A.y, fmaf(ha.z,w0A.z, fmaf(ha.w,w0A.w, aL0A[b]))));
        aL0B[b] = fmaf(ha.x,w0B.x, fmaf(ha.y,w0B.y, fmaf(ha.z,w0B.z, fmaf(ha.w,w0B.w, aL0B[b]))));
        float t1 = fmaf(ha.x,w1xA.x, fmaf(ha.y,w1xA.y, fmaf(ha.z,w1xA.z, fmaf(ha.w,w1xA.w, aL1A[b]))));
        aL1A[b] = fmaf(hb.x,w1hA.x, fmaf(hb.y,w1hA.y, fmaf(hb.z,w1hA.z, fmaf(hb.w,w1hA.w, t1))));
        float t2 = fmaf(ha.x,w1xB.x, fmaf(ha.y,w1xB.y, fmaf(ha.z,w1xB.z, fmaf(ha.w,w1xB.w, aL1B[b]))));
        aL1B[b] = fmaf(hb.x,w1hB.x, fmaf(hb.y,w1hB.y, fmaf(hb.z,w1hB.z, fmaf(hb.w,w1hB.w, t2))));
      }
      xreduce(aL0A, lane); xreduce(aL0B, lane);
      gsA[kh*256 + (rpair*2 + (lane >= 32 ? 1 : 0))*32 + (lane & 31)] = (lane < 32) ? aL0A[0] : aL0B[0];
      xreduce(aL1A, lane); xreduce(aL1B, lane);
      gsB[kh*256 + (rpair*2 + (lane >= 32 ? 1 : 0))*32 + (lane & 31)] = (lane < 32) ? aL1A[0] : aL1B[0];
    }
    __syncthreads();
    // ---- cells (tid<64) ----
    if (tid < 64){
      int ul = tid >> 5, b = tid & 31, u = bid*2 + ul, rl = ul*4;
      if (tau < 64){
        float gi = gsA[(rl+0)*32+b] + gsA[256+(rl+0)*32+b] + xgi;
        float gf = gsA[(rl+1)*32+b] + gsA[256+(rl+1)*32+b] + xgf;
        float gg = gsA[(rl+2)*32+b] + gsA[256+(rl+2)*32+b] + xgg;
        float go = gsA[(rl+3)*32+b] + gsA[256+(rl+3)*32+b] + xgo;
        float cn = sigf(gf)*c0_reg + sigf(gi)*tanhf(gg);
        c0_reg = cn;
        stc(h0p + (tau&1)*16384 + b*512 + u, sigf(go)*tanhf(cn));
      }
      if (tau >= 1){
        int t1s = tau - 1;
        float gi = gsB[(rl+0)*32+b] + gsB[256+(rl+0)*32+b] + bs_i;
        float gf = gsB[(rl+1)*32+b] + gsB[256+(rl+1)*32+b] + bs_f;
        float gg = gsB[(rl+2)*32+b] + gsB[256+(rl+2)*32+b] + bs_g;
        float go = gsB[(rl+3)*32+b] + gsB[256+(rl+3)*32+b] + bs_o;
        float cn = sigf(gf)*c1_reg + sigf(gi)*tanhf(gg);
        c1_reg = cn;
        float hv = sigf(go)*tanhf(cn);
        stc(h1p + (t1s&3)*16384 + b*512 + u, hv);
        hist[(size_t)t1s*65536 + b*512 + u] = hv;   // plain; read after kernel end
      }
    }
    gbar(bar, bid, &ep);
  }
  // ---- final c writeback ----
  if (tid < 64){
    int b = tid & 31, u = bid*2 + (tid >> 5);
    cbuf[b*512 + u] = c0_reg;
    cbuf[16384 + b*512 + u] = c1_reg;
  }
}

// ---------------- batched attention: scores+softmax+ctx per (t,b) ----------------
__global__ __launch_bounds__(256) void attn_batch(const float* hist,
    const float* __restrict__ enc, float* ctxout){
  __shared__ float h_s[Hz], e_s[Sz], red_s[2];
  const int bid = blockIdx.x;             // 2048: t*32 + b
  const int t = bid >> 5, b = bid & 31, tid = threadIdx.x;
  const float* h1 = hist + (size_t)t*65536 + b*512;
  *(float2*)(h_s + tid*2) = *(const float2*)(h1 + tid*2);
  __syncthreads();
  {
    int s = tid >> 1, half = tid & 1;
    const float4* e4 = (const float4*)(enc + ((size_t)b*Sz + s)*Hz + half*256);
    const float4* h4 = (const float4*)(h_s + half*256);
    float a = 0.f;
    #pragma unroll 16
    for (int k = 0; k < 64; k++){
      float4 e = e4[k], h = h4[k];
      a += e.x*h.x + e.y*h.y + e.z*h.z + e.w*h.w;
    }
    a += __shfl_xor(a, 1);
    if (!half) e_s[s] = a;
  }
  __syncthreads();
  if (tid < 64){
    float v = fmaxf(e_s[tid], e_s[tid+64]);
    #pragma unroll
    for (int o = 32; o; o >>= 1) v = fmaxf(v, __shfl_xor(v, o));
    if (tid == 0) red_s[0] = v;
  }
  __syncthreads();
  if (tid < Sz) e_s[tid] = expf(e_s[tid] - red_s[0]);
  __syncthreads();
  if (tid < 64){
    float v = e_s[tid] + e_s[tid+64];
    #pragma unroll
    for (int o = 32; o; o >>= 1) v += __shfl_xor(v, o);
    if (tid == 0) red_s[1] = v;
  }
  __syncthreads();
  {
    float inv = 1.f/red_s[1];
    int k0 = tid*2;
    float c0 = 0.f, c1 = 0.f;
    const float* ep = enc + (size_t)b*Sz*Hz + k0;
    #pragma unroll 8
    for (int s = 0; s < Sz; s++){
      float2 ev = *(const float2*)(ep + (size_t)s*Hz);
      float pr = e_s[s];
      c0 += pr*ev.x; c1 += pr*ev.y;
    }
    float2 o; o.x = c0*inv; o.y = c1*inv;
    *(float2*)(ctxout + (size_t)t*65536 + 32768 + b*512 + k0) = o;
  }
}

// ---------------- out_att GEMM: [2048 x 512] = [hist|ctx][2048x1024] @ Wc^T, tanh, ->bf16 ----
__global__ __launch_bounds__(256) void outatt_gemm(const float* xg,
    const float* __restrict__ Wc, const float* __restrict__ bc,
    unsigned short* __restrict__ oa){
  __shared__ float As[32][68], Bs[32][68];
  int tid = threadIdx.x;
  int m0 = blockIdx.y*64, n0 = blockIdx.x*64;
  int lm = tid >> 2, lk = (tid & 3)*8;
  int ty = tid >> 4, tx = tid & 15;
  int am = m0 + lm, at = am >> 5, ab = am & 31;
  const float* arow = xg + (size_t)at*65536 + ab*512;
  float acc[4][4] = {{0.f}};
  for (int kt = 0; kt < 32; kt++){
    int k = kt*32 + lk;
    const float* asrc = (k < 512) ? (arow + k) : (arow + 32768 + (k - 512));
    float4 a0 = *(const float4*)asrc;
    float4 a1 = *(const float4*)(asrc + 4);
    float4 b0 = *(const float4*)(Wc + (size_t)(n0+lm)*1024 + k);
    float4 b1 = *(const float4*)(Wc + (size_t)(n0+lm)*1024 + k + 4);
    __syncthreads();
    As[lk+0][lm]=a0.x; As[lk+1][lm]=a0.y; As[lk+2][lm]=a0.z; As[lk+3][lm]=a0.w;
    As[lk+4][lm]=a1.x; As[lk+5][lm]=a1.y; As[lk+6][lm]=a1.z; As[lk+7][lm]=a1.w;
    Bs[lk+0][lm]=b0.x; Bs[lk+1][lm]=b0.y; Bs[lk+2][lm]=b0.z; Bs[lk+3][lm]=b0.w;
    Bs[lk+4][lm]=b1.x; Bs[lk+5][lm]=b1.y; Bs[lk+6][lm]=b1.z; Bs[lk+7][lm]=b1.w;
    __syncthreads();
    #pragma unroll
    for (int k2 = 0; k2 < 32; k2++){
      float4 av = *(const float4*)&As[k2][ty*4];
      float4 bv = *(const float4*)&Bs[k2][tx*4];
      acc[0][0]+=av.x*bv.x; acc[0][1]+=av.x*bv.y; acc[0][2]+=av.x*bv.z; acc[0][3]+=av.x*bv.w;
      acc[1][0]+=av.y*bv.x; acc[1][1]+=av.y*bv.y; acc[1][2]+=av.y*bv.z; acc[1][3]+=av.y*bv.w;
      acc[2][0]+=av.z*bv.x; acc[2][1]+=av.z*bv.y; acc[2][2]+=av.z*bv.z; acc[2][3]+=av.z*bv.w;
      acc[3][0]+=av.w*bv.x; acc[3][1]+=av.w*bv.y; acc[3][2]+=av.w*bv.z; acc[3][3]+=av.w*bv.w;
    }
  }
  #pragma unroll
  for (int j = 0; j < 4; j++){
    int col = n0 + tx*4 + j;
    float bias = bc[col];
    #pragma unroll
    for (int i = 0; i < 4; i++){
      int m = m0 + ty*4 + i;
      int t = m >> 5, b = m & 31;
      oa[((size_t)(b*64 + t))*512 + col] = f2bf(tanhf(acc[i][j] + bias));
    }
  }
}

// ---------------- pred GEMM: XCD-pinned + swizzled LDS ----------------
__global__ __launch_bounds__(256) void pred_gemm_v2(const unsigned short* __restrict__ A,
    const unsigned short* __restrict__ Bm, const float* __restrict__ bo,
    float* __restrict__ out){
  __shared__ unsigned short As[128*32];
  __shared__ unsigned short Bs[128*32];
  int bid = blockIdx.x;
  int xcd = bid & 7, lin = bid >> 3;
  int ntile = xcd*32 + (lin & 31);
  int mtile = lin >> 5;
  if (ntile >= 250) return;
  int n0 = ntile*128, m0 = mtile*128;
  int tid = threadIdx.x, lane = tid & 63, wid = tid >> 6;
  f32x4 acc[4][4];
  #pragma unroll
  for (int i = 0; i < 4; i++)
    #pragma unroll
    for (int j = 0; j < 4; j++)
      #pragma unroll
      for (int r = 0; r < 4; r++) acc[i][j][r] = 0.f;

  int wm = wid >> 1, wn = wid & 1;
  int r16 = lane & 15, kgr = lane >> 4;

  for (int kt = 0; kt < Hz/32; kt++){
    __syncthreads();
    #pragma unroll
    for (int call = 0; call < 2; call++){
      int c = call*256 + tid;
      int row = c >> 2, kg = c & 3;
      int kgs = kg ^ ((row >> 1) & 3);
      *(int4*)&As[row*32 + kgs*8] = *(const int4*)(A  + (size_t)(m0+row)*Hz + kt*32 + kg*8);
      *(int4*)&Bs[row*32 + kgs*8] = *(const int4*)(Bm + (size_t)(n0+row)*Hz + kt*32 + kg*8);
    }
    __syncthreads();
    bf16x8 aF[4], bF[4];
    #pragma unroll
    for (int i = 0; i < 4; i++){
      int ra = wm*64 + i*16 + r16;
      int rb = wn*64 + i*16 + r16;
      aF[i] = *(const bf16x8*)&As[ra*32 + (kgr ^ ((ra>>1)&3))*8];
      bF[i] = *(const bf16x8*)&Bs[rb*32 + (kgr ^ ((rb>>1)&3))*8];
    }
    #pragma unroll
    for (int i = 0; i < 4; i++)
      #pragma unroll
      for (int j = 0; j < 4; j++)
        acc[i][j] = __builtin_amdgcn_mfma_f32_16x16x32_bf16(aF[i], bF[j], acc[i][j], 0, 0, 0);
  }

  int rg = lane >> 4;
  #pragma unroll
  for (int i = 0; i < 4; i++)
    #pragma unroll
    for (int j = 0; j < 4; j++){
      int col = n0 + wn*64 + j*16 + r16;
      float bias = bo[col];
      #pragma unroll
      for (int r = 0; r < 4; r++){
        int row = m0 + wm*64 + i*16 + rg*4 + r;   // row = b*64 + t
        out[(size_t)row*Vz + col] = acc[i][j][r] + bias;
      }
    }
}

// ---------------- final h,c copy ----------------
__global__ __launch_bounds__(256) void copy_hc_v4(const float* __restrict__ h0fin,
    const float* __restrict__ h1fin, const float* __restrict__ cbuf,
    float* __restrict__ out_hc){
  int i = blockIdx.x*256 + threadIdx.x;
  float v;
  if (i < 16384)      v = h0fin[i];
  else if (i < 32768) v = h1fin[i-16384];
  else                v = cbuf[i-32768];
  out_hc[i] = v;
}

extern "C" void kernel_launch(void* const* d_in, const int* in_sizes, int n_in,
                              void* d_out, int out_size, void* d_ws, size_t ws_size,
                              hipStream_t stream){
  const int*   tgt = (const int*)  d_in[0];
  const float* h0  = (const float*)d_in[1];
  const float* c0  = (const float*)d_in[2];
  const float* enc = (const float*)d_in[3];
  const float* emb = (const float*)d_in[4];
  const float* Wih = (const float*)d_in[5];
  const float* Whh = (const float*)d_in[6];
  const float* bih = (const float*)d_in[7];
  const float* bhh = (const float*)d_in[8];
  const float* Wc  = (const float*)d_in[9];
  const float* bc  = (const float*)d_in[10];
  const float* Wo  = (const float*)d_in[11];
  const float* bo  = (const float*)d_in[12];
  float* out = (float*)d_out;

  // workspace layout (floats)
  // x0g slot t (65536 f): [0:16384) hist(t) after phase t | [32768:49152) ctx(t)
  float* x0g  = (float*)d_ws;                 // 4,194,304
  float* h0p  = x0g  + 4194304;               // 32,768  [2][16384]
  float* h1p  = h0p  + 32768;                 // 65,536  [4][16384]
  float* cbuf = h1p  + 65536;                 // 32,768
  float* Wp0  = cbuf + 32768;                 // 1,048,576
  float* Wp1  = Wp0  + 1048576;               // 2,097,152
  unsigned int* bar = (unsigned int*)(Wp1 + 2097152);           // 5120 words
  unsigned short* oa    = (unsigned short*)(bar + 5120);        // 1,048,576 us [b][t][u]
  unsigned short* wo_bf = oa + 1048576;       // 16,384,000 us (32MB)

  const int DLDS_BYTES = 34304 * 4;           // 137.2 KB dynamic LDS
  hipFuncSetAttribute((const void*)decoder_persist_v8,
      hipFuncAttributeMaxDynamicSharedMemorySize, DLDS_BYTES);

  init_state_v8<<<128, 256, 0, stream>>>(h0, h0p, h1p, bar);
  conv_bf16_kernel<<<16000, 256, 0, stream>>>(Wo, wo_bf);
  pack_l0_v3<<<1024, 256, 0, stream>>>(Whh, Wp0);
  pack_l1_v3<<<2048, 256, 0, stream>>>(Wih + (size_t)G4*Hz, Whh + (size_t)G4*Hz, Wp1);
  x0g_v3<<<dim3(32, 32), 256, 0, stream>>>(tgt, emb, Wih, bih, bhh, x0g);

  decoder_persist_v8<<<NBLK, 512, DLDS_BYTES, stream>>>(
      Wp0, Wp1, x0g, bih + G4, bhh + G4, c0,
      h0p, h1p, /*hist=*/x0g, cbuf, (unsigned int*)bar);

  attn_batch<<<2048, 256, 0, stream>>>(x0g, enc, x0g);
  outatt_gemm<<<dim3(8, 32), 256, 0, stream>>>(x0g, Wc, bc, oa);
  pred_gemm_v2<<<4096, 256, 0, stream>>>(oa, wo_bf, bo, out);
  copy_hc_v4<<<256, 256, 0, stream>>>(h0p + 16384, x0g + (size_t)63*65536, cbuf,
                                      out + (size_t)Bz*Tz*Vz);

  (void)in_sizes; (void)n_in; (void)out_size; (void)ws_size;
}